// Round 4
// baseline (776.289 us; speedup 1.0000x reference)
//
#include <hip/hip_runtime.h>
#include <math.h>

#define F_IN 128
#define TDIM 64
#define NGRAPH 256

__device__ __forceinline__ float gelu_f(float x) {
    float x3 = x * x * x;
    return 0.5f * x * (1.0f + tanhf(0.7978845608028654f * (x + 0.044715f * x3)));
}

// ---------------- degree / CSR build ----------------

__global__ __launch_bounds__(256) void deg_count_kernel(const int* __restrict__ dst,
                                                        int* __restrict__ cnt, int E) {
    int e = blockIdx.x * blockDim.x + threadIdx.x;
    if (e < E) atomicAdd(&cnt[dst[e]], 1);
}

__global__ __launch_bounds__(256) void deg_fin_kernel(const int* __restrict__ cnt,
                                                      float* __restrict__ isq,
                                                      float* __restrict__ dinv, int n) {
    int i = blockIdx.x * blockDim.x + threadIdx.x;
    if (i < n) {
        float d = (float)cnt[i] + 1.0f;  // +1 self loop
        isq[i] = rsqrtf(d);
        dinv[i] = 1.0f / d;
    }
}

// 3-phase exclusive scan of cnt[N] -> row_off[N+1], chunk = 2048 per block
__global__ __launch_bounds__(256) void scanA_kernel(const int* __restrict__ cnt,
                                                    int* __restrict__ bsums, int n) {
    __shared__ int sh[256];
    int t = threadIdx.x;
    int base = blockIdx.x * 2048 + t * 8;
    int s = 0;
    for (int j = 0; j < 8; ++j) {
        int i = base + j;
        if (i < n) s += cnt[i];
    }
    sh[t] = s;
    __syncthreads();
    for (int off = 128; off > 0; off >>= 1) {
        if (t < off) sh[t] += sh[t + off];
        __syncthreads();
    }
    if (t == 0) bsums[blockIdx.x] = sh[0];
}

__global__ void scanB_kernel(int* __restrict__ bsums, int nb, int* __restrict__ row_off) {
    if (threadIdx.x == 0 && blockIdx.x == 0) {
        int c = 0;
        for (int i = 0; i < nb; ++i) {
            int v = bsums[i];
            bsums[i] = c;
            c += v;
        }
        row_off[0] = 0;
    }
}

__global__ __launch_bounds__(256) void scanC_kernel(const int* __restrict__ cnt,
                                                    const int* __restrict__ bsums,
                                                    int* __restrict__ row_off, int n) {
    __shared__ int sh[256];
    int t = threadIdx.x;
    int base = blockIdx.x * 2048 + t * 8;
    int v[8];
    int s = 0;
    for (int j = 0; j < 8; ++j) {
        int i = base + j;
        int x = (i < n) ? cnt[i] : 0;
        s += x;
        v[j] = s;  // local inclusive
    }
    sh[t] = s;
    __syncthreads();
    for (int off = 1; off < 256; off <<= 1) {
        int x = (t >= off) ? sh[t - off] : 0;
        __syncthreads();
        sh[t] += x;
        __syncthreads();
    }
    int threadExcl = sh[t] - s;
    int off0 = bsums[blockIdx.x] + threadExcl;
    for (int j = 0; j < 8; ++j) {
        int i = base + j;
        if (i < n) row_off[i + 1] = off0 + v[j];
    }
}

__global__ __launch_bounds__(256) void fill_edges_kernel(const int* __restrict__ src,
                                                         const int* __restrict__ dst,
                                                         const int* __restrict__ row_off,
                                                         int* __restrict__ cursor,
                                                         const float* __restrict__ isq,
                                                         int* __restrict__ src_s,
                                                         float* __restrict__ nrm_s, int E) {
    int e = blockIdx.x * blockDim.x + threadIdx.x;
    if (e >= E) return;
    int s = src[e];
    int d = dst[e];
    int p = atomicAdd(&cursor[d], 1);
    int idx = row_off[d] + p;
    src_s[idx] = s;
    nrm_s[idx] = isq[s] * isq[d];
}

// ---------------- fp32 GEMM: Y[N,FOUT] = X[N,128] @ W[128,FOUT] ----------------

template <int FOUT>
__global__ __launch_bounds__(256) void gemm_kernel(const float* __restrict__ X,
                                                   const float* __restrict__ W,
                                                   float* __restrict__ Y, int nrows) {
    constexpr int TN = FOUT / 16;
    __shared__ float As[16][128];   // [k][row]
    __shared__ float Ws[16][FOUT];  // [k][col]
    int t = threadIdx.x;
    int tr = t / 16;  // row group 0..15
    int tc = t % 16;  // col group 0..15
    int rowBase = blockIdx.x * 128;
    float acc[8][TN];
#pragma unroll
    for (int i = 0; i < 8; ++i)
#pragma unroll
        for (int j = 0; j < TN; ++j) acc[i][j] = 0.0f;

    for (int k0 = 0; k0 < 128; k0 += 16) {
        for (int l = t; l < 512; l += 256) {
            int rr = l >> 2;
            int kk4 = (l & 3) * 4;
            int grow = rowBase + rr;
            float4 v = make_float4(0.f, 0.f, 0.f, 0.f);
            if (grow < nrows) v = *(const float4*)(X + (size_t)grow * 128 + k0 + kk4);
            As[kk4 + 0][rr] = v.x;
            As[kk4 + 1][rr] = v.y;
            As[kk4 + 2][rr] = v.z;
            As[kk4 + 3][rr] = v.w;
        }
        for (int l = t; l < 16 * FOUT / 4; l += 256) {
            int kk = l / (FOUT / 4);
            int cc4 = (l % (FOUT / 4)) * 4;
            *(float4*)&Ws[kk][cc4] = *(const float4*)(W + (size_t)(k0 + kk) * FOUT + cc4);
        }
        __syncthreads();
#pragma unroll
        for (int kk = 0; kk < 16; ++kk) {
            float a[8], b[TN];
#pragma unroll
            for (int i = 0; i < 8; ++i) a[i] = As[kk][tr * 8 + i];
#pragma unroll
            for (int j = 0; j < TN; ++j) b[j] = Ws[kk][tc * TN + j];
#pragma unroll
            for (int i = 0; i < 8; ++i)
#pragma unroll
                for (int j = 0; j < TN; ++j) acc[i][j] += a[i] * b[j];
        }
        __syncthreads();
    }
    for (int i = 0; i < 8; ++i) {
        int grow = rowBase + tr * 8 + i;
        if (grow < nrows) {
#pragma unroll
            for (int j = 0; j < TN; j += 4)
                *(float4*)(Y + (size_t)grow * FOUT + tc * TN + j) = *(float4*)&acc[i][j];
        }
    }
}

// ---------------- edge aggregation (F=128): float2/lane => 1 load per edge row ----------------

__global__ __launch_bounds__(256) void agg128_kernel(const float* __restrict__ xl,
                                                     const int* __restrict__ row_off,
                                                     const int* __restrict__ src_s,
                                                     const float* __restrict__ nrm_s,
                                                     const float* __restrict__ dinv,
                                                     const float* __restrict__ bias,
                                                     float* __restrict__ out, int nnodes) {
    int wave = (blockIdx.x * blockDim.x + threadIdx.x) >> 6;
    int lane = threadIdx.x & 63;
    if (wave >= nnodes) return;
    int e0 = row_off[wave], e1 = row_off[wave + 1];
    float ax = 0.f, ay = 0.f;
    int e = e0;
    for (; e + 8 <= e1; e += 8) {
        int s[8];
        float nw[8];
#pragma unroll
        for (int j = 0; j < 8; ++j) s[j] = src_s[e + j];
#pragma unroll
        for (int j = 0; j < 8; ++j) nw[j] = nrm_s[e + j];
        float2 v[8];
#pragma unroll
        for (int j = 0; j < 8; ++j)
            v[j] = *(const float2*)(xl + (size_t)s[j] * 128 + lane * 2);
#pragma unroll
        for (int j = 0; j < 8; ++j) {
            ax += nw[j] * v[j].x;
            ay += nw[j] * v[j].y;
        }
    }
    for (; e < e1; ++e) {
        int s = src_s[e];
        float nw = nrm_s[e];
        float2 v = *(const float2*)(xl + (size_t)s * 128 + lane * 2);
        ax += nw * v.x;
        ay += nw * v.y;
    }
    float di = dinv[wave];
    float2 pi = *(const float2*)(xl + (size_t)wave * 128 + lane * 2);
    float2 bb = *(const float2*)(bias + lane * 2);
    float2 o;
    o.x = gelu_f(ax + di * pi.x + bb.x);
    o.y = gelu_f(ay + di * pi.y + bb.y);
    *(float2*)(out + (size_t)wave * 128 + lane * 2) = o;
}

// ---------------- edge aggregation (F=64): half-wave per edge, float2/lane ----------------

__global__ __launch_bounds__(256) void agg64_kernel(const float* __restrict__ xl,
                                                    const int* __restrict__ row_off,
                                                    const int* __restrict__ src_s,
                                                    const float* __restrict__ nrm_s,
                                                    const float* __restrict__ dinv,
                                                    const float* __restrict__ bias,
                                                    float* __restrict__ out, int nnodes) {
    int wave = (blockIdx.x * blockDim.x + threadIdx.x) >> 6;
    int lane = threadIdx.x & 63;
    int sub = lane >> 5;   // which edge of the pair
    int sl = lane & 31;    // column group: cols 2*sl, 2*sl+1
    if (wave >= nnodes) return;
    int e0 = row_off[wave], e1 = row_off[wave + 1];
    float ax = 0.f, ay = 0.f;
    int e = e0;
    for (; e + 8 <= e1; e += 8) {
        int s[4];
        float nw[4];
#pragma unroll
        for (int j = 0; j < 4; ++j) {
            s[j] = src_s[e + 2 * j + sub];
            nw[j] = nrm_s[e + 2 * j + sub];
        }
        float2 v[4];
#pragma unroll
        for (int j = 0; j < 4; ++j)
            v[j] = *(const float2*)(xl + (size_t)s[j] * 64 + sl * 2);
#pragma unroll
        for (int j = 0; j < 4; ++j) {
            ax += nw[j] * v[j].x;
            ay += nw[j] * v[j].y;
        }
    }
    for (; e + 2 <= e1; e += 2) {
        int s = src_s[e + sub];
        float nw = nrm_s[e + sub];
        float2 v = *(const float2*)(xl + (size_t)s * 64 + sl * 2);
        ax += nw * v.x;
        ay += nw * v.y;
    }
    if (e < e1 && sub == 0) {
        int s = src_s[e];
        float nw = nrm_s[e];
        float2 v = *(const float2*)(xl + (size_t)s * 64 + sl * 2);
        ax += nw * v.x;
        ay += nw * v.y;
    }
    // combine the two half-wave edge streams
    ax += __shfl_xor(ax, 32, 64);
    ay += __shfl_xor(ay, 32, 64);
    if (sub == 0) {
        float di = dinv[wave];
        float2 pi = *(const float2*)(xl + (size_t)wave * 64 + sl * 2);
        float2 bb = *(const float2*)(bias + sl * 2);
        float2 o;
        o.x = gelu_f(ax + di * pi.x + bb.x);
        o.y = gelu_f(ay + di * pi.y + bb.y);
        *(float2*)(out + (size_t)wave * 64 + sl * 2) = o;
    }
}

// ---------------- mean pool (batch sorted: segment-accumulate per wave chunk) ----------------

#define POOL_CHUNK 64

__global__ __launch_bounds__(256) void pool_kernel(const float* __restrict__ h,
                                                   const int* __restrict__ batch,
                                                   float* __restrict__ psum,
                                                   float* __restrict__ pcnt, int nnodes) {
    int wave = (blockIdx.x * blockDim.x + threadIdx.x) >> 6;
    int lane = threadIdx.x & 63;
    int n0 = wave * POOL_CHUNK;
    if (n0 >= nnodes) return;
    int n1 = n0 + POOL_CHUNK;
    if (n1 > nnodes) n1 = nnodes;

    int g_cur = batch[n0];
    float acc = 0.f;
    int cnt = 0;
    for (int node = n0; node < n1; ++node) {
        int g = batch[node];
        if (g != g_cur) {
            atomicAdd(&psum[g_cur * TDIM + lane], acc);
            if (lane == 0) atomicAdd(&pcnt[g_cur], (float)cnt);
            acc = 0.f;
            cnt = 0;
            g_cur = g;
        }
        acc += h[(size_t)node * TDIM + lane];
        ++cnt;
    }
    atomicAdd(&psum[g_cur * TDIM + lane], acc);
    if (lane == 0) atomicAdd(&pcnt[g_cur], (float)cnt);
}

__global__ __launch_bounds__(256) void fin_kernel(const float* __restrict__ psum,
                                                  const float* __restrict__ pcnt,
                                                  float* __restrict__ out) {
    int i = blockIdx.x * blockDim.x + threadIdx.x;
    if (i < NGRAPH * TDIM) {
        float c = pcnt[i >> 6];
        out[i] = psum[i] / fmaxf(c, 1.0f);
    }
}

// ---------------- launch ----------------

extern "C" void kernel_launch(void* const* d_in, const int* in_sizes, int n_in,
                              void* d_out, int out_size, void* d_ws, size_t ws_size,
                              hipStream_t stream) {
    const float* x = (const float*)d_in[0];
    const int* ei = (const int*)d_in[1];
    const int* batch = (const int*)d_in[2];
    const float* W0 = (const float*)d_in[3];
    const float* b0 = (const float*)d_in[4];
    const float* W1 = (const float*)d_in[5];
    const float* b1 = (const float*)d_in[6];
    const float* W2 = (const float*)d_in[7];
    const float* b2 = (const float*)d_in[8];

    const int N = in_sizes[0] / F_IN;
    const int E = in_sizes[1] / 2;
    const int* src = ei;
    const int* dst = ei + E;

    char* w = (char*)d_ws;
    auto alloc = [&](size_t bytes) -> void* {
        void* p = (void*)w;
        w += (bytes + 255) & ~(size_t)255;
        return p;
    };
    float* isq = (float*)alloc((size_t)N * 4);
    float* dinv = (float*)alloc((size_t)N * 4);
    int* cnt = (int*)alloc((size_t)N * 4);
    int* cursor = (int*)alloc((size_t)N * 4);
    int* row_off = (int*)alloc((size_t)(N + 1) * 4);
    int* bsums = (int*)alloc(256 * 4);
    int* src_s = (int*)alloc((size_t)E * 4);
    float* nrm_s = (float*)alloc((size_t)E * 4);
    float* psum = (float*)alloc((size_t)NGRAPH * TDIM * 4);
    float* pcnt = (float*)alloc((size_t)NGRAPH * 4);
    float* bufA = (float*)alloc((size_t)N * 128 * 4);
    float* bufB = (float*)alloc((size_t)N * 128 * 4);

    hipMemsetAsync(cnt, 0, (size_t)N * 4, stream);
    hipMemsetAsync(cursor, 0, (size_t)N * 4, stream);
    hipMemsetAsync(psum, 0, (size_t)NGRAPH * TDIM * 4, stream);
    hipMemsetAsync(pcnt, 0, (size_t)NGRAPH * 4, stream);

    const int tb = 256;
    deg_count_kernel<<<(E + tb - 1) / tb, tb, 0, stream>>>(dst, cnt, E);
    deg_fin_kernel<<<(N + tb - 1) / tb, tb, 0, stream>>>(cnt, isq, dinv, N);

    int nchunk = (N + 2047) / 2048;
    scanA_kernel<<<nchunk, 256, 0, stream>>>(cnt, bsums, N);
    scanB_kernel<<<1, 64, 0, stream>>>(bsums, nchunk, row_off);
    scanC_kernel<<<nchunk, 256, 0, stream>>>(cnt, bsums, row_off, N);
    fill_edges_kernel<<<(E + tb - 1) / tb, tb, 0, stream>>>(src, dst, row_off, cursor, isq,
                                                            src_s, nrm_s, E);

    int gblocks = (N + 127) / 128;
    int ablocks = (N * 64 + 255) / 256;

    // layer 0: x @ W0 -> bufA; agg -> bufB
    gemm_kernel<128><<<gblocks, 256, 0, stream>>>(x, W0, bufA, N);
    agg128_kernel<<<ablocks, 256, 0, stream>>>(bufA, row_off, src_s, nrm_s, dinv, b0, bufB, N);
    // layer 1
    gemm_kernel<128><<<gblocks, 256, 0, stream>>>(bufB, W1, bufA, N);
    agg128_kernel<<<ablocks, 256, 0, stream>>>(bufA, row_off, src_s, nrm_s, dinv, b1, bufB, N);
    // layer 2 (Fout = 64)
    gemm_kernel<64><<<gblocks, 256, 0, stream>>>(bufB, W2, bufA, N);
    agg64_kernel<<<ablocks, 256, 0, stream>>>(bufA, row_off, src_s, nrm_s, dinv, b2, bufB, N);

    // pool
    int pwaves = (N + POOL_CHUNK - 1) / POOL_CHUNK;
    int pblocks = (pwaves * 64 + 255) / 256;
    pool_kernel<<<pblocks, 256, 0, stream>>>(bufB, batch, psum, pcnt, N);
    fin_kernel<<<(NGRAPH * TDIM + 255) / 256, 256, 0, stream>>>(psum, pcnt, (float*)d_out);
}

// Round 5
// 677.982 us; speedup vs baseline: 1.1450x; 1.1450x over previous
//
#include <hip/hip_runtime.h>
#include <math.h>

#define F_IN 128
#define TDIM 64
#define NGRAPH 256

__device__ __forceinline__ float gelu_f(float x) {
    float x3 = x * x * x;
    return 0.5f * x * (1.0f + tanhf(0.7978845608028654f * (x + 0.044715f * x3)));
}

// pack two fp32 -> bf16 pair (RNE), and unpack
__device__ __forceinline__ unsigned bf16pair(float a, float b) {
    unsigned ua = __float_as_uint(a), ub = __float_as_uint(b);
    ua = (ua + 0x7fffu + ((ua >> 16) & 1u)) >> 16;
    ub = (ub + 0x7fffu + ((ub >> 16) & 1u)) >> 16;
    return ua | (ub << 16);
}
__device__ __forceinline__ float2 bf16unpack(unsigned u) {
    float2 r;
    r.x = __uint_as_float(u << 16);
    r.y = __uint_as_float(u & 0xffff0000u);
    return r;
}

// ---------------- degree / CSR build ----------------

__global__ __launch_bounds__(256) void deg_count_kernel(const int* __restrict__ dst,
                                                        int* __restrict__ cnt, int E) {
    int e = blockIdx.x * blockDim.x + threadIdx.x;
    if (e < E) atomicAdd(&cnt[dst[e]], 1);
}

__global__ __launch_bounds__(256) void deg_fin_kernel(const int* __restrict__ cnt,
                                                      float* __restrict__ isq,
                                                      float* __restrict__ dinv, int n) {
    int i = blockIdx.x * blockDim.x + threadIdx.x;
    if (i < n) {
        float d = (float)cnt[i] + 1.0f;  // +1 self loop
        isq[i] = rsqrtf(d);
        dinv[i] = 1.0f / d;
    }
}

// 3-phase exclusive scan of cnt[N] -> row_off[N+1], chunk = 2048 per block
__global__ __launch_bounds__(256) void scanA_kernel(const int* __restrict__ cnt,
                                                    int* __restrict__ bsums, int n) {
    __shared__ int sh[256];
    int t = threadIdx.x;
    int base = blockIdx.x * 2048 + t * 8;
    int s = 0;
    for (int j = 0; j < 8; ++j) {
        int i = base + j;
        if (i < n) s += cnt[i];
    }
    sh[t] = s;
    __syncthreads();
    for (int off = 128; off > 0; off >>= 1) {
        if (t < off) sh[t] += sh[t + off];
        __syncthreads();
    }
    if (t == 0) bsums[blockIdx.x] = sh[0];
}

__global__ void scanB_kernel(int* __restrict__ bsums, int nb, int* __restrict__ row_off) {
    if (threadIdx.x == 0 && blockIdx.x == 0) {
        int c = 0;
        for (int i = 0; i < nb; ++i) {
            int v = bsums[i];
            bsums[i] = c;
            c += v;
        }
        row_off[0] = 0;
    }
}

__global__ __launch_bounds__(256) void scanC_kernel(const int* __restrict__ cnt,
                                                    const int* __restrict__ bsums,
                                                    int* __restrict__ row_off, int n) {
    __shared__ int sh[256];
    int t = threadIdx.x;
    int base = blockIdx.x * 2048 + t * 8;
    int v[8];
    int s = 0;
    for (int j = 0; j < 8; ++j) {
        int i = base + j;
        int x = (i < n) ? cnt[i] : 0;
        s += x;
        v[j] = s;  // local inclusive
    }
    sh[t] = s;
    __syncthreads();
    for (int off = 1; off < 256; off <<= 1) {
        int x = (t >= off) ? sh[t - off] : 0;
        __syncthreads();
        sh[t] += x;
        __syncthreads();
    }
    int threadExcl = sh[t] - s;
    int off0 = bsums[blockIdx.x] + threadExcl;
    for (int j = 0; j < 8; ++j) {
        int i = base + j;
        if (i < n) row_off[i + 1] = off0 + v[j];
    }
}

__global__ __launch_bounds__(256) void fill_edges_kernel(const int* __restrict__ src,
                                                         const int* __restrict__ dst,
                                                         const int* __restrict__ row_off,
                                                         int* __restrict__ cursor,
                                                         const float* __restrict__ isq,
                                                         int* __restrict__ src_s,
                                                         float* __restrict__ nrm_s, int E) {
    int e = blockIdx.x * blockDim.x + threadIdx.x;
    if (e >= E) return;
    int s = src[e];
    int d = dst[e];
    int p = atomicAdd(&cursor[d], 1);
    int idx = row_off[d] + p;
    src_s[idx] = s;
    nrm_s[idx] = isq[s] * isq[d];
}

// ---------------- fp32 GEMM: Y[N,FOUT] = X[N,128] @ W[128,FOUT] ----------------
// also emits packed-bf16 copy Yb (for the gather stage)

template <int FOUT>
__global__ __launch_bounds__(256) void gemm_kernel(const float* __restrict__ X,
                                                   const float* __restrict__ W,
                                                   float* __restrict__ Y,
                                                   unsigned* __restrict__ Yb, int nrows) {
    constexpr int TN = FOUT / 16;
    __shared__ float As[16][128];   // [k][row]
    __shared__ float Ws[16][FOUT];  // [k][col]
    int t = threadIdx.x;
    int tr = t / 16;  // row group 0..15
    int tc = t % 16;  // col group 0..15
    int rowBase = blockIdx.x * 128;
    float acc[8][TN];
#pragma unroll
    for (int i = 0; i < 8; ++i)
#pragma unroll
        for (int j = 0; j < TN; ++j) acc[i][j] = 0.0f;

    for (int k0 = 0; k0 < 128; k0 += 16) {
        for (int l = t; l < 512; l += 256) {
            int rr = l >> 2;
            int kk4 = (l & 3) * 4;
            int grow = rowBase + rr;
            float4 v = make_float4(0.f, 0.f, 0.f, 0.f);
            if (grow < nrows) v = *(const float4*)(X + (size_t)grow * 128 + k0 + kk4);
            As[kk4 + 0][rr] = v.x;
            As[kk4 + 1][rr] = v.y;
            As[kk4 + 2][rr] = v.z;
            As[kk4 + 3][rr] = v.w;
        }
        for (int l = t; l < 16 * FOUT / 4; l += 256) {
            int kk = l / (FOUT / 4);
            int cc4 = (l % (FOUT / 4)) * 4;
            *(float4*)&Ws[kk][cc4] = *(const float4*)(W + (size_t)(k0 + kk) * FOUT + cc4);
        }
        __syncthreads();
#pragma unroll
        for (int kk = 0; kk < 16; ++kk) {
            float a[8], b[TN];
#pragma unroll
            for (int i = 0; i < 8; ++i) a[i] = As[kk][tr * 8 + i];
#pragma unroll
            for (int j = 0; j < TN; ++j) b[j] = Ws[kk][tc * TN + j];
#pragma unroll
            for (int i = 0; i < 8; ++i)
#pragma unroll
                for (int j = 0; j < TN; ++j) acc[i][j] += a[i] * b[j];
        }
        __syncthreads();
    }
    for (int i = 0; i < 8; ++i) {
        int grow = rowBase + tr * 8 + i;
        if (grow < nrows) {
#pragma unroll
            for (int j = 0; j < TN; j += 4)
                *(float4*)(Y + (size_t)grow * FOUT + tc * TN + j) = *(float4*)&acc[i][j];
            // packed bf16 copy: uint u holds cols (2u, 2u+1)
            unsigned pk[TN / 2];
#pragma unroll
            for (int j = 0; j < TN; j += 2) pk[j / 2] = bf16pair(acc[i][j], acc[i][j + 1]);
            if (TN == 8)
                *(uint4*)(Yb + (size_t)grow * 64 + tc * 4) = *(uint4*)pk;
            else
                *(uint2*)(Yb + (size_t)grow * 32 + tc * 2) = *(uint2*)pk;
        }
    }
}

// ---------------- edge aggregation (F=128): bf16 gather, fp32 accumulate ----------------

__global__ __launch_bounds__(256) void agg128_kernel(const float* __restrict__ xl,
                                                     const unsigned* __restrict__ xlb,
                                                     const int* __restrict__ row_off,
                                                     const int* __restrict__ src_s,
                                                     const float* __restrict__ nrm_s,
                                                     const float* __restrict__ dinv,
                                                     const float* __restrict__ bias,
                                                     float* __restrict__ out, int nnodes) {
    int wave = (blockIdx.x * blockDim.x + threadIdx.x) >> 6;
    int lane = threadIdx.x & 63;
    if (wave >= nnodes) return;
    int e0 = row_off[wave], e1 = row_off[wave + 1];
    float ax = 0.f, ay = 0.f;
    int e = e0;
    for (; e + 8 <= e1; e += 8) {
        int s[8];
        float nw[8];
#pragma unroll
        for (int j = 0; j < 8; ++j) s[j] = src_s[e + j];
#pragma unroll
        for (int j = 0; j < 8; ++j) nw[j] = nrm_s[e + j];
        unsigned v[8];
#pragma unroll
        for (int j = 0; j < 8; ++j) v[j] = xlb[(size_t)s[j] * 64 + lane];
#pragma unroll
        for (int j = 0; j < 8; ++j) {
            float2 f = bf16unpack(v[j]);
            ax += nw[j] * f.x;
            ay += nw[j] * f.y;
        }
    }
    for (; e < e1; ++e) {
        int s = src_s[e];
        float nw = nrm_s[e];
        float2 f = bf16unpack(xlb[(size_t)s * 64 + lane]);
        ax += nw * f.x;
        ay += nw * f.y;
    }
    // self-loop term in full fp32 (own row, coalesced)
    float di = dinv[wave];
    float2 pi = *(const float2*)(xl + (size_t)wave * 128 + lane * 2);
    float2 bb = *(const float2*)(bias + lane * 2);
    float2 o;
    o.x = gelu_f(ax + di * pi.x + bb.x);
    o.y = gelu_f(ay + di * pi.y + bb.y);
    *(float2*)(out + (size_t)wave * 128 + lane * 2) = o;
}

// ---------------- edge aggregation (F=64): half-wave per edge, bf16 gather ----------------

__global__ __launch_bounds__(256) void agg64_kernel(const float* __restrict__ xl,
                                                    const unsigned* __restrict__ xlb,
                                                    const int* __restrict__ row_off,
                                                    const int* __restrict__ src_s,
                                                    const float* __restrict__ nrm_s,
                                                    const float* __restrict__ dinv,
                                                    const float* __restrict__ bias,
                                                    float* __restrict__ out, int nnodes) {
    int wave = (blockIdx.x * blockDim.x + threadIdx.x) >> 6;
    int lane = threadIdx.x & 63;
    int sub = lane >> 5;   // which edge of the pair
    int sl = lane & 31;    // column group: cols 2*sl, 2*sl+1
    if (wave >= nnodes) return;
    int e0 = row_off[wave], e1 = row_off[wave + 1];
    float ax = 0.f, ay = 0.f;
    int e = e0;
    for (; e + 8 <= e1; e += 8) {
        int s[4];
        float nw[4];
#pragma unroll
        for (int j = 0; j < 4; ++j) {
            s[j] = src_s[e + 2 * j + sub];
            nw[j] = nrm_s[e + 2 * j + sub];
        }
        unsigned v[4];
#pragma unroll
        for (int j = 0; j < 4; ++j) v[j] = xlb[(size_t)s[j] * 32 + sl];
#pragma unroll
        for (int j = 0; j < 4; ++j) {
            float2 f = bf16unpack(v[j]);
            ax += nw[j] * f.x;
            ay += nw[j] * f.y;
        }
    }
    for (; e + 2 <= e1; e += 2) {
        int s = src_s[e + sub];
        float nw = nrm_s[e + sub];
        float2 f = bf16unpack(xlb[(size_t)s * 32 + sl]);
        ax += nw * f.x;
        ay += nw * f.y;
    }
    if (e < e1 && sub == 0) {
        int s = src_s[e];
        float nw = nrm_s[e];
        float2 f = bf16unpack(xlb[(size_t)s * 32 + sl]);
        ax += nw * f.x;
        ay += nw * f.y;
    }
    // combine the two half-wave edge streams
    ax += __shfl_xor(ax, 32, 64);
    ay += __shfl_xor(ay, 32, 64);
    if (sub == 0) {
        float di = dinv[wave];
        float2 pi = *(const float2*)(xl + (size_t)wave * 64 + sl * 2);
        float2 bb = *(const float2*)(bias + sl * 2);
        float2 o;
        o.x = gelu_f(ax + di * pi.x + bb.x);
        o.y = gelu_f(ay + di * pi.y + bb.y);
        *(float2*)(out + (size_t)wave * 64 + sl * 2) = o;
    }
}

// ---------------- mean pool (batch sorted: segment-accumulate per wave chunk) ----------------

#define POOL_CHUNK 64

__global__ __launch_bounds__(256) void pool_kernel(const float* __restrict__ h,
                                                   const int* __restrict__ batch,
                                                   float* __restrict__ psum,
                                                   float* __restrict__ pcnt, int nnodes) {
    int wave = (blockIdx.x * blockDim.x + threadIdx.x) >> 6;
    int lane = threadIdx.x & 63;
    int n0 = wave * POOL_CHUNK;
    if (n0 >= nnodes) return;
    int n1 = n0 + POOL_CHUNK;
    if (n1 > nnodes) n1 = nnodes;

    int g_cur = batch[n0];
    float acc = 0.f;
    int cnt = 0;
    for (int node = n0; node < n1; ++node) {
        int g = batch[node];
        if (g != g_cur) {
            atomicAdd(&psum[g_cur * TDIM + lane], acc);
            if (lane == 0) atomicAdd(&pcnt[g_cur], (float)cnt);
            acc = 0.f;
            cnt = 0;
            g_cur = g;
        }
        acc += h[(size_t)node * TDIM + lane];
        ++cnt;
    }
    atomicAdd(&psum[g_cur * TDIM + lane], acc);
    if (lane == 0) atomicAdd(&pcnt[g_cur], (float)cnt);
}

__global__ __launch_bounds__(256) void fin_kernel(const float* __restrict__ psum,
                                                  const float* __restrict__ pcnt,
                                                  float* __restrict__ out) {
    int i = blockIdx.x * blockDim.x + threadIdx.x;
    if (i < NGRAPH * TDIM) {
        float c = pcnt[i >> 6];
        out[i] = psum[i] / fmaxf(c, 1.0f);
    }
}

// ---------------- launch ----------------

extern "C" void kernel_launch(void* const* d_in, const int* in_sizes, int n_in,
                              void* d_out, int out_size, void* d_ws, size_t ws_size,
                              hipStream_t stream) {
    const float* x = (const float*)d_in[0];
    const int* ei = (const int*)d_in[1];
    const int* batch = (const int*)d_in[2];
    const float* W0 = (const float*)d_in[3];
    const float* b0 = (const float*)d_in[4];
    const float* W1 = (const float*)d_in[5];
    const float* b1 = (const float*)d_in[6];
    const float* W2 = (const float*)d_in[7];
    const float* b2 = (const float*)d_in[8];

    const int N = in_sizes[0] / F_IN;
    const int E = in_sizes[1] / 2;
    const int* src = ei;
    const int* dst = ei + E;

    char* w = (char*)d_ws;
    auto alloc = [&](size_t bytes) -> void* {
        void* p = (void*)w;
        w += (bytes + 255) & ~(size_t)255;
        return p;
    };
    float* isq = (float*)alloc((size_t)N * 4);
    float* dinv = (float*)alloc((size_t)N * 4);
    int* cnt = (int*)alloc((size_t)N * 4);
    int* cursor = (int*)alloc((size_t)N * 4);
    int* row_off = (int*)alloc((size_t)(N + 1) * 4);
    int* bsums = (int*)alloc(256 * 4);
    int* src_s = (int*)alloc((size_t)E * 4);
    float* nrm_s = (float*)alloc((size_t)E * 4);
    float* psum = (float*)alloc((size_t)NGRAPH * TDIM * 4);
    float* pcnt = (float*)alloc((size_t)NGRAPH * 4);
    float* bufA = (float*)alloc((size_t)N * 128 * 4);
    float* bufB = (float*)alloc((size_t)N * 128 * 4);
    unsigned* bufAb = (unsigned*)alloc((size_t)N * 64 * 4);  // packed bf16 xl

    hipMemsetAsync(cnt, 0, (size_t)N * 4, stream);
    hipMemsetAsync(cursor, 0, (size_t)N * 4, stream);
    hipMemsetAsync(psum, 0, (size_t)NGRAPH * TDIM * 4, stream);
    hipMemsetAsync(pcnt, 0, (size_t)NGRAPH * 4, stream);

    const int tb = 256;
    deg_count_kernel<<<(E + tb - 1) / tb, tb, 0, stream>>>(dst, cnt, E);
    deg_fin_kernel<<<(N + tb - 1) / tb, tb, 0, stream>>>(cnt, isq, dinv, N);

    int nchunk = (N + 2047) / 2048;
    scanA_kernel<<<nchunk, 256, 0, stream>>>(cnt, bsums, N);
    scanB_kernel<<<1, 64, 0, stream>>>(bsums, nchunk, row_off);
    scanC_kernel<<<nchunk, 256, 0, stream>>>(cnt, bsums, row_off, N);
    fill_edges_kernel<<<(E + tb - 1) / tb, tb, 0, stream>>>(src, dst, row_off, cursor, isq,
                                                            src_s, nrm_s, E);

    int gblocks = (N + 127) / 128;
    int ablocks = (N * 64 + 255) / 256;

    // layer 0: x @ W0 -> bufA (+bf16); agg -> bufB
    gemm_kernel<128><<<gblocks, 256, 0, stream>>>(x, W0, bufA, bufAb, N);
    agg128_kernel<<<ablocks, 256, 0, stream>>>(bufA, bufAb, row_off, src_s, nrm_s, dinv, b0,
                                               bufB, N);
    // layer 1
    gemm_kernel<128><<<gblocks, 256, 0, stream>>>(bufB, W1, bufA, bufAb, N);
    agg128_kernel<<<ablocks, 256, 0, stream>>>(bufA, bufAb, row_off, src_s, nrm_s, dinv, b1,
                                               bufB, N);
    // layer 2 (Fout = 64)
    gemm_kernel<64><<<gblocks, 256, 0, stream>>>(bufB, W2, bufA, bufAb, N);
    agg64_kernel<<<ablocks, 256, 0, stream>>>(bufA, bufAb, row_off, src_s, nrm_s, dinv, b2,
                                              bufB, N);

    // pool
    int pwaves = (N + POOL_CHUNK - 1) / POOL_CHUNK;
    int pblocks = (pwaves * 64 + 255) / 256;
    pool_kernel<<<pblocks, 256, 0, stream>>>(bufB, batch, psum, pcnt, N);
    fin_kernel<<<(NGRAPH * TDIM + 255) / 256, 256, 0, stream>>>(psum, pcnt, (float*)d_out);
}

// Round 6
// 675.905 us; speedup vs baseline: 1.1485x; 1.0031x over previous
//
#include <hip/hip_runtime.h>
#include <math.h>

#define F_IN 128
#define TDIM 64
#define NGRAPH 256

typedef __attribute__((ext_vector_type(8))) short short8;
typedef __attribute__((ext_vector_type(4))) float f32x4;

__device__ __forceinline__ float gelu_f(float x) {
    float x3 = x * x * x;
    return 0.5f * x * (1.0f + tanhf(0.7978845608028654f * (x + 0.044715f * x3)));
}

// fp32 <-> bf16 bit helpers (RNE)
__device__ __forceinline__ unsigned short bf16_of(float x) {
    unsigned u = __float_as_uint(x);
    return (unsigned short)((u + 0x7fffu + ((u >> 16) & 1u)) >> 16);
}
__device__ __forceinline__ float f_of(unsigned short h) {
    return __uint_as_float(((unsigned)h) << 16);
}
__device__ __forceinline__ unsigned bf16pair(float a, float b) {
    return (unsigned)bf16_of(a) | ((unsigned)bf16_of(b) << 16);
}
__device__ __forceinline__ float2 bf16unpack(unsigned u) {
    float2 r;
    r.x = __uint_as_float(u << 16);
    r.y = __uint_as_float(u & 0xffff0000u);
    return r;
}

// ---------------- degree / CSR build ----------------

__global__ __launch_bounds__(256) void deg_count_kernel(const int* __restrict__ dst,
                                                        int* __restrict__ cnt, int E) {
    int e = blockIdx.x * blockDim.x + threadIdx.x;
    if (e < E) atomicAdd(&cnt[dst[e]], 1);
}

__global__ __launch_bounds__(256) void deg_fin_kernel(const int* __restrict__ cnt,
                                                      float* __restrict__ isq,
                                                      float* __restrict__ dinv, int n) {
    int i = blockIdx.x * blockDim.x + threadIdx.x;
    if (i < n) {
        float d = (float)cnt[i] + 1.0f;  // +1 self loop
        isq[i] = rsqrtf(d);
        dinv[i] = 1.0f / d;
    }
}

__global__ __launch_bounds__(256) void scanA_kernel(const int* __restrict__ cnt,
                                                    int* __restrict__ bsums, int n) {
    __shared__ int sh[256];
    int t = threadIdx.x;
    int base = blockIdx.x * 2048 + t * 8;
    int s = 0;
    for (int j = 0; j < 8; ++j) {
        int i = base + j;
        if (i < n) s += cnt[i];
    }
    sh[t] = s;
    __syncthreads();
    for (int off = 128; off > 0; off >>= 1) {
        if (t < off) sh[t] += sh[t + off];
        __syncthreads();
    }
    if (t == 0) bsums[blockIdx.x] = sh[0];
}

__global__ void scanB_kernel(int* __restrict__ bsums, int nb, int* __restrict__ row_off) {
    if (threadIdx.x == 0 && blockIdx.x == 0) {
        int c = 0;
        for (int i = 0; i < nb; ++i) {
            int v = bsums[i];
            bsums[i] = c;
            c += v;
        }
        row_off[0] = 0;
    }
}

__global__ __launch_bounds__(256) void scanC_kernel(const int* __restrict__ cnt,
                                                    const int* __restrict__ bsums,
                                                    int* __restrict__ row_off, int n) {
    __shared__ int sh[256];
    int t = threadIdx.x;
    int base = blockIdx.x * 2048 + t * 8;
    int v[8];
    int s = 0;
    for (int j = 0; j < 8; ++j) {
        int i = base + j;
        int x = (i < n) ? cnt[i] : 0;
        s += x;
        v[j] = s;
    }
    sh[t] = s;
    __syncthreads();
    for (int off = 1; off < 256; off <<= 1) {
        int x = (t >= off) ? sh[t - off] : 0;
        __syncthreads();
        sh[t] += x;
        __syncthreads();
    }
    int threadExcl = sh[t] - s;
    int off0 = bsums[blockIdx.x] + threadExcl;
    for (int j = 0; j < 8; ++j) {
        int i = base + j;
        if (i < n) row_off[i + 1] = off0 + v[j];
    }
}

// fused (src, norm) record: one scattered 8B store per edge instead of two 4B
__global__ __launch_bounds__(256) void fill_edges_kernel(const int* __restrict__ src,
                                                         const int* __restrict__ dst,
                                                         const int* __restrict__ row_off,
                                                         int* __restrict__ cursor,
                                                         const float* __restrict__ isq,
                                                         uint2* __restrict__ edges, int E) {
    int e = blockIdx.x * blockDim.x + threadIdx.x;
    if (e >= E) return;
    int s = src[e];
    int d = dst[e];
    int p = atomicAdd(&cursor[d], 1);
    int idx = row_off[d] + p;
    edges[idx] = make_uint2((unsigned)s, __float_as_uint(isq[s] * isq[d]));
}

// ---------------- weight split: W[K][FOUT] -> bf16 hi/lo, transposed [FOUT][128] ----------------

__global__ __launch_bounds__(256) void wconv_kernel(const float* __restrict__ W, int FOUT,
                                                    unsigned short* __restrict__ whiT,
                                                    unsigned short* __restrict__ wloT) {
    int idx = blockIdx.x * blockDim.x + threadIdx.x;
    if (idx >= 128 * FOUT) return;
    int k = idx / FOUT;
    int n = idx % FOUT;
    float w = W[idx];
    unsigned short h = bf16_of(w);
    whiT[(size_t)n * 128 + k] = h;
    wloT[(size_t)n * 128 + k] = bf16_of(w - f_of(h));
}

// ---------------- MFMA GEMM (split-bf16, LDS-free): Yb = pack_bf16(X @ W) ----------------
// block = 4 waves; wave handles 16 rows x FOUT cols. A frag: m=lane&15, k=quad*8+j.
// B frag from transposed weights: n=lane&15, k=quad*8+j (16B contiguous load).
// C/D: col=lane&15, row=quad*4+reg  [m89-verified layout].

template <int FOUT>
__global__ __launch_bounds__(256) void gemm_mfma_kernel(const float* __restrict__ X,
                                                        const unsigned short* __restrict__ whiT,
                                                        const unsigned short* __restrict__ wloT,
                                                        unsigned* __restrict__ Yb, int nrows) {
    constexpr int NT = FOUT / 16;
    int lane = threadIdx.x & 63;
    int wave = threadIdx.x >> 6;
    int quad = lane >> 4;
    int l16 = lane & 15;
    int rowBase = blockIdx.x * 64 + wave * 16;

    f32x4 acc[NT];
#pragma unroll
    for (int t = 0; t < NT; ++t) acc[t] = (f32x4){0.f, 0.f, 0.f, 0.f};

    int arow = rowBase + l16;
    bool aok = arow < nrows;
    const float* xrow = X + (size_t)arow * 128;

#pragma unroll
    for (int k0 = 0; k0 < 128; k0 += 32) {
        float xv[8];
        if (aok) {
            float4 v0 = *(const float4*)(xrow + k0 + quad * 8);
            float4 v1 = *(const float4*)(xrow + k0 + quad * 8 + 4);
            xv[0] = v0.x; xv[1] = v0.y; xv[2] = v0.z; xv[3] = v0.w;
            xv[4] = v1.x; xv[5] = v1.y; xv[6] = v1.z; xv[7] = v1.w;
        } else {
#pragma unroll
            for (int j = 0; j < 8; ++j) xv[j] = 0.f;
        }
        short8 ahi, alo;
#pragma unroll
        for (int j = 0; j < 8; ++j) {
            unsigned short h = bf16_of(xv[j]);
            ahi[j] = (short)h;
            alo[j] = (short)bf16_of(xv[j] - f_of(h));
        }
#pragma unroll
        for (int t = 0; t < NT; ++t) {
            size_t off = (size_t)(t * 16 + l16) * 128 + k0 + quad * 8;
            short8 bhi = *(const short8*)(whiT + off);
            short8 blo = *(const short8*)(wloT + off);
            acc[t] = __builtin_amdgcn_mfma_f32_16x16x32_bf16(ahi, bhi, acc[t], 0, 0, 0);
            acc[t] = __builtin_amdgcn_mfma_f32_16x16x32_bf16(alo, bhi, acc[t], 0, 0, 0);
            acc[t] = __builtin_amdgcn_mfma_f32_16x16x32_bf16(ahi, blo, acc[t], 0, 0, 0);
        }
    }

    // epilogue: pack bf16 pairs (adjacent cols live in adjacent lanes -> shfl_xor 1)
#pragma unroll
    for (int t = 0; t < NT; ++t) {
        int col = t * 16 + l16;
#pragma unroll
        for (int i = 0; i < 4; ++i) {
            int r = rowBase + quad * 4 + i;
            float v = acc[t][i];
            float nb = __shfl_xor(v, 1, 64);
            if (((lane & 1) == 0) && r < nrows)
                Yb[(size_t)r * (FOUT / 2) + (col >> 1)] = bf16pair(v, nb);
        }
    }
}

// ---------------- edge aggregation (F=128): bf16 gather, fp32 accumulate ----------------

__global__ __launch_bounds__(256) void agg128_kernel(const unsigned* __restrict__ xlb,
                                                     const int* __restrict__ row_off,
                                                     const uint2* __restrict__ edges,
                                                     const float* __restrict__ dinv,
                                                     const float* __restrict__ bias,
                                                     float* __restrict__ out, int nnodes) {
    int wave = (blockIdx.x * blockDim.x + threadIdx.x) >> 6;
    int lane = threadIdx.x & 63;
    if (wave >= nnodes) return;
    int e0 = row_off[wave], e1 = row_off[wave + 1];
    float ax = 0.f, ay = 0.f;
    int e = e0;
    for (; e + 8 <= e1; e += 8) {
        uint2 ed[8];
#pragma unroll
        for (int j = 0; j < 8; ++j) ed[j] = edges[e + j];
        unsigned v[8];
#pragma unroll
        for (int j = 0; j < 8; ++j) v[j] = xlb[(size_t)ed[j].x * 64 + lane];
#pragma unroll
        for (int j = 0; j < 8; ++j) {
            float nw = __uint_as_float(ed[j].y);
            float2 f = bf16unpack(v[j]);
            ax += nw * f.x;
            ay += nw * f.y;
        }
    }
    for (; e < e1; ++e) {
        uint2 ed = edges[e];
        float nw = __uint_as_float(ed.y);
        float2 f = bf16unpack(xlb[(size_t)ed.x * 64 + lane]);
        ax += nw * f.x;
        ay += nw * f.y;
    }
    float di = dinv[wave];
    float2 pi = bf16unpack(xlb[(size_t)wave * 64 + lane]);
    float2 bb = *(const float2*)(bias + lane * 2);
    float2 o;
    o.x = gelu_f(ax + di * pi.x + bb.x);
    o.y = gelu_f(ay + di * pi.y + bb.y);
    *(float2*)(out + (size_t)wave * 128 + lane * 2) = o;
}

// ---------------- edge aggregation (F=64): half-wave per edge ----------------

__global__ __launch_bounds__(256) void agg64_kernel(const unsigned* __restrict__ xlb,
                                                    const int* __restrict__ row_off,
                                                    const uint2* __restrict__ edges,
                                                    const float* __restrict__ dinv,
                                                    const float* __restrict__ bias,
                                                    float* __restrict__ out, int nnodes) {
    int wave = (blockIdx.x * blockDim.x + threadIdx.x) >> 6;
    int lane = threadIdx.x & 63;
    int sub = lane >> 5;
    int sl = lane & 31;
    if (wave >= nnodes) return;
    int e0 = row_off[wave], e1 = row_off[wave + 1];
    float ax = 0.f, ay = 0.f;
    int e = e0;
    for (; e + 8 <= e1; e += 8) {
        uint2 ed[4];
#pragma unroll
        for (int j = 0; j < 4; ++j) ed[j] = edges[e + 2 * j + sub];
        unsigned v[4];
#pragma unroll
        for (int j = 0; j < 4; ++j) v[j] = xlb[(size_t)ed[j].x * 32 + sl];
#pragma unroll
        for (int j = 0; j < 4; ++j) {
            float nw = __uint_as_float(ed[j].y);
            float2 f = bf16unpack(v[j]);
            ax += nw * f.x;
            ay += nw * f.y;
        }
    }
    for (; e + 2 <= e1; e += 2) {
        uint2 ed = edges[e + sub];
        float nw = __uint_as_float(ed.y);
        float2 f = bf16unpack(xlb[(size_t)ed.x * 32 + sl]);
        ax += nw * f.x;
        ay += nw * f.y;
    }
    if (e < e1 && sub == 0) {
        uint2 ed = edges[e];
        float nw = __uint_as_float(ed.y);
        float2 f = bf16unpack(xlb[(size_t)ed.x * 32 + sl]);
        ax += nw * f.x;
        ay += nw * f.y;
    }
    ax += __shfl_xor(ax, 32, 64);
    ay += __shfl_xor(ay, 32, 64);
    if (sub == 0) {
        float di = dinv[wave];
        float2 pi = bf16unpack(xlb[(size_t)wave * 32 + sl]);
        float2 bb = *(const float2*)(bias + sl * 2);
        float2 o;
        o.x = gelu_f(ax + di * pi.x + bb.x);
        o.y = gelu_f(ay + di * pi.y + bb.y);
        *(float2*)(out + (size_t)wave * 64 + sl * 2) = o;
    }
}

// ---------------- mean pool (batch sorted) ----------------

#define POOL_CHUNK 64

__global__ __launch_bounds__(256) void pool_kernel(const float* __restrict__ h,
                                                   const int* __restrict__ batch,
                                                   float* __restrict__ psum,
                                                   float* __restrict__ pcnt, int nnodes) {
    int wave = (blockIdx.x * blockDim.x + threadIdx.x) >> 6;
    int lane = threadIdx.x & 63;
    int n0 = wave * POOL_CHUNK;
    if (n0 >= nnodes) return;
    int n1 = n0 + POOL_CHUNK;
    if (n1 > nnodes) n1 = nnodes;

    int g_cur = batch[n0];
    float acc = 0.f;
    int cnt = 0;
    for (int node = n0; node < n1; ++node) {
        int g = batch[node];
        if (g != g_cur) {
            atomicAdd(&psum[g_cur * TDIM + lane], acc);
            if (lane == 0) atomicAdd(&pcnt[g_cur], (float)cnt);
            acc = 0.f;
            cnt = 0;
            g_cur = g;
        }
        acc += h[(size_t)node * TDIM + lane];
        ++cnt;
    }
    atomicAdd(&psum[g_cur * TDIM + lane], acc);
    if (lane == 0) atomicAdd(&pcnt[g_cur], (float)cnt);
}

__global__ __launch_bounds__(256) void fin_kernel(const float* __restrict__ psum,
                                                  const float* __restrict__ pcnt,
                                                  float* __restrict__ out) {
    int i = blockIdx.x * blockDim.x + threadIdx.x;
    if (i < NGRAPH * TDIM) {
        float c = pcnt[i >> 6];
        out[i] = psum[i] / fmaxf(c, 1.0f);
    }
}

// ---------------- launch ----------------

extern "C" void kernel_launch(void* const* d_in, const int* in_sizes, int n_in,
                              void* d_out, int out_size, void* d_ws, size_t ws_size,
                              hipStream_t stream) {
    const float* x = (const float*)d_in[0];
    const int* ei = (const int*)d_in[1];
    const int* batch = (const int*)d_in[2];
    const float* W0 = (const float*)d_in[3];
    const float* b0 = (const float*)d_in[4];
    const float* W1 = (const float*)d_in[5];
    const float* b1 = (const float*)d_in[6];
    const float* W2 = (const float*)d_in[7];
    const float* b2 = (const float*)d_in[8];

    const int N = in_sizes[0] / F_IN;
    const int E = in_sizes[1] / 2;
    const int* src = ei;
    const int* dst = ei + E;

    char* w = (char*)d_ws;
    auto alloc = [&](size_t bytes) -> void* {
        void* p = (void*)w;
        w += (bytes + 255) & ~(size_t)255;
        return p;
    };
    float* isq = (float*)alloc((size_t)N * 4);
    float* dinv = (float*)alloc((size_t)N * 4);
    int* cnt = (int*)alloc((size_t)N * 4);
    int* cursor = (int*)alloc((size_t)N * 4);
    int* row_off = (int*)alloc((size_t)(N + 1) * 4);
    int* bsums = (int*)alloc(256 * 4);
    uint2* edges = (uint2*)alloc((size_t)E * 8);
    float* psum = (float*)alloc((size_t)NGRAPH * TDIM * 4);
    float* pcnt = (float*)alloc((size_t)NGRAPH * 4);
    float* bufH = (float*)alloc((size_t)N * 128 * 4);       // fp32 post-agg activations
    unsigned* bufXb = (unsigned*)alloc((size_t)N * 64 * 4); // packed bf16 xl
    unsigned short* whiT0 = (unsigned short*)alloc(128 * 128 * 2);
    unsigned short* wloT0 = (unsigned short*)alloc(128 * 128 * 2);
    unsigned short* whiT1 = (unsigned short*)alloc(128 * 128 * 2);
    unsigned short* wloT1 = (unsigned short*)alloc(128 * 128 * 2);
    unsigned short* whiT2 = (unsigned short*)alloc(64 * 128 * 2);
    unsigned short* wloT2 = (unsigned short*)alloc(64 * 128 * 2);

    hipMemsetAsync(cnt, 0, (size_t)N * 4, stream);
    hipMemsetAsync(cursor, 0, (size_t)N * 4, stream);
    hipMemsetAsync(psum, 0, (size_t)NGRAPH * TDIM * 4, stream);
    hipMemsetAsync(pcnt, 0, (size_t)NGRAPH * 4, stream);

    const int tb = 256;
    deg_count_kernel<<<(E + tb - 1) / tb, tb, 0, stream>>>(dst, cnt, E);
    deg_fin_kernel<<<(N + tb - 1) / tb, tb, 0, stream>>>(cnt, isq, dinv, N);

    int nchunk = (N + 2047) / 2048;
    scanA_kernel<<<nchunk, 256, 0, stream>>>(cnt, bsums, N);
    scanB_kernel<<<1, 64, 0, stream>>>(bsums, nchunk, row_off);
    scanC_kernel<<<nchunk, 256, 0, stream>>>(cnt, bsums, row_off, N);
    fill_edges_kernel<<<(E + tb - 1) / tb, tb, 0, stream>>>(src, dst, row_off, cursor, isq,
                                                            edges, E);

    // weight conversion (tiny)
    wconv_kernel<<<(128 * 128 + 255) / 256, 256, 0, stream>>>(W0, 128, whiT0, wloT0);
    wconv_kernel<<<(128 * 128 + 255) / 256, 256, 0, stream>>>(W1, 128, whiT1, wloT1);
    wconv_kernel<<<(128 * 64 + 255) / 256, 256, 0, stream>>>(W2, 64, whiT2, wloT2);

    int gblocks = (N + 63) / 64;
    int ablocks = (N * 64 + 255) / 256;

    // layer 0
    gemm_mfma_kernel<128><<<gblocks, 256, 0, stream>>>(x, whiT0, wloT0, bufXb, N);
    agg128_kernel<<<ablocks, 256, 0, stream>>>(bufXb, row_off, edges, dinv, b0, bufH, N);
    // layer 1
    gemm_mfma_kernel<128><<<gblocks, 256, 0, stream>>>(bufH, whiT1, wloT1, bufXb, N);
    agg128_kernel<<<ablocks, 256, 0, stream>>>(bufXb, row_off, edges, dinv, b1, bufH, N);
    // layer 2 (Fout = 64)
    gemm_mfma_kernel<64><<<gblocks, 256, 0, stream>>>(bufH, whiT2, wloT2, bufXb, N);
    agg64_kernel<<<ablocks, 256, 0, stream>>>(bufXb, row_off, edges, dinv, b2, bufH, N);

    // pool
    int pwaves = (N + POOL_CHUNK - 1) / POOL_CHUNK;
    int pblocks = (pwaves * 64 + 255) / 256;
    pool_kernel<<<pblocks, 256, 0, stream>>>(bufH, batch, psum, pcnt, N);
    fin_kernel<<<(NGRAPH * TDIM + 255) / 256, 256, 0, stream>>>(psum, pcnt, (float*)d_out);
}

// Round 7
// 587.107 us; speedup vs baseline: 1.3222x; 1.1512x over previous
//
#include <hip/hip_runtime.h>
#include <math.h>

#define F_IN 128
#define TDIM 64
#define NGRAPH 256

typedef __attribute__((ext_vector_type(8))) short short8;
typedef __attribute__((ext_vector_type(4))) float f32x4;

__device__ __forceinline__ float gelu_f(float x) {
    float x3 = x * x * x;
    return 0.5f * x * (1.0f + tanhf(0.7978845608028654f * (x + 0.044715f * x3)));
}

// fp32 <-> bf16 bit helpers (RNE)
__device__ __forceinline__ unsigned short bf16_of(float x) {
    unsigned u = __float_as_uint(x);
    return (unsigned short)((u + 0x7fffu + ((u >> 16) & 1u)) >> 16);
}
__device__ __forceinline__ float f_of(unsigned short h) {
    return __uint_as_float(((unsigned)h) << 16);
}
__device__ __forceinline__ unsigned bf16pair(float a, float b) {
    return (unsigned)bf16_of(a) | ((unsigned)bf16_of(b) << 16);
}
__device__ __forceinline__ float2 bf16unpack(unsigned u) {
    float2 r;
    r.x = __uint_as_float(u << 16);
    r.y = __uint_as_float(u & 0xffff0000u);
    return r;
}

// ---------------- degree / CSR build ----------------

__global__ __launch_bounds__(256) void deg_count_kernel(const int* __restrict__ dst,
                                                        int* __restrict__ cnt, int E) {
    int e = blockIdx.x * blockDim.x + threadIdx.x;
    if (e < E) atomicAdd(&cnt[dst[e]], 1);
}

__global__ __launch_bounds__(256) void deg_fin_kernel(const int* __restrict__ cnt,
                                                      float* __restrict__ isq,
                                                      float* __restrict__ dinv, int n) {
    int i = blockIdx.x * blockDim.x + threadIdx.x;
    if (i < n) {
        float d = (float)cnt[i] + 1.0f;  // +1 self loop
        isq[i] = rsqrtf(d);
        dinv[i] = 1.0f / d;
    }
}

__global__ __launch_bounds__(256) void scanA_kernel(const int* __restrict__ cnt,
                                                    int* __restrict__ bsums, int n) {
    __shared__ int sh[256];
    int t = threadIdx.x;
    int base = blockIdx.x * 2048 + t * 8;
    int s = 0;
    for (int j = 0; j < 8; ++j) {
        int i = base + j;
        if (i < n) s += cnt[i];
    }
    sh[t] = s;
    __syncthreads();
    for (int off = 128; off > 0; off >>= 1) {
        if (t < off) sh[t] += sh[t + off];
        __syncthreads();
    }
    if (t == 0) bsums[blockIdx.x] = sh[0];
}

__global__ void scanB_kernel(int* __restrict__ bsums, int nb, int* __restrict__ row_off) {
    if (threadIdx.x == 0 && blockIdx.x == 0) {
        int c = 0;
        for (int i = 0; i < nb; ++i) {
            int v = bsums[i];
            bsums[i] = c;
            c += v;
        }
        row_off[0] = 0;
    }
}

__global__ __launch_bounds__(256) void scanC_kernel(const int* __restrict__ cnt,
                                                    const int* __restrict__ bsums,
                                                    int* __restrict__ row_off, int n) {
    __shared__ int sh[256];
    int t = threadIdx.x;
    int base = blockIdx.x * 2048 + t * 8;
    int v[8];
    int s = 0;
    for (int j = 0; j < 8; ++j) {
        int i = base + j;
        int x = (i < n) ? cnt[i] : 0;
        s += x;
        v[j] = s;
    }
    sh[t] = s;
    __syncthreads();
    for (int off = 1; off < 256; off <<= 1) {
        int x = (t >= off) ? sh[t - off] : 0;
        __syncthreads();
        sh[t] += x;
        __syncthreads();
    }
    int threadExcl = sh[t] - s;
    int off0 = bsums[blockIdx.x] + threadExcl;
    for (int j = 0; j < 8; ++j) {
        int i = base + j;
        if (i < n) row_off[i + 1] = off0 + v[j];
    }
}

__global__ __launch_bounds__(256) void fill_edges_kernel(const int* __restrict__ src,
                                                         const int* __restrict__ dst,
                                                         const int* __restrict__ row_off,
                                                         int* __restrict__ cursor,
                                                         const float* __restrict__ isq,
                                                         uint2* __restrict__ edges, int E) {
    int e = blockIdx.x * blockDim.x + threadIdx.x;
    if (e >= E) return;
    int s = src[e];
    int d = dst[e];
    int p = atomicAdd(&cursor[d], 1);
    int idx = row_off[d] + p;
    edges[idx] = make_uint2((unsigned)s, __float_as_uint(isq[s] * isq[d]));
}

// ---------------- weight split: W[K][FOUT] -> bf16 hi/lo, transposed [FOUT][128] ----------------

__global__ __launch_bounds__(256) void wconv_kernel(const float* __restrict__ W, int FOUT,
                                                    unsigned short* __restrict__ whiT,
                                                    unsigned short* __restrict__ wloT) {
    int idx = blockIdx.x * blockDim.x + threadIdx.x;
    if (idx >= 128 * FOUT) return;
    int k = idx / FOUT;
    int n = idx % FOUT;
    float w = W[idx];
    unsigned short h = bf16_of(w);
    whiT[(size_t)n * 128 + k] = h;
    wloT[(size_t)n * 128 + k] = bf16_of(w - f_of(h));
}

// ---------------- MFMA GEMM (split-bf16, weights in LDS): Yb = pack_bf16(X @ W) ----------------
// block = 4 waves x 32 rows = 128 rows. Weights staged to LDS once (row pad +16B,
// reads are 2-way bank aliasing = free). B-frag: ds_read_b128. 3 MFMAs per tile
// (hi*hi, lo*hi, hi*lo) keep the GEMM near-fp32-exact. C/D: col=lane&15, row=quad*4+reg.

#define LROW 136  // LDS row stride in shorts (272 B = 256 + 16 pad)

template <int FOUT>
__global__ __launch_bounds__(256) void gemm_mfma_kernel(const float* __restrict__ X,
                                                        const unsigned short* __restrict__ whiT,
                                                        const unsigned short* __restrict__ wloT,
                                                        unsigned* __restrict__ Yb, int nrows) {
    constexpr int NT = FOUT / 16;
    __shared__ short lds[2 * FOUT * LROW];
    short* shi = lds;
    short* slo = lds + FOUT * LROW;

    // stage weights (coalesced 16B chunks)
    for (int c = threadIdx.x; c < FOUT * 16; c += 256) {
        int n = c >> 4, r = c & 15;
        *(short8*)(shi + n * LROW + r * 8) = *(const short8*)(whiT + (size_t)n * 128 + r * 8);
        *(short8*)(slo + n * LROW + r * 8) = *(const short8*)(wloT + (size_t)n * 128 + r * 8);
    }
    __syncthreads();

    int lane = threadIdx.x & 63;
    int wave = threadIdx.x >> 6;
    int quad = lane >> 4;
    int l16 = lane & 15;
    int rowBase = blockIdx.x * 128 + wave * 32;

    f32x4 acc[2][NT];
#pragma unroll
    for (int m = 0; m < 2; ++m)
#pragma unroll
        for (int t = 0; t < NT; ++t) acc[m][t] = (f32x4){0.f, 0.f, 0.f, 0.f};

    int arow0 = rowBase + l16;
    int arow1 = rowBase + 16 + l16;
    bool ok0 = arow0 < nrows, ok1 = arow1 < nrows;
    const float* xr0 = X + (size_t)arow0 * 128;
    const float* xr1 = X + (size_t)arow1 * 128;

#pragma unroll
    for (int k0 = 0; k0 < 128; k0 += 32) {
        short8 ahi[2], alo[2];
#pragma unroll
        for (int m = 0; m < 2; ++m) {
            const float* xr = m ? xr1 : xr0;
            bool ok = m ? ok1 : ok0;
            float xv[8];
            if (ok) {
                float4 v0 = *(const float4*)(xr + k0 + quad * 8);
                float4 v1 = *(const float4*)(xr + k0 + quad * 8 + 4);
                xv[0] = v0.x; xv[1] = v0.y; xv[2] = v0.z; xv[3] = v0.w;
                xv[4] = v1.x; xv[5] = v1.y; xv[6] = v1.z; xv[7] = v1.w;
            } else {
#pragma unroll
                for (int j = 0; j < 8; ++j) xv[j] = 0.f;
            }
#pragma unroll
            for (int j = 0; j < 8; ++j) {
                unsigned short h = bf16_of(xv[j]);
                ahi[m][j] = (short)h;
                alo[m][j] = (short)bf16_of(xv[j] - f_of(h));
            }
        }
#pragma unroll
        for (int t = 0; t < NT; ++t) {
            int off = (t * 16 + l16) * LROW + k0 + quad * 8;
            short8 bhi = *(const short8*)(shi + off);
            short8 blo = *(const short8*)(slo + off);
#pragma unroll
            for (int m = 0; m < 2; ++m) {
                acc[m][t] = __builtin_amdgcn_mfma_f32_16x16x32_bf16(ahi[m], bhi, acc[m][t], 0, 0, 0);
                acc[m][t] = __builtin_amdgcn_mfma_f32_16x16x32_bf16(alo[m], bhi, acc[m][t], 0, 0, 0);
                acc[m][t] = __builtin_amdgcn_mfma_f32_16x16x32_bf16(ahi[m], blo, acc[m][t], 0, 0, 0);
            }
        }
    }

    // epilogue: pack bf16 pairs (adjacent cols in adjacent lanes -> shfl_xor 1)
#pragma unroll
    for (int m = 0; m < 2; ++m) {
        int col0 = l16;
#pragma unroll
        for (int t = 0; t < NT; ++t) {
            int col = t * 16 + col0;
#pragma unroll
            for (int i = 0; i < 4; ++i) {
                int r = rowBase + m * 16 + quad * 4 + i;
                float v = acc[m][t][i];
                float nb = __shfl_xor(v, 1, 64);
                if (((lane & 1) == 0) && r < nrows)
                    Yb[(size_t)r * (FOUT / 2) + (col >> 1)] = bf16pair(v, nb);
            }
        }
    }
}

// ---------------- edge aggregation (F=128): bf16 gather, fp32 accumulate ----------------

__global__ __launch_bounds__(256) void agg128_kernel(const unsigned* __restrict__ xlb,
                                                     const int* __restrict__ row_off,
                                                     const uint2* __restrict__ edges,
                                                     const float* __restrict__ dinv,
                                                     const float* __restrict__ bias,
                                                     float* __restrict__ out, int nnodes) {
    int wave = (blockIdx.x * blockDim.x + threadIdx.x) >> 6;
    int lane = threadIdx.x & 63;
    if (wave >= nnodes) return;
    int e0 = row_off[wave], e1 = row_off[wave + 1];
    float ax = 0.f, ay = 0.f;
    int e = e0;
    for (; e + 8 <= e1; e += 8) {
        uint2 ed[8];
#pragma unroll
        for (int j = 0; j < 8; ++j) ed[j] = edges[e + j];
        unsigned v[8];
#pragma unroll
        for (int j = 0; j < 8; ++j) v[j] = xlb[(size_t)ed[j].x * 64 + lane];
#pragma unroll
        for (int j = 0; j < 8; ++j) {
            float nw = __uint_as_float(ed[j].y);
            float2 f = bf16unpack(v[j]);
            ax += nw * f.x;
            ay += nw * f.y;
        }
    }
    for (; e < e1; ++e) {
        uint2 ed = edges[e];
        float nw = __uint_as_float(ed.y);
        float2 f = bf16unpack(xlb[(size_t)ed.x * 64 + lane]);
        ax += nw * f.x;
        ay += nw * f.y;
    }
    float di = dinv[wave];
    float2 pi = bf16unpack(xlb[(size_t)wave * 64 + lane]);
    float2 bb = *(const float2*)(bias + lane * 2);
    float2 o;
    o.x = gelu_f(ax + di * pi.x + bb.x);
    o.y = gelu_f(ay + di * pi.y + bb.y);
    *(float2*)(out + (size_t)wave * 128 + lane * 2) = o;
}

// ---------------- edge aggregation (F=64): half-wave per edge ----------------

__global__ __launch_bounds__(256) void agg64_kernel(const unsigned* __restrict__ xlb,
                                                    const int* __restrict__ row_off,
                                                    const uint2* __restrict__ edges,
                                                    const float* __restrict__ dinv,
                                                    const float* __restrict__ bias,
                                                    float* __restrict__ out, int nnodes) {
    int wave = (blockIdx.x * blockDim.x + threadIdx.x) >> 6;
    int lane = threadIdx.x & 63;
    int sub = lane >> 5;
    int sl = lane & 31;
    if (wave >= nnodes) return;
    int e0 = row_off[wave], e1 = row_off[wave + 1];
    float ax = 0.f, ay = 0.f;
    int e = e0;
    for (; e + 8 <= e1; e += 8) {
        uint2 ed[4];
#pragma unroll
        for (int j = 0; j < 4; ++j) ed[j] = edges[e + 2 * j + sub];
        unsigned v[4];
#pragma unroll
        for (int j = 0; j < 4; ++j) v[j] = xlb[(size_t)ed[j].x * 32 + sl];
#pragma unroll
        for (int j = 0; j < 4; ++j) {
            float nw = __uint_as_float(ed[j].y);
            float2 f = bf16unpack(v[j]);
            ax += nw * f.x;
            ay += nw * f.y;
        }
    }
    for (; e + 2 <= e1; e += 2) {
        uint2 ed = edges[e + sub];
        float nw = __uint_as_float(ed.y);
        float2 f = bf16unpack(xlb[(size_t)ed.x * 32 + sl]);
        ax += nw * f.x;
        ay += nw * f.y;
    }
    if (e < e1 && sub == 0) {
        uint2 ed = edges[e];
        float nw = __uint_as_float(ed.y);
        float2 f = bf16unpack(xlb[(size_t)ed.x * 32 + sl]);
        ax += nw * f.x;
        ay += nw * f.y;
    }
    ax += __shfl_xor(ax, 32, 64);
    ay += __shfl_xor(ay, 32, 64);
    if (sub == 0) {
        float di = dinv[wave];
        float2 pi = bf16unpack(xlb[(size_t)wave * 32 + sl]);
        float2 bb = *(const float2*)(bias + sl * 2);
        float2 o;
        o.x = gelu_f(ax + di * pi.x + bb.x);
        o.y = gelu_f(ay + di * pi.y + bb.y);
        *(float2*)(out + (size_t)wave * 64 + sl * 2) = o;
    }
}

// ---------------- mean pool (batch sorted) ----------------

#define POOL_CHUNK 64

__global__ __launch_bounds__(256) void pool_kernel(const float* __restrict__ h,
                                                   const int* __restrict__ batch,
                                                   float* __restrict__ psum,
                                                   float* __restrict__ pcnt, int nnodes) {
    int wave = (blockIdx.x * blockDim.x + threadIdx.x) >> 6;
    int lane = threadIdx.x & 63;
    int n0 = wave * POOL_CHUNK;
    if (n0 >= nnodes) return;
    int n1 = n0 + POOL_CHUNK;
    if (n1 > nnodes) n1 = nnodes;

    int g_cur = batch[n0];
    float acc = 0.f;
    int cnt = 0;
    for (int node = n0; node < n1; ++node) {
        int g = batch[node];
        if (g != g_cur) {
            atomicAdd(&psum[g_cur * TDIM + lane], acc);
            if (lane == 0) atomicAdd(&pcnt[g_cur], (float)cnt);
            acc = 0.f;
            cnt = 0;
            g_cur = g;
        }
        acc += h[(size_t)node * TDIM + lane];
        ++cnt;
    }
    atomicAdd(&psum[g_cur * TDIM + lane], acc);
    if (lane == 0) atomicAdd(&pcnt[g_cur], (float)cnt);
}

__global__ __launch_bounds__(256) void fin_kernel(const float* __restrict__ psum,
                                                  const float* __restrict__ pcnt,
                                                  float* __restrict__ out) {
    int i = blockIdx.x * blockDim.x + threadIdx.x;
    if (i < NGRAPH * TDIM) {
        float c = pcnt[i >> 6];
        out[i] = psum[i] / fmaxf(c, 1.0f);
    }
}

// ---------------- launch ----------------

extern "C" void kernel_launch(void* const* d_in, const int* in_sizes, int n_in,
                              void* d_out, int out_size, void* d_ws, size_t ws_size,
                              hipStream_t stream) {
    const float* x = (const float*)d_in[0];
    const int* ei = (const int*)d_in[1];
    const int* batch = (const int*)d_in[2];
    const float* W0 = (const float*)d_in[3];
    const float* b0 = (const float*)d_in[4];
    const float* W1 = (const float*)d_in[5];
    const float* b1 = (const float*)d_in[6];
    const float* W2 = (const float*)d_in[7];
    const float* b2 = (const float*)d_in[8];

    const int N = in_sizes[0] / F_IN;
    const int E = in_sizes[1] / 2;
    const int* src = ei;
    const int* dst = ei + E;

    char* w = (char*)d_ws;
    auto alloc = [&](size_t bytes) -> void* {
        void* p = (void*)w;
        w += (bytes + 255) & ~(size_t)255;
        return p;
    };
    float* isq = (float*)alloc((size_t)N * 4);
    float* dinv = (float*)alloc((size_t)N * 4);
    int* cnt = (int*)alloc((size_t)N * 4);
    int* cursor = (int*)alloc((size_t)N * 4);
    int* row_off = (int*)alloc((size_t)(N + 1) * 4);
    int* bsums = (int*)alloc(256 * 4);
    uint2* edges = (uint2*)alloc((size_t)E * 8);
    float* psum = (float*)alloc((size_t)NGRAPH * TDIM * 4);
    float* pcnt = (float*)alloc((size_t)NGRAPH * 4);
    float* bufH = (float*)alloc((size_t)N * 128 * 4);
    unsigned* bufXb = (unsigned*)alloc((size_t)N * 64 * 4);
    unsigned short* whiT0 = (unsigned short*)alloc(128 * 128 * 2);
    unsigned short* wloT0 = (unsigned short*)alloc(128 * 128 * 2);
    unsigned short* whiT1 = (unsigned short*)alloc(128 * 128 * 2);
    unsigned short* wloT1 = (unsigned short*)alloc(128 * 128 * 2);
    unsigned short* whiT2 = (unsigned short*)alloc(64 * 128 * 2);
    unsigned short* wloT2 = (unsigned short*)alloc(64 * 128 * 2);

    hipMemsetAsync(cnt, 0, (size_t)N * 4, stream);
    hipMemsetAsync(cursor, 0, (size_t)N * 4, stream);
    hipMemsetAsync(psum, 0, (size_t)NGRAPH * TDIM * 4, stream);
    hipMemsetAsync(pcnt, 0, (size_t)NGRAPH * 4, stream);

    const int tb = 256;
    deg_count_kernel<<<(E + tb - 1) / tb, tb, 0, stream>>>(dst, cnt, E);
    deg_fin_kernel<<<(N + tb - 1) / tb, tb, 0, stream>>>(cnt, isq, dinv, N);

    int nchunk = (N + 2047) / 2048;
    scanA_kernel<<<nchunk, 256, 0, stream>>>(cnt, bsums, N);
    scanB_kernel<<<1, 64, 0, stream>>>(bsums, nchunk, row_off);
    scanC_kernel<<<nchunk, 256, 0, stream>>>(cnt, bsums, row_off, N);
    fill_edges_kernel<<<(E + tb - 1) / tb, tb, 0, stream>>>(src, dst, row_off, cursor, isq,
                                                            edges, E);

    wconv_kernel<<<(128 * 128 + 255) / 256, 256, 0, stream>>>(W0, 128, whiT0, wloT0);
    wconv_kernel<<<(128 * 128 + 255) / 256, 256, 0, stream>>>(W1, 128, whiT1, wloT1);
    wconv_kernel<<<(128 * 64 + 255) / 256, 256, 0, stream>>>(W2, 64, whiT2, wloT2);

    int gblocks = (N + 127) / 128;
    int ablocks = (N * 64 + 255) / 256;

    // layer 0
    gemm_mfma_kernel<128><<<gblocks, 256, 0, stream>>>(x, whiT0, wloT0, bufXb, N);
    agg128_kernel<<<ablocks, 256, 0, stream>>>(bufXb, row_off, edges, dinv, b0, bufH, N);
    // layer 1
    gemm_mfma_kernel<128><<<gblocks, 256, 0, stream>>>(bufH, whiT1, wloT1, bufXb, N);
    agg128_kernel<<<ablocks, 256, 0, stream>>>(bufXb, row_off, edges, dinv, b1, bufH, N);
    // layer 2 (Fout = 64)
    gemm_mfma_kernel<64><<<gblocks, 256, 0, stream>>>(bufH, whiT2, wloT2, bufXb, N);
    agg64_kernel<<<ablocks, 256, 0, stream>>>(bufXb, row_off, edges, dinv, b2, bufH, N);

    // pool
    int pwaves = (N + POOL_CHUNK - 1) / POOL_CHUNK;
    int pblocks = (pwaves * 64 + 255) / 256;
    pool_kernel<<<pblocks, 256, 0, stream>>>(bufH, batch, psum, pcnt, N);
    fin_kernel<<<(NGRAPH * TDIM + 255) / 256, 256, 0, stream>>>(psum, pcnt, (float*)d_out);
}

// Round 8
// 575.231 us; speedup vs baseline: 1.3495x; 1.0206x over previous
//
#include <hip/hip_runtime.h>
#include <math.h>

#define F_IN 128
#define TDIM 64
#define NGRAPH 256

typedef __attribute__((ext_vector_type(8))) short short8;
typedef __attribute__((ext_vector_type(4))) float f32x4;

__device__ __forceinline__ float gelu_f(float x) {
    float x3 = x * x * x;
    return 0.5f * x * (1.0f + tanhf(0.7978845608028654f * (x + 0.044715f * x3)));
}

// fp32 <-> bf16 bit helpers (RNE)
__device__ __forceinline__ unsigned short bf16_of(float x) {
    unsigned u = __float_as_uint(x);
    return (unsigned short)((u + 0x7fffu + ((u >> 16) & 1u)) >> 16);
}
__device__ __forceinline__ float f_of(unsigned short h) {
    return __uint_as_float(((unsigned)h) << 16);
}
__device__ __forceinline__ unsigned bf16pair(float a, float b) {
    return (unsigned)bf16_of(a) | ((unsigned)bf16_of(b) << 16);
}
__device__ __forceinline__ float2 bf16unpack(unsigned u) {
    float2 r;
    r.x = __uint_as_float(u << 16);
    r.y = __uint_as_float(u & 0xffff0000u);
    return r;
}

// ---------------- degree / CSR build ----------------

__global__ __launch_bounds__(256) void deg_count_kernel(const int* __restrict__ dst,
                                                        int* __restrict__ cnt, int E) {
    int e = blockIdx.x * blockDim.x + threadIdx.x;
    if (e < E) atomicAdd(&cnt[dst[e]], 1);
}

__global__ __launch_bounds__(256) void deg_fin_kernel(const int* __restrict__ cnt,
                                                      float* __restrict__ isq,
                                                      float* __restrict__ dinv, int n) {
    int i = blockIdx.x * blockDim.x + threadIdx.x;
    if (i < n) {
        float d = (float)cnt[i] + 1.0f;  // +1 self loop
        isq[i] = rsqrtf(d);
        dinv[i] = 1.0f / d;
    }
}

__global__ __launch_bounds__(256) void scanA_kernel(const int* __restrict__ cnt,
                                                    int* __restrict__ bsums, int n) {
    __shared__ int sh[256];
    int t = threadIdx.x;
    int base = blockIdx.x * 2048 + t * 8;
    int s = 0;
    for (int j = 0; j < 8; ++j) {
        int i = base + j;
        if (i < n) s += cnt[i];
    }
    sh[t] = s;
    __syncthreads();
    for (int off = 128; off > 0; off >>= 1) {
        if (t < off) sh[t] += sh[t + off];
        __syncthreads();
    }
    if (t == 0) bsums[blockIdx.x] = sh[0];
}

__global__ void scanB_kernel(int* __restrict__ bsums, int nb, int* __restrict__ row_off) {
    if (threadIdx.x == 0 && blockIdx.x == 0) {
        int c = 0;
        for (int i = 0; i < nb; ++i) {
            int v = bsums[i];
            bsums[i] = c;
            c += v;
        }
        row_off[0] = 0;
    }
}

__global__ __launch_bounds__(256) void scanC_kernel(const int* __restrict__ cnt,
                                                    const int* __restrict__ bsums,
                                                    int* __restrict__ row_off, int n) {
    __shared__ int sh[256];
    int t = threadIdx.x;
    int base = blockIdx.x * 2048 + t * 8;
    int v[8];
    int s = 0;
    for (int j = 0; j < 8; ++j) {
        int i = base + j;
        int x = (i < n) ? cnt[i] : 0;
        s += x;
        v[j] = s;
    }
    sh[t] = s;
    __syncthreads();
    for (int off = 1; off < 256; off <<= 1) {
        int x = (t >= off) ? sh[t - off] : 0;
        __syncthreads();
        sh[t] += x;
        __syncthreads();
    }
    int threadExcl = sh[t] - s;
    int off0 = bsums[blockIdx.x] + threadExcl;
    for (int j = 0; j < 8; ++j) {
        int i = base + j;
        if (i < n) row_off[i + 1] = off0 + v[j];
    }
}

// ---------------- edge scatter, XCD-sliced by dst range ----------------
// blockIdx % 8 -> dst-range slice; round-robin dispatch puts slice r on XCD r,
// so each XCD's scattered stores land in a ~1.6 MB L2-resident region and
// combine in L2 instead of costing a full-line HBM writeback per edge.

#define FB_CHUNK 2048

__global__ __launch_bounds__(256) void fill_edges_kernel(const int* __restrict__ src,
                                                         const int* __restrict__ dst,
                                                         const int* __restrict__ row_off,
                                                         int* __restrict__ cursor,
                                                         const float* __restrict__ isq,
                                                         uint2* __restrict__ edges, int E,
                                                         int N) {
    int r = blockIdx.x & 7;
    int chunk = blockIdx.x >> 3;
    int lo = (int)(((long long)N * r) >> 3);
    int hi = (int)(((long long)N * (r + 1)) >> 3);
    int base = chunk * FB_CHUNK;
    int end = base + FB_CHUNK;
    if (end > E) end = E;
    for (int e = base + threadIdx.x; e < end; e += 256) {
        int d = dst[e];
        if (d >= lo && d < hi) {
            int s = src[e];
            int p = atomicAdd(&cursor[d], 1);
            edges[row_off[d] + p] = make_uint2((unsigned)s, __float_as_uint(isq[s] * isq[d]));
        }
    }
}

// ---------------- weight split: W[K][FOUT] -> bf16 hi/lo, transposed [FOUT][128] ----------------

__global__ __launch_bounds__(256) void wconv_kernel(const float* __restrict__ W, int FOUT,
                                                    unsigned short* __restrict__ whiT,
                                                    unsigned short* __restrict__ wloT) {
    int idx = blockIdx.x * blockDim.x + threadIdx.x;
    if (idx >= 128 * FOUT) return;
    int k = idx / FOUT;
    int n = idx % FOUT;
    float w = W[idx];
    unsigned short h = bf16_of(w);
    whiT[(size_t)n * 128 + k] = h;
    wloT[(size_t)n * 128 + k] = bf16_of(w - f_of(h));
}

// ---------------- MFMA GEMM (split-bf16, weights in LDS): Yb = pack_bf16(X @ W) ----------------

#define LROW 136  // LDS row stride in shorts (272 B = 256 + 16 pad)

template <int FOUT>
__global__ __launch_bounds__(256) void gemm_mfma_kernel(const float* __restrict__ X,
                                                        const unsigned short* __restrict__ whiT,
                                                        const unsigned short* __restrict__ wloT,
                                                        unsigned* __restrict__ Yb, int nrows) {
    constexpr int NT = FOUT / 16;
    __shared__ short lds[2 * FOUT * LROW];
    short* shi = lds;
    short* slo = lds + FOUT * LROW;

    for (int c = threadIdx.x; c < FOUT * 16; c += 256) {
        int n = c >> 4, r = c & 15;
        *(short8*)(shi + n * LROW + r * 8) = *(const short8*)(whiT + (size_t)n * 128 + r * 8);
        *(short8*)(slo + n * LROW + r * 8) = *(const short8*)(wloT + (size_t)n * 128 + r * 8);
    }
    __syncthreads();

    int lane = threadIdx.x & 63;
    int wave = threadIdx.x >> 6;
    int quad = lane >> 4;
    int l16 = lane & 15;
    int rowBase = blockIdx.x * 128 + wave * 32;

    f32x4 acc[2][NT];
#pragma unroll
    for (int m = 0; m < 2; ++m)
#pragma unroll
        for (int t = 0; t < NT; ++t) acc[m][t] = (f32x4){0.f, 0.f, 0.f, 0.f};

    int arow0 = rowBase + l16;
    int arow1 = rowBase + 16 + l16;
    bool ok0 = arow0 < nrows, ok1 = arow1 < nrows;
    const float* xr0 = X + (size_t)arow0 * 128;
    const float* xr1 = X + (size_t)arow1 * 128;

#pragma unroll
    for (int k0 = 0; k0 < 128; k0 += 32) {
        short8 ahi[2], alo[2];
#pragma unroll
        for (int m = 0; m < 2; ++m) {
            const float* xr = m ? xr1 : xr0;
            bool ok = m ? ok1 : ok0;
            float xv[8];
            if (ok) {
                float4 v0 = *(const float4*)(xr + k0 + quad * 8);
                float4 v1 = *(const float4*)(xr + k0 + quad * 8 + 4);
                xv[0] = v0.x; xv[1] = v0.y; xv[2] = v0.z; xv[3] = v0.w;
                xv[4] = v1.x; xv[5] = v1.y; xv[6] = v1.z; xv[7] = v1.w;
            } else {
#pragma unroll
                for (int j = 0; j < 8; ++j) xv[j] = 0.f;
            }
#pragma unroll
            for (int j = 0; j < 8; ++j) {
                unsigned short h = bf16_of(xv[j]);
                ahi[m][j] = (short)h;
                alo[m][j] = (short)bf16_of(xv[j] - f_of(h));
            }
        }
#pragma unroll
        for (int t = 0; t < NT; ++t) {
            int off = (t * 16 + l16) * LROW + k0 + quad * 8;
            short8 bhi = *(const short8*)(shi + off);
            short8 blo = *(const short8*)(slo + off);
#pragma unroll
            for (int m = 0; m < 2; ++m) {
                acc[m][t] = __builtin_amdgcn_mfma_f32_16x16x32_bf16(ahi[m], bhi, acc[m][t], 0, 0, 0);
                acc[m][t] = __builtin_amdgcn_mfma_f32_16x16x32_bf16(alo[m], bhi, acc[m][t], 0, 0, 0);
                acc[m][t] = __builtin_amdgcn_mfma_f32_16x16x32_bf16(ahi[m], blo, acc[m][t], 0, 0, 0);
            }
        }
    }

#pragma unroll
    for (int m = 0; m < 2; ++m) {
#pragma unroll
        for (int t = 0; t < NT; ++t) {
            int col = t * 16 + l16;
#pragma unroll
            for (int i = 0; i < 4; ++i) {
                int r = rowBase + m * 16 + quad * 4 + i;
                float v = acc[m][t][i];
                float nb = __shfl_xor(v, 1, 64);
                if (((lane & 1) == 0) && r < nrows)
                    Yb[(size_t)r * (FOUT / 2) + (col >> 1)] = bf16pair(v, nb);
            }
        }
    }
}

// ---------------- edge aggregation (F=128): bf16 gather, fp32 accumulate ----------------

__global__ __launch_bounds__(256) void agg128_kernel(const unsigned* __restrict__ xlb,
                                                     const int* __restrict__ row_off,
                                                     const uint2* __restrict__ edges,
                                                     const float* __restrict__ dinv,
                                                     const float* __restrict__ bias,
                                                     float* __restrict__ out, int nnodes) {
    int wave = (blockIdx.x * blockDim.x + threadIdx.x) >> 6;
    int lane = threadIdx.x & 63;
    if (wave >= nnodes) return;
    int e0 = row_off[wave], e1 = row_off[wave + 1];
    float ax = 0.f, ay = 0.f;
    int e = e0;
    for (; e + 8 <= e1; e += 8) {
        uint2 ed[8];
#pragma unroll
        for (int j = 0; j < 8; ++j) ed[j] = edges[e + j];
        unsigned v[8];
#pragma unroll
        for (int j = 0; j < 8; ++j) v[j] = xlb[(size_t)ed[j].x * 64 + lane];
#pragma unroll
        for (int j = 0; j < 8; ++j) {
            float nw = __uint_as_float(ed[j].y);
            float2 f = bf16unpack(v[j]);
            ax += nw * f.x;
            ay += nw * f.y;
        }
    }
    for (; e < e1; ++e) {
        uint2 ed = edges[e];
        float nw = __uint_as_float(ed.y);
        float2 f = bf16unpack(xlb[(size_t)ed.x * 64 + lane]);
        ax += nw * f.x;
        ay += nw * f.y;
    }
    float di = dinv[wave];
    float2 pi = bf16unpack(xlb[(size_t)wave * 64 + lane]);
    float2 bb = *(const float2*)(bias + lane * 2);
    float2 o;
    o.x = gelu_f(ax + di * pi.x + bb.x);
    o.y = gelu_f(ay + di * pi.y + bb.y);
    *(float2*)(out + (size_t)wave * 128 + lane * 2) = o;
}

// ---------------- edge aggregation (F=64): half-wave per edge ----------------

__global__ __launch_bounds__(256) void agg64_kernel(const unsigned* __restrict__ xlb,
                                                    const int* __restrict__ row_off,
                                                    const uint2* __restrict__ edges,
                                                    const float* __restrict__ dinv,
                                                    const float* __restrict__ bias,
                                                    float* __restrict__ out, int nnodes) {
    int wave = (blockIdx.x * blockDim.x + threadIdx.x) >> 6;
    int lane = threadIdx.x & 63;
    int sub = lane >> 5;
    int sl = lane & 31;
    if (wave >= nnodes) return;
    int e0 = row_off[wave], e1 = row_off[wave + 1];
    float ax = 0.f, ay = 0.f;
    int e = e0;
    for (; e + 8 <= e1; e += 8) {
        uint2 ed[4];
#pragma unroll
        for (int j = 0; j < 4; ++j) ed[j] = edges[e + 2 * j + sub];
        unsigned v[4];
#pragma unroll
        for (int j = 0; j < 4; ++j) v[j] = xlb[(size_t)ed[j].x * 32 + sl];
#pragma unroll
        for (int j = 0; j < 4; ++j) {
            float nw = __uint_as_float(ed[j].y);
            float2 f = bf16unpack(v[j]);
            ax += nw * f.x;
            ay += nw * f.y;
        }
    }
    for (; e + 2 <= e1; e += 2) {
        uint2 ed = edges[e + sub];
        float nw = __uint_as_float(ed.y);
        float2 f = bf16unpack(xlb[(size_t)ed.x * 32 + sl]);
        ax += nw * f.x;
        ay += nw * f.y;
    }
    if (e < e1 && sub == 0) {
        uint2 ed = edges[e];
        float nw = __uint_as_float(ed.y);
        float2 f = bf16unpack(xlb[(size_t)ed.x * 32 + sl]);
        ax += nw * f.x;
        ay += nw * f.y;
    }
    ax += __shfl_xor(ax, 32, 64);
    ay += __shfl_xor(ay, 32, 64);
    if (sub == 0) {
        float di = dinv[wave];
        float2 pi = bf16unpack(xlb[(size_t)wave * 32 + sl]);
        float2 bb = *(const float2*)(bias + sl * 2);
        float2 o;
        o.x = gelu_f(ax + di * pi.x + bb.x);
        o.y = gelu_f(ay + di * pi.y + bb.y);
        *(float2*)(out + (size_t)wave * 64 + sl * 2) = o;
    }
}

// ---------------- mean pool (batch sorted) ----------------

#define POOL_CHUNK 64

__global__ __launch_bounds__(256) void pool_kernel(const float* __restrict__ h,
                                                   const int* __restrict__ batch,
                                                   float* __restrict__ psum,
                                                   float* __restrict__ pcnt, int nnodes) {
    int wave = (blockIdx.x * blockDim.x + threadIdx.x) >> 6;
    int lane = threadIdx.x & 63;
    int n0 = wave * POOL_CHUNK;
    if (n0 >= nnodes) return;
    int n1 = n0 + POOL_CHUNK;
    if (n1 > nnodes) n1 = nnodes;

    int g_cur = batch[n0];
    float acc = 0.f;
    int cnt = 0;
    for (int node = n0; node < n1; ++node) {
        int g = batch[node];
        if (g != g_cur) {
            atomicAdd(&psum[g_cur * TDIM + lane], acc);
            if (lane == 0) atomicAdd(&pcnt[g_cur], (float)cnt);
            acc = 0.f;
            cnt = 0;
            g_cur = g;
        }
        acc += h[(size_t)node * TDIM + lane];
        ++cnt;
    }
    atomicAdd(&psum[g_cur * TDIM + lane], acc);
    if (lane == 0) atomicAdd(&pcnt[g_cur], (float)cnt);
}

__global__ __launch_bounds__(256) void fin_kernel(const float* __restrict__ psum,
                                                  const float* __restrict__ pcnt,
                                                  float* __restrict__ out) {
    int i = blockIdx.x * blockDim.x + threadIdx.x;
    if (i < NGRAPH * TDIM) {
        float c = pcnt[i >> 6];
        out[i] = psum[i] / fmaxf(c, 1.0f);
    }
}

// ---------------- launch ----------------

extern "C" void kernel_launch(void* const* d_in, const int* in_sizes, int n_in,
                              void* d_out, int out_size, void* d_ws, size_t ws_size,
                              hipStream_t stream) {
    const float* x = (const float*)d_in[0];
    const int* ei = (const int*)d_in[1];
    const int* batch = (const int*)d_in[2];
    const float* W0 = (const float*)d_in[3];
    const float* b0 = (const float*)d_in[4];
    const float* W1 = (const float*)d_in[5];
    const float* b1 = (const float*)d_in[6];
    const float* W2 = (const float*)d_in[7];
    const float* b2 = (const float*)d_in[8];

    const int N = in_sizes[0] / F_IN;
    const int E = in_sizes[1] / 2;
    const int* src = ei;
    const int* dst = ei + E;

    char* w = (char*)d_ws;
    auto alloc = [&](size_t bytes) -> void* {
        void* p = (void*)w;
        w += (bytes + 255) & ~(size_t)255;
        return p;
    };
    float* isq = (float*)alloc((size_t)N * 4);
    float* dinv = (float*)alloc((size_t)N * 4);
    int* cnt = (int*)alloc((size_t)N * 4);
    int* cursor = (int*)alloc((size_t)N * 4);
    int* row_off = (int*)alloc((size_t)(N + 1) * 4);
    int* bsums = (int*)alloc(256 * 4);
    uint2* edges = (uint2*)alloc((size_t)E * 8);
    float* psum = (float*)alloc((size_t)NGRAPH * TDIM * 4);
    float* pcnt = (float*)alloc((size_t)NGRAPH * 4);
    float* bufH = (float*)alloc((size_t)N * 128 * 4);
    unsigned* bufXb = (unsigned*)alloc((size_t)N * 64 * 4);
    unsigned short* whiT0 = (unsigned short*)alloc(128 * 128 * 2);
    unsigned short* wloT0 = (unsigned short*)alloc(128 * 128 * 2);
    unsigned short* whiT1 = (unsigned short*)alloc(128 * 128 * 2);
    unsigned short* wloT1 = (unsigned short*)alloc(128 * 128 * 2);
    unsigned short* whiT2 = (unsigned short*)alloc(64 * 128 * 2);
    unsigned short* wloT2 = (unsigned short*)alloc(64 * 128 * 2);

    hipMemsetAsync(cnt, 0, (size_t)N * 4, stream);
    hipMemsetAsync(cursor, 0, (size_t)N * 4, stream);
    hipMemsetAsync(psum, 0, (size_t)NGRAPH * TDIM * 4, stream);
    hipMemsetAsync(pcnt, 0, (size_t)NGRAPH * 4, stream);

    const int tb = 256;
    deg_count_kernel<<<(E + tb - 1) / tb, tb, 0, stream>>>(dst, cnt, E);
    deg_fin_kernel<<<(N + tb - 1) / tb, tb, 0, stream>>>(cnt, isq, dinv, N);

    int nchunk = (N + 2047) / 2048;
    scanA_kernel<<<nchunk, 256, 0, stream>>>(cnt, bsums, N);
    scanB_kernel<<<1, 64, 0, stream>>>(bsums, nchunk, row_off);
    scanC_kernel<<<nchunk, 256, 0, stream>>>(cnt, bsums, row_off, N);

    int fchunks = (E + FB_CHUNK - 1) / FB_CHUNK;
    fill_edges_kernel<<<fchunks * 8, 256, 0, stream>>>(src, dst, row_off, cursor, isq, edges,
                                                       E, N);

    wconv_kernel<<<(128 * 128 + 255) / 256, 256, 0, stream>>>(W0, 128, whiT0, wloT0);
    wconv_kernel<<<(128 * 128 + 255) / 256, 256, 0, stream>>>(W1, 128, whiT1, wloT1);
    wconv_kernel<<<(128 * 64 + 255) / 256, 256, 0, stream>>>(W2, 64, whiT2, wloT2);

    int gblocks = (N + 127) / 128;
    int ablocks = (N * 64 + 255) / 256;

    // layer 0
    gemm_mfma_kernel<128><<<gblocks, 256, 0, stream>>>(x, whiT0, wloT0, bufXb, N);
    agg128_kernel<<<ablocks, 256, 0, stream>>>(bufXb, row_off, edges, dinv, b0, bufH, N);
    // layer 1
    gemm_mfma_kernel<128><<<gblocks, 256, 0, stream>>>(bufH, whiT1, wloT1, bufXb, N);
    agg128_kernel<<<ablocks, 256, 0, stream>>>(bufXb, row_off, edges, dinv, b1, bufH, N);
    // layer 2 (Fout = 64)
    gemm_mfma_kernel<64><<<gblocks, 256, 0, stream>>>(bufH, whiT2, wloT2, bufXb, N);
    agg64_kernel<<<ablocks, 256, 0, stream>>>(bufXb, row_off, edges, dinv, b2, bufH, N);

    // pool
    int pwaves = (N + POOL_CHUNK - 1) / POOL_CHUNK;
    int pblocks = (pwaves * 64 + 255) / 256;
    pool_kernel<<<pblocks, 256, 0, stream>>>(bufH, batch, psum, pcnt, N);
    fin_kernel<<<(NGRAPH * TDIM + 255) / 256, 256, 0, stream>>>(psum, pcnt, (float*)d_out);
}

// Round 9
// 528.017 us; speedup vs baseline: 1.4702x; 1.0894x over previous
//
#include <hip/hip_runtime.h>
#include <math.h>

#define F_IN 128
#define TDIM 64
#define NGRAPH 256

typedef __attribute__((ext_vector_type(8))) short short8;
typedef __attribute__((ext_vector_type(4))) float f32x4;

__device__ __forceinline__ float gelu_f(float x) {
    float x3 = x * x * x;
    return 0.5f * x * (1.0f + tanhf(0.7978845608028654f * (x + 0.044715f * x3)));
}

// fp32 <-> bf16 bit helpers (RNE)
__device__ __forceinline__ unsigned short bf16_of(float x) {
    unsigned u = __float_as_uint(x);
    return (unsigned short)((u + 0x7fffu + ((u >> 16) & 1u)) >> 16);
}
__device__ __forceinline__ float f_of(unsigned short h) {
    return __uint_as_float(((unsigned)h) << 16);
}
__device__ __forceinline__ unsigned bf16pair(float a, float b) {
    return (unsigned)bf16_of(a) | ((unsigned)bf16_of(b) << 16);
}
__device__ __forceinline__ float2 bf16unpack(unsigned u) {
    float2 r;
    r.x = __uint_as_float(u << 16);
    r.y = __uint_as_float(u & 0xffff0000u);
    return r;
}

// ---------------- degree / CSR build ----------------

__global__ __launch_bounds__(256) void deg_count_kernel(const int* __restrict__ dst,
                                                        int* __restrict__ cnt, int E) {
    int e = blockIdx.x * blockDim.x + threadIdx.x;
    if (e < E) atomicAdd(&cnt[dst[e]], 1);
}

__global__ __launch_bounds__(256) void deg_fin_kernel(const int* __restrict__ cnt,
                                                      float* __restrict__ isq,
                                                      float* __restrict__ dinv, int n) {
    int i = blockIdx.x * blockDim.x + threadIdx.x;
    if (i < n) {
        float d = (float)cnt[i] + 1.0f;  // +1 self loop
        isq[i] = rsqrtf(d);
        dinv[i] = 1.0f / d;
    }
}

__global__ __launch_bounds__(256) void scanA_kernel(const int* __restrict__ cnt,
                                                    int* __restrict__ bsums, int n) {
    __shared__ int sh[256];
    int t = threadIdx.x;
    int base = blockIdx.x * 2048 + t * 8;
    int s = 0;
    for (int j = 0; j < 8; ++j) {
        int i = base + j;
        if (i < n) s += cnt[i];
    }
    sh[t] = s;
    __syncthreads();
    for (int off = 128; off > 0; off >>= 1) {
        if (t < off) sh[t] += sh[t + off];
        __syncthreads();
    }
    if (t == 0) bsums[blockIdx.x] = sh[0];
}

__global__ void scanB_kernel(int* __restrict__ bsums, int nb, int* __restrict__ row_off) {
    if (threadIdx.x == 0 && blockIdx.x == 0) {
        int c = 0;
        for (int i = 0; i < nb; ++i) {
            int v = bsums[i];
            bsums[i] = c;
            c += v;
        }
        row_off[0] = 0;
    }
}

__global__ __launch_bounds__(256) void scanC_kernel(const int* __restrict__ cnt,
                                                    const int* __restrict__ bsums,
                                                    int* __restrict__ row_off, int n) {
    __shared__ int sh[256];
    int t = threadIdx.x;
    int base = blockIdx.x * 2048 + t * 8;
    int v[8];
    int s = 0;
    for (int j = 0; j < 8; ++j) {
        int i = base + j;
        int x = (i < n) ? cnt[i] : 0;
        s += x;
        v[j] = s;
    }
    sh[t] = s;
    __syncthreads();
    for (int off = 1; off < 256; off <<= 1) {
        int x = (t >= off) ? sh[t - off] : 0;
        __syncthreads();
        sh[t] += x;
        __syncthreads();
    }
    int threadExcl = sh[t] - s;
    int off0 = bsums[blockIdx.x] + threadExcl;
    for (int j = 0; j < 8; ++j) {
        int i = base + j;
        if (i < n) row_off[i + 1] = off0 + v[j];
    }
}

// ---------------- edge build: 2-pass LDS-binned scatter ----------------
// Buckets = 256-node dst ranges. bucket_off[b] == row_off[b<<8] (free from CSR scan).
// Pass C: bin edges into bucket-grouped tmp[] with per-block bulk reservations ->
// writes are short contiguous runs (full-ish lines, no per-edge line writeback).
// Pass D: one block per bucket; LDS cursors; final scatter confined to a ~33 KB
// window -> combines in L2 of whatever XCD runs the block (no mapping assumption).

#define BIN_CH 4096
#define MAXNB 512

__global__ __launch_bounds__(256) void binC_kernel(const int* __restrict__ src,
                                                   const int* __restrict__ dst,
                                                   const int* __restrict__ row_off,
                                                   int* __restrict__ bucket_cursor,
                                                   uint2* __restrict__ tmp, int E, int N,
                                                   int NB) {
    __shared__ int hist[MAXNB];
    __shared__ int hbase[MAXNB];
    __shared__ int hcur[MAXNB];
    int tid = threadIdx.x;
    int base = blockIdx.x * BIN_CH;
    int end = base + BIN_CH;
    if (end > E) end = E;
    for (int i = tid; i < NB; i += 256) hist[i] = 0;
    __syncthreads();
    for (int e = base + tid; e < end; e += 256) atomicAdd(&hist[dst[e] >> 8], 1);
    __syncthreads();
    for (int i = tid; i < NB; i += 256) {
        int c = hist[i];
        hbase[i] = (c > 0) ? atomicAdd(&bucket_cursor[i], c) : 0;
        hcur[i] = 0;
    }
    __syncthreads();
    for (int e = base + tid; e < end; e += 256) {
        int d = dst[e];
        int b = d >> 8;
        int p = atomicAdd(&hcur[b], 1);
        int boff = row_off[b << 8];  // b<<8 <= d < N, in range
        tmp[(size_t)boff + hbase[b] + p] = make_uint2((unsigned)src[e], (unsigned)d);
    }
}

__global__ __launch_bounds__(256) void binD_kernel(const uint2* __restrict__ tmp,
                                                   const int* __restrict__ row_off,
                                                   const float* __restrict__ isq,
                                                   uint2* __restrict__ edges, int N) {
    __shared__ int lcur[256];
    __shared__ float lisq[256];
    int b = blockIdx.x;
    int node0 = b << 8;
    int tid = threadIdx.x;
    lcur[tid] = 0;
    int nd = node0 + tid;
    lisq[tid] = (nd < N) ? isq[nd] : 0.f;
    __syncthreads();
    int hiNode = node0 + 256;
    if (hiNode > N) hiNode = N;
    int s0 = row_off[node0];
    int s1 = row_off[hiNode];
    for (int e = s0 + tid; e < s1; e += 256) {
        uint2 t = tmp[e];
        int d = (int)t.y;
        int dl = d & 255;
        int p = atomicAdd(&lcur[dl], 1);
        float nrm = isq[t.x] * lisq[dl];
        edges[(size_t)row_off[d] + p] = make_uint2(t.x, __float_as_uint(nrm));
    }
}

// ---------------- weight split: W[K][FOUT] -> bf16 hi/lo, transposed [FOUT][128] ----------------

__global__ __launch_bounds__(256) void wconv_kernel(const float* __restrict__ W, int FOUT,
                                                    unsigned short* __restrict__ whiT,
                                                    unsigned short* __restrict__ wloT) {
    int idx = blockIdx.x * blockDim.x + threadIdx.x;
    if (idx >= 128 * FOUT) return;
    int k = idx / FOUT;
    int n = idx % FOUT;
    float w = W[idx];
    unsigned short h = bf16_of(w);
    whiT[(size_t)n * 128 + k] = h;
    wloT[(size_t)n * 128 + k] = bf16_of(w - f_of(h));
}

// ---------------- MFMA GEMM (split-bf16, weights in LDS): Yb = pack_bf16(X @ W) ----------------

#define LROW 136  // LDS row stride in shorts (272 B = 256 + 16 pad)

template <int FOUT>
__global__ __launch_bounds__(256) void gemm_mfma_kernel(const float* __restrict__ X,
                                                        const unsigned short* __restrict__ whiT,
                                                        const unsigned short* __restrict__ wloT,
                                                        unsigned* __restrict__ Yb, int nrows) {
    constexpr int NT = FOUT / 16;
    __shared__ short lds[2 * FOUT * LROW];
    short* shi = lds;
    short* slo = lds + FOUT * LROW;

    for (int c = threadIdx.x; c < FOUT * 16; c += 256) {
        int n = c >> 4, r = c & 15;
        *(short8*)(shi + n * LROW + r * 8) = *(const short8*)(whiT + (size_t)n * 128 + r * 8);
        *(short8*)(slo + n * LROW + r * 8) = *(const short8*)(wloT + (size_t)n * 128 + r * 8);
    }
    __syncthreads();

    int lane = threadIdx.x & 63;
    int wave = threadIdx.x >> 6;
    int quad = lane >> 4;
    int l16 = lane & 15;
    int rowBase = blockIdx.x * 128 + wave * 32;

    f32x4 acc[2][NT];
#pragma unroll
    for (int m = 0; m < 2; ++m)
#pragma unroll
        for (int t = 0; t < NT; ++t) acc[m][t] = (f32x4){0.f, 0.f, 0.f, 0.f};

    int arow0 = rowBase + l16;
    int arow1 = rowBase + 16 + l16;
    bool ok0 = arow0 < nrows, ok1 = arow1 < nrows;
    const float* xr0 = X + (size_t)arow0 * 128;
    const float* xr1 = X + (size_t)arow1 * 128;

#pragma unroll
    for (int k0 = 0; k0 < 128; k0 += 32) {
        short8 ahi[2], alo[2];
#pragma unroll
        for (int m = 0; m < 2; ++m) {
            const float* xr = m ? xr1 : xr0;
            bool ok = m ? ok1 : ok0;
            float xv[8];
            if (ok) {
                float4 v0 = *(const float4*)(xr + k0 + quad * 8);
                float4 v1 = *(const float4*)(xr + k0 + quad * 8 + 4);
                xv[0] = v0.x; xv[1] = v0.y; xv[2] = v0.z; xv[3] = v0.w;
                xv[4] = v1.x; xv[5] = v1.y; xv[6] = v1.z; xv[7] = v1.w;
            } else {
#pragma unroll
                for (int j = 0; j < 8; ++j) xv[j] = 0.f;
            }
#pragma unroll
            for (int j = 0; j < 8; ++j) {
                unsigned short h = bf16_of(xv[j]);
                ahi[m][j] = (short)h;
                alo[m][j] = (short)bf16_of(xv[j] - f_of(h));
            }
        }
#pragma unroll
        for (int t = 0; t < NT; ++t) {
            int off = (t * 16 + l16) * LROW + k0 + quad * 8;
            short8 bhi = *(const short8*)(shi + off);
            short8 blo = *(const short8*)(slo + off);
#pragma unroll
            for (int m = 0; m < 2; ++m) {
                acc[m][t] = __builtin_amdgcn_mfma_f32_16x16x32_bf16(ahi[m], bhi, acc[m][t], 0, 0, 0);
                acc[m][t] = __builtin_amdgcn_mfma_f32_16x16x32_bf16(alo[m], bhi, acc[m][t], 0, 0, 0);
                acc[m][t] = __builtin_amdgcn_mfma_f32_16x16x32_bf16(ahi[m], blo, acc[m][t], 0, 0, 0);
            }
        }
    }

#pragma unroll
    for (int m = 0; m < 2; ++m) {
#pragma unroll
        for (int t = 0; t < NT; ++t) {
            int col = t * 16 + l16;
#pragma unroll
            for (int i = 0; i < 4; ++i) {
                int r = rowBase + m * 16 + quad * 4 + i;
                float v = acc[m][t][i];
                float nb = __shfl_xor(v, 1, 64);
                if (((lane & 1) == 0) && r < nrows)
                    Yb[(size_t)r * (FOUT / 2) + (col >> 1)] = bf16pair(v, nb);
            }
        }
    }
}

// ---------------- edge aggregation (F=128): scalar edge records, 16-wide gather ----------------

__global__ __launch_bounds__(256) void agg128_kernel(const unsigned* __restrict__ xlb,
                                                     const int* __restrict__ row_off,
                                                     const uint2* __restrict__ edges,
                                                     const float* __restrict__ dinv,
                                                     const float* __restrict__ bias,
                                                     float* __restrict__ out, int nnodes) {
    int wave = (blockIdx.x * blockDim.x + threadIdx.x) >> 6;
    int lane = threadIdx.x & 63;
    if (wave >= nnodes) return;
    int e0 = __builtin_amdgcn_readfirstlane(row_off[wave]);
    int e1 = __builtin_amdgcn_readfirstlane(row_off[wave + 1]);
    float ax = 0.f, ay = 0.f;
    int e = e0;
    for (; e + 16 <= e1; e += 16) {
        unsigned sreg[16];
        float nw[16];
#pragma unroll
        for (int j = 0; j < 16; ++j) {
            uint2 ed = edges[e + j];
            sreg[j] = (unsigned)__builtin_amdgcn_readfirstlane((int)ed.x);
            nw[j] = __uint_as_float((unsigned)__builtin_amdgcn_readfirstlane((int)ed.y));
        }
        unsigned v[16];
#pragma unroll
        for (int j = 0; j < 16; ++j) v[j] = xlb[(size_t)sreg[j] * 64 + lane];
#pragma unroll
        for (int j = 0; j < 16; ++j) {
            float2 f = bf16unpack(v[j]);
            ax += nw[j] * f.x;
            ay += nw[j] * f.y;
        }
    }
    for (; e + 4 <= e1; e += 4) {
        unsigned sreg[4];
        float nw[4];
#pragma unroll
        for (int j = 0; j < 4; ++j) {
            uint2 ed = edges[e + j];
            sreg[j] = (unsigned)__builtin_amdgcn_readfirstlane((int)ed.x);
            nw[j] = __uint_as_float((unsigned)__builtin_amdgcn_readfirstlane((int)ed.y));
        }
        unsigned v[4];
#pragma unroll
        for (int j = 0; j < 4; ++j) v[j] = xlb[(size_t)sreg[j] * 64 + lane];
#pragma unroll
        for (int j = 0; j < 4; ++j) {
            float2 f = bf16unpack(v[j]);
            ax += nw[j] * f.x;
            ay += nw[j] * f.y;
        }
    }
    for (; e < e1; ++e) {
        uint2 ed = edges[e];
        float nw = __uint_as_float(ed.y);
        float2 f = bf16unpack(xlb[(size_t)ed.x * 64 + lane]);
        ax += nw * f.x;
        ay += nw * f.y;
    }
    float di = dinv[wave];
    float2 pi = bf16unpack(xlb[(size_t)wave * 64 + lane]);
    float2 bb = *(const float2*)(bias + lane * 2);
    float2 o;
    o.x = gelu_f(ax + di * pi.x + bb.x);
    o.y = gelu_f(ay + di * pi.y + bb.y);
    *(float2*)(out + (size_t)wave * 128 + lane * 2) = o;
}

// ---------------- edge aggregation (F=64): half-wave per edge, 16-wide batch ----------------

__global__ __launch_bounds__(256) void agg64_kernel(const unsigned* __restrict__ xlb,
                                                    const int* __restrict__ row_off,
                                                    const uint2* __restrict__ edges,
                                                    const float* __restrict__ dinv,
                                                    const float* __restrict__ bias,
                                                    float* __restrict__ out, int nnodes) {
    int wave = (blockIdx.x * blockDim.x + threadIdx.x) >> 6;
    int lane = threadIdx.x & 63;
    int sub = lane >> 5;
    int sl = lane & 31;
    if (wave >= nnodes) return;
    int e0 = row_off[wave], e1 = row_off[wave + 1];
    float ax = 0.f, ay = 0.f;
    int e = e0;
    for (; e + 16 <= e1; e += 16) {
        uint2 ed[8];
#pragma unroll
        for (int j = 0; j < 8; ++j) ed[j] = edges[e + 2 * j + sub];
        unsigned v[8];
#pragma unroll
        for (int j = 0; j < 8; ++j) v[j] = xlb[(size_t)ed[j].x * 32 + sl];
#pragma unroll
        for (int j = 0; j < 8; ++j) {
            float nw = __uint_as_float(ed[j].y);
            float2 f = bf16unpack(v[j]);
            ax += nw * f.x;
            ay += nw * f.y;
        }
    }
    for (; e + 2 <= e1; e += 2) {
        uint2 ed = edges[e + sub];
        float nw = __uint_as_float(ed.y);
        float2 f = bf16unpack(xlb[(size_t)ed.x * 32 + sl]);
        ax += nw * f.x;
        ay += nw * f.y;
    }
    if (e < e1 && sub == 0) {
        uint2 ed = edges[e];
        float nw = __uint_as_float(ed.y);
        float2 f = bf16unpack(xlb[(size_t)ed.x * 32 + sl]);
        ax += nw * f.x;
        ay += nw * f.y;
    }
    ax += __shfl_xor(ax, 32, 64);
    ay += __shfl_xor(ay, 32, 64);
    if (sub == 0) {
        float di = dinv[wave];
        float2 pi = bf16unpack(xlb[(size_t)wave * 32 + sl]);
        float2 bb = *(const float2*)(bias + sl * 2);
        float2 o;
        o.x = gelu_f(ax + di * pi.x + bb.x);
        o.y = gelu_f(ay + di * pi.y + bb.y);
        *(float2*)(out + (size_t)wave * 64 + sl * 2) = o;
    }
}

// ---------------- mean pool (batch sorted) ----------------

#define POOL_CHUNK 64

__global__ __launch_bounds__(256) void pool_kernel(const float* __restrict__ h,
                                                   const int* __restrict__ batch,
                                                   float* __restrict__ psum,
                                                   float* __restrict__ pcnt, int nnodes) {
    int wave = (blockIdx.x * blockDim.x + threadIdx.x) >> 6;
    int lane = threadIdx.x & 63;
    int n0 = wave * POOL_CHUNK;
    if (n0 >= nnodes) return;
    int n1 = n0 + POOL_CHUNK;
    if (n1 > nnodes) n1 = nnodes;

    int g_cur = batch[n0];
    float acc = 0.f;
    int cnt = 0;
    for (int node = n0; node < n1; ++node) {
        int g = batch[node];
        if (g != g_cur) {
            atomicAdd(&psum[g_cur * TDIM + lane], acc);
            if (lane == 0) atomicAdd(&pcnt[g_cur], (float)cnt);
            acc = 0.f;
            cnt = 0;
            g_cur = g;
        }
        acc += h[(size_t)node * TDIM + lane];
        ++cnt;
    }
    atomicAdd(&psum[g_cur * TDIM + lane], acc);
    if (lane == 0) atomicAdd(&pcnt[g_cur], (float)cnt);
}

__global__ __launch_bounds__(256) void fin_kernel(const float* __restrict__ psum,
                                                  const float* __restrict__ pcnt,
                                                  float* __restrict__ out) {
    int i = blockIdx.x * blockDim.x + threadIdx.x;
    if (i < NGRAPH * TDIM) {
        float c = pcnt[i >> 6];
        out[i] = psum[i] / fmaxf(c, 1.0f);
    }
}

// ---------------- launch ----------------

extern "C" void kernel_launch(void* const* d_in, const int* in_sizes, int n_in,
                              void* d_out, int out_size, void* d_ws, size_t ws_size,
                              hipStream_t stream) {
    const float* x = (const float*)d_in[0];
    const int* ei = (const int*)d_in[1];
    const int* batch = (const int*)d_in[2];
    const float* W0 = (const float*)d_in[3];
    const float* b0 = (const float*)d_in[4];
    const float* W1 = (const float*)d_in[5];
    const float* b1 = (const float*)d_in[6];
    const float* W2 = (const float*)d_in[7];
    const float* b2 = (const float*)d_in[8];

    const int N = in_sizes[0] / F_IN;
    const int E = in_sizes[1] / 2;
    const int* src = ei;
    const int* dst = ei + E;
    const int NB = (N + 255) >> 8;

    char* w = (char*)d_ws;
    auto alloc = [&](size_t bytes) -> void* {
        void* p = (void*)w;
        w += (bytes + 255) & ~(size_t)255;
        return p;
    };
    float* isq = (float*)alloc((size_t)N * 4);
    float* dinv = (float*)alloc((size_t)N * 4);
    int* cnt = (int*)alloc((size_t)N * 4);
    int* bucket_cursor = (int*)alloc((size_t)MAXNB * 4);
    int* row_off = (int*)alloc((size_t)(N + 1) * 4);
    int* bsums = (int*)alloc(256 * 4);
    uint2* edges = (uint2*)alloc((size_t)E * 8);
    uint2* tmp = (uint2*)alloc((size_t)E * 8);
    float* psum = (float*)alloc((size_t)NGRAPH * TDIM * 4);
    float* pcnt = (float*)alloc((size_t)NGRAPH * 4);
    float* bufH = (float*)alloc((size_t)N * 128 * 4);
    unsigned* bufXb = (unsigned*)alloc((size_t)N * 64 * 4);
    unsigned short* whiT0 = (unsigned short*)alloc(128 * 128 * 2);
    unsigned short* wloT0 = (unsigned short*)alloc(128 * 128 * 2);
    unsigned short* whiT1 = (unsigned short*)alloc(128 * 128 * 2);
    unsigned short* wloT1 = (unsigned short*)alloc(128 * 128 * 2);
    unsigned short* whiT2 = (unsigned short*)alloc(64 * 128 * 2);
    unsigned short* wloT2 = (unsigned short*)alloc(64 * 128 * 2);

    hipMemsetAsync(cnt, 0, (size_t)N * 4, stream);
    hipMemsetAsync(bucket_cursor, 0, (size_t)MAXNB * 4, stream);
    hipMemsetAsync(psum, 0, (size_t)NGRAPH * TDIM * 4, stream);
    hipMemsetAsync(pcnt, 0, (size_t)NGRAPH * 4, stream);

    const int tb = 256;
    deg_count_kernel<<<(E + tb - 1) / tb, tb, 0, stream>>>(dst, cnt, E);
    deg_fin_kernel<<<(N + tb - 1) / tb, tb, 0, stream>>>(cnt, isq, dinv, N);

    int nchunk = (N + 2047) / 2048;
    scanA_kernel<<<nchunk, 256, 0, stream>>>(cnt, bsums, N);
    scanB_kernel<<<1, 64, 0, stream>>>(bsums, nchunk, row_off);
    scanC_kernel<<<nchunk, 256, 0, stream>>>(cnt, bsums, row_off, N);

    int cblocks = (E + BIN_CH - 1) / BIN_CH;
    binC_kernel<<<cblocks, 256, 0, stream>>>(src, dst, row_off, bucket_cursor, tmp, E, N, NB);
    binD_kernel<<<NB, 256, 0, stream>>>(tmp, row_off, isq, edges, N);

    wconv_kernel<<<(128 * 128 + 255) / 256, 256, 0, stream>>>(W0, 128, whiT0, wloT0);
    wconv_kernel<<<(128 * 128 + 255) / 256, 256, 0, stream>>>(W1, 128, whiT1, wloT1);
    wconv_kernel<<<(128 * 64 + 255) / 256, 256, 0, stream>>>(W2, 64, whiT2, wloT2);

    int gblocks = (N + 127) / 128;
    int ablocks = (N * 64 + 255) / 256;

    // layer 0
    gemm_mfma_kernel<128><<<gblocks, 256, 0, stream>>>(x, whiT0, wloT0, bufXb, N);
    agg128_kernel<<<ablocks, 256, 0, stream>>>(bufXb, row_off, edges, dinv, b0, bufH, N);
    // layer 1
    gemm_mfma_kernel<128><<<gblocks, 256, 0, stream>>>(bufH, whiT1, wloT1, bufXb, N);
    agg128_kernel<<<ablocks, 256, 0, stream>>>(bufXb, row_off, edges, dinv, b1, bufH, N);
    // layer 2 (Fout = 64)
    gemm_mfma_kernel<64><<<gblocks, 256, 0, stream>>>(bufH, whiT2, wloT2, bufXb, N);
    agg64_kernel<<<ablocks, 256, 0, stream>>>(bufXb, row_off, edges, dinv, b2, bufH, N);

    // pool
    int pwaves = (N + POOL_CHUNK - 1) / POOL_CHUNK;
    int pblocks = (pwaves * 64 + 255) / 256;
    pool_kernel<<<pblocks, 256, 0, stream>>>(bufH, batch, psum, pcnt, N);
    fin_kernel<<<(NGRAPH * TDIM + 255) / 256, 256, 0, stream>>>(psum, pcnt, (float*)d_out);
}

// Round 10
// 516.758 us; speedup vs baseline: 1.5022x; 1.0218x over previous
//
#include <hip/hip_runtime.h>
#include <math.h>

#define F_IN 128
#define TDIM 64
#define NGRAPH 256

typedef __attribute__((ext_vector_type(8))) short short8;
typedef __attribute__((ext_vector_type(4))) float f32x4;

__device__ __forceinline__ float gelu_f(float x) {
    float x3 = x * x * x;
    return 0.5f * x * (1.0f + tanhf(0.7978845608028654f * (x + 0.044715f * x3)));
}

// fp32 <-> bf16 bit helpers (RNE)
__device__ __forceinline__ unsigned short bf16_of(float x) {
    unsigned u = __float_as_uint(x);
    return (unsigned short)((u + 0x7fffu + ((u >> 16) & 1u)) >> 16);
}
__device__ __forceinline__ float f_of(unsigned short h) {
    return __uint_as_float(((unsigned)h) << 16);
}
__device__ __forceinline__ unsigned bf16pair(float a, float b) {
    return (unsigned)bf16_of(a) | ((unsigned)bf16_of(b) << 16);
}
__device__ __forceinline__ float2 bf16unpack(unsigned u) {
    float2 r;
    r.x = __uint_as_float(u << 16);
    r.y = __uint_as_float(u & 0xffff0000u);
    return r;
}

// ---------------- degree / CSR build ----------------

__global__ __launch_bounds__(256) void deg_count_kernel(const int* __restrict__ dst,
                                                        int* __restrict__ cnt, int E) {
    int e = blockIdx.x * blockDim.x + threadIdx.x;
    if (e < E) atomicAdd(&cnt[dst[e]], 1);
}

__global__ __launch_bounds__(256) void scanA_kernel(const int* __restrict__ cnt,
                                                    int* __restrict__ bsums, int n) {
    __shared__ int sh[256];
    int t = threadIdx.x;
    int base = blockIdx.x * 2048 + t * 8;
    int s = 0;
    for (int j = 0; j < 8; ++j) {
        int i = base + j;
        if (i < n) s += cnt[i];
    }
    sh[t] = s;
    __syncthreads();
    for (int off = 128; off > 0; off >>= 1) {
        if (t < off) sh[t] += sh[t + off];
        __syncthreads();
    }
    if (t == 0) bsums[blockIdx.x] = sh[0];
}

__global__ void scanB_kernel(int* __restrict__ bsums, int nb, int* __restrict__ row_off) {
    if (threadIdx.x == 0 && blockIdx.x == 0) {
        int c = 0;
        for (int i = 0; i < nb; ++i) {
            int v = bsums[i];
            bsums[i] = c;
            c += v;
        }
        row_off[0] = 0;
    }
}

// scanC also emits isq/dinv (deg_fin folded in)
__global__ __launch_bounds__(256) void scanC_kernel(const int* __restrict__ cnt,
                                                    const int* __restrict__ bsums,
                                                    int* __restrict__ row_off,
                                                    float* __restrict__ isq,
                                                    float* __restrict__ dinv, int n) {
    __shared__ int sh[256];
    int t = threadIdx.x;
    int base = blockIdx.x * 2048 + t * 8;
    int v[8];
    int s = 0;
    for (int j = 0; j < 8; ++j) {
        int i = base + j;
        int x = (i < n) ? cnt[i] : 0;
        if (i < n) {
            float d = (float)x + 1.0f;
            isq[i] = rsqrtf(d);
            dinv[i] = 1.0f / d;
        }
        s += x;
        v[j] = s;
    }
    sh[t] = s;
    __syncthreads();
    for (int off = 1; off < 256; off <<= 1) {
        int x = (t >= off) ? sh[t - off] : 0;
        __syncthreads();
        sh[t] += x;
        __syncthreads();
    }
    int threadExcl = sh[t] - s;
    int off0 = bsums[blockIdx.x] + threadExcl;
    for (int j = 0; j < 8; ++j) {
        int i = base + j;
        if (i < n) row_off[i + 1] = off0 + v[j];
    }
}

// ---------------- edge build: 2-pass LDS-binned scatter ----------------

#define BIN_CH 4096
#define MAXNB 512

__global__ __launch_bounds__(256) void binC_kernel(const int* __restrict__ src,
                                                   const int* __restrict__ dst,
                                                   const int* __restrict__ row_off,
                                                   int* __restrict__ bucket_cursor,
                                                   uint2* __restrict__ tmp, int E, int N,
                                                   int NB) {
    __shared__ int hist[MAXNB];
    __shared__ int hbase[MAXNB];
    __shared__ int hcur[MAXNB];
    int tid = threadIdx.x;
    int base = blockIdx.x * BIN_CH;
    int end = base + BIN_CH;
    if (end > E) end = E;
    for (int i = tid; i < NB; i += 256) hist[i] = 0;
    __syncthreads();
    for (int e = base + tid; e < end; e += 256) atomicAdd(&hist[dst[e] >> 8], 1);
    __syncthreads();
    for (int i = tid; i < NB; i += 256) {
        int c = hist[i];
        hbase[i] = (c > 0) ? atomicAdd(&bucket_cursor[i], c) : 0;
        hcur[i] = 0;
    }
    __syncthreads();
    for (int e = base + tid; e < end; e += 256) {
        int d = dst[e];
        int b = d >> 8;
        int p = atomicAdd(&hcur[b], 1);
        int boff = row_off[b << 8];
        tmp[(size_t)boff + hbase[b] + p] = make_uint2((unsigned)src[e], (unsigned)d);
    }
}

__global__ __launch_bounds__(256) void binD_kernel(const uint2* __restrict__ tmp,
                                                   const int* __restrict__ row_off,
                                                   const float* __restrict__ isq,
                                                   uint2* __restrict__ edges, int N) {
    __shared__ int lcur[256];
    __shared__ float lisq[256];
    int b = blockIdx.x;
    int node0 = b << 8;
    int tid = threadIdx.x;
    lcur[tid] = 0;
    int nd = node0 + tid;
    lisq[tid] = (nd < N) ? isq[nd] : 0.f;
    __syncthreads();
    int hiNode = node0 + 256;
    if (hiNode > N) hiNode = N;
    int s0 = row_off[node0];
    int s1 = row_off[hiNode];
    for (int e = s0 + tid; e < s1; e += 256) {
        uint2 t = tmp[e];
        int d = (int)t.y;
        int dl = d & 255;
        int p = atomicAdd(&lcur[dl], 1);
        float nrm = isq[t.x] * lisq[dl];
        edges[(size_t)row_off[d] + p] = make_uint2(t.x, __float_as_uint(nrm));
    }
}

// ---------------- fused weight split for all 3 layers ----------------

__global__ __launch_bounds__(256) void wconv_all_kernel(const float* __restrict__ W0,
                                                        const float* __restrict__ W1,
                                                        const float* __restrict__ W2,
                                                        unsigned short* __restrict__ hi0,
                                                        unsigned short* __restrict__ lo0,
                                                        unsigned short* __restrict__ hi1,
                                                        unsigned short* __restrict__ lo1,
                                                        unsigned short* __restrict__ hi2,
                                                        unsigned short* __restrict__ lo2) {
    int idx = blockIdx.x * blockDim.x + threadIdx.x;
    const float* W;
    unsigned short *whi, *wlo;
    int local, FOUT;
    if (idx < 16384) {
        W = W0; whi = hi0; wlo = lo0; local = idx; FOUT = 128;
    } else if (idx < 32768) {
        W = W1; whi = hi1; wlo = lo1; local = idx - 16384; FOUT = 128;
    } else if (idx < 40960) {
        W = W2; whi = hi2; wlo = lo2; local = idx - 32768; FOUT = 64;
    } else {
        return;
    }
    int k = local / FOUT;
    int n = local % FOUT;
    float w = W[local];
    unsigned short h = bf16_of(w);
    whi[(size_t)n * 128 + k] = h;
    wlo[(size_t)n * 128 + k] = bf16_of(w - f_of(h));
}

// ---------------- MFMA GEMM (split-bf16, weights in LDS): Yb = pack_bf16(X @ W) ----------------

#define LROW 136  // LDS row stride in shorts (272 B = 256 + 16 pad)

template <int FOUT>
__global__ __launch_bounds__(256) void gemm_mfma_kernel(const float* __restrict__ X,
                                                        const unsigned short* __restrict__ whiT,
                                                        const unsigned short* __restrict__ wloT,
                                                        unsigned* __restrict__ Yb, int nrows) {
    constexpr int NT = FOUT / 16;
    __shared__ short lds[2 * FOUT * LROW];
    short* shi = lds;
    short* slo = lds + FOUT * LROW;

    for (int c = threadIdx.x; c < FOUT * 16; c += 256) {
        int n = c >> 4, r = c & 15;
        *(short8*)(shi + n * LROW + r * 8) = *(const short8*)(whiT + (size_t)n * 128 + r * 8);
        *(short8*)(slo + n * LROW + r * 8) = *(const short8*)(wloT + (size_t)n * 128 + r * 8);
    }
    __syncthreads();

    int lane = threadIdx.x & 63;
    int wave = threadIdx.x >> 6;
    int quad = lane >> 4;
    int l16 = lane & 15;
    int rowBase = blockIdx.x * 128 + wave * 32;

    f32x4 acc[2][NT];
#pragma unroll
    for (int m = 0; m < 2; ++m)
#pragma unroll
        for (int t = 0; t < NT; ++t) acc[m][t] = (f32x4){0.f, 0.f, 0.f, 0.f};

    int arow0 = rowBase + l16;
    int arow1 = rowBase + 16 + l16;
    bool ok0 = arow0 < nrows, ok1 = arow1 < nrows;
    const float* xr0 = X + (size_t)arow0 * 128;
    const float* xr1 = X + (size_t)arow1 * 128;

#pragma unroll
    for (int k0 = 0; k0 < 128; k0 += 32) {
        short8 ahi[2], alo[2];
#pragma unroll
        for (int m = 0; m < 2; ++m) {
            const float* xr = m ? xr1 : xr0;
            bool ok = m ? ok1 : ok0;
            float xv[8];
            if (ok) {
                float4 v0 = *(const float4*)(xr + k0 + quad * 8);
                float4 v1 = *(const float4*)(xr + k0 + quad * 8 + 4);
                xv[0] = v0.x; xv[1] = v0.y; xv[2] = v0.z; xv[3] = v0.w;
                xv[4] = v1.x; xv[5] = v1.y; xv[6] = v1.z; xv[7] = v1.w;
            } else {
#pragma unroll
                for (int j = 0; j < 8; ++j) xv[j] = 0.f;
            }
#pragma unroll
            for (int j = 0; j < 8; ++j) {
                unsigned short h = bf16_of(xv[j]);
                ahi[m][j] = (short)h;
                alo[m][j] = (short)bf16_of(xv[j] - f_of(h));
            }
        }
#pragma unroll
        for (int t = 0; t < NT; ++t) {
            int off = (t * 16 + l16) * LROW + k0 + quad * 8;
            short8 bhi = *(const short8*)(shi + off);
            short8 blo = *(const short8*)(slo + off);
#pragma unroll
            for (int m = 0; m < 2; ++m) {
                acc[m][t] = __builtin_amdgcn_mfma_f32_16x16x32_bf16(ahi[m], bhi, acc[m][t], 0, 0, 0);
                acc[m][t] = __builtin_amdgcn_mfma_f32_16x16x32_bf16(alo[m], bhi, acc[m][t], 0, 0, 0);
                acc[m][t] = __builtin_amdgcn_mfma_f32_16x16x32_bf16(ahi[m], blo, acc[m][t], 0, 0, 0);
            }
        }
    }

#pragma unroll
    for (int m = 0; m < 2; ++m) {
#pragma unroll
        for (int t = 0; t < NT; ++t) {
            int col = t * 16 + l16;
#pragma unroll
            for (int i = 0; i < 4; ++i) {
                int r = rowBase + m * 16 + quad * 4 + i;
                float v = acc[m][t][i];
                float nb = __shfl_xor(v, 1, 64);
                if (((lane & 1) == 0) && r < nrows)
                    Yb[(size_t)r * (FOUT / 2) + (col >> 1)] = bf16pair(v, nb);
            }
        }
    }
}

// ---------------- edge aggregation (F=128): masked-uniform 16-deep batches ----------------
// records scalarized to SGPRs; every round issues exactly 16 gathers (invalid
// slots clamped to a cached row with weight 0) -> constant MLP 16, no tail.

__global__ __launch_bounds__(256) void agg128_kernel(const unsigned* __restrict__ xlb,
                                                     const int* __restrict__ row_off,
                                                     const uint2* __restrict__ edges,
                                                     const float* __restrict__ dinv,
                                                     const float* __restrict__ bias,
                                                     float* __restrict__ out, int nnodes) {
    int wave = (blockIdx.x * blockDim.x + threadIdx.x) >> 6;
    int lane = threadIdx.x & 63;
    if (wave >= nnodes) return;
    int e0 = __builtin_amdgcn_readfirstlane(row_off[wave]);
    int e1 = __builtin_amdgcn_readfirstlane(row_off[wave + 1]);
    float ax = 0.f, ay = 0.f;
    int rounds = (e1 - e0 + 15) >> 4;
    for (int r = 0; r < rounds; ++r) {
        int base = e0 + (r << 4);
        unsigned sreg[16];
        float nw[16];
#pragma unroll
        for (int j = 0; j < 16; ++j) {
            int idx = base + j;
            int cl = idx < e1 ? idx : e1 - 1;
            uint2 ed = edges[cl];
            sreg[j] = (unsigned)__builtin_amdgcn_readfirstlane((int)ed.x);
            unsigned ny = (unsigned)__builtin_amdgcn_readfirstlane((int)ed.y);
            nw[j] = (idx < e1) ? __uint_as_float(ny) : 0.f;
        }
        unsigned v[16];
#pragma unroll
        for (int j = 0; j < 16; ++j) v[j] = xlb[(size_t)sreg[j] * 64 + lane];
#pragma unroll
        for (int j = 0; j < 16; ++j) {
            float2 f = bf16unpack(v[j]);
            ax += nw[j] * f.x;
            ay += nw[j] * f.y;
        }
    }
    float di = dinv[wave];
    float2 pi = bf16unpack(xlb[(size_t)wave * 64 + lane]);
    float2 bb = *(const float2*)(bias + lane * 2);
    float2 o;
    o.x = gelu_f(ax + di * pi.x + bb.x);
    o.y = gelu_f(ay + di * pi.y + bb.y);
    *(float2*)(out + (size_t)wave * 128 + lane * 2) = o;
}

// ---------------- edge aggregation (F=64): node per half-wave, masked 16-deep ----------------
// Each half-wave owns its own node and always has 16 gathers in flight.

__global__ __launch_bounds__(256) void agg64_kernel(const unsigned* __restrict__ xlb,
                                                    const int* __restrict__ row_off,
                                                    const uint2* __restrict__ edges,
                                                    const float* __restrict__ dinv,
                                                    const float* __restrict__ bias,
                                                    float* __restrict__ out, int nnodes) {
    int wave = (blockIdx.x * blockDim.x + threadIdx.x) >> 6;
    int lane = threadIdx.x & 63;
    int sub = lane >> 5;
    int sl = lane & 31;
    int node = wave * 2 + sub;
    bool nv = node < nnodes;
    int e0 = nv ? row_off[node] : 0;
    int e1 = nv ? row_off[node + 1] : 0;
    int rounds = (e1 - e0 + 15) >> 4;
    int ro = __shfl_xor(rounds, 32, 64);
    int maxr = rounds > ro ? rounds : ro;
    float ax = 0.f, ay = 0.f;
    for (int r = 0; r < maxr; ++r) {
        int base = e0 + (r << 4);
        uint2 ed[16];
#pragma unroll
        for (int j = 0; j < 16; ++j) {
            int idx = base + j;
            int cl = idx < e1 ? idx : (e1 > e0 ? e1 - 1 : 0);
            ed[j] = edges[cl];
            if (idx >= e1) ed[j].y = 0u;
        }
        unsigned v[16];
#pragma unroll
        for (int j = 0; j < 16; ++j) v[j] = xlb[(size_t)ed[j].x * 32 + sl];
#pragma unroll
        for (int j = 0; j < 16; ++j) {
            float nw = __uint_as_float(ed[j].y);
            float2 f = bf16unpack(v[j]);
            ax += nw * f.x;
            ay += nw * f.y;
        }
    }
    if (nv) {
        float di = dinv[node];
        float2 pi = bf16unpack(xlb[(size_t)node * 32 + sl]);
        float2 bb = *(const float2*)(bias + sl * 2);
        float2 o;
        o.x = gelu_f(ax + di * pi.x + bb.x);
        o.y = gelu_f(ay + di * pi.y + bb.y);
        *(float2*)(out + (size_t)node * 64 + sl * 2) = o;
    }
}

// ---------------- mean pool (batch sorted) ----------------

#define POOL_CHUNK 64

__global__ __launch_bounds__(256) void pool_kernel(const float* __restrict__ h,
                                                   const int* __restrict__ batch,
                                                   float* __restrict__ psum,
                                                   float* __restrict__ pcnt, int nnodes) {
    int wave = (blockIdx.x * blockDim.x + threadIdx.x) >> 6;
    int lane = threadIdx.x & 63;
    int n0 = wave * POOL_CHUNK;
    if (n0 >= nnodes) return;
    int n1 = n0 + POOL_CHUNK;
    if (n1 > nnodes) n1 = nnodes;

    int g_cur = batch[n0];
    float acc = 0.f;
    int cnt = 0;
    for (int node = n0; node < n1; ++node) {
        int g = batch[node];
        if (g != g_cur) {
            atomicAdd(&psum[g_cur * TDIM + lane], acc);
            if (lane == 0) atomicAdd(&pcnt[g_cur], (float)cnt);
            acc = 0.f;
            cnt = 0;
            g_cur = g;
        }
        acc += h[(size_t)node * TDIM + lane];
        ++cnt;
    }
    atomicAdd(&psum[g_cur * TDIM + lane], acc);
    if (lane == 0) atomicAdd(&pcnt[g_cur], (float)cnt);
}

__global__ __launch_bounds__(256) void fin_kernel(const float* __restrict__ psum,
                                                  const float* __restrict__ pcnt,
                                                  float* __restrict__ out) {
    int i = blockIdx.x * blockDim.x + threadIdx.x;
    if (i < NGRAPH * TDIM) {
        float c = pcnt[i >> 6];
        out[i] = psum[i] / fmaxf(c, 1.0f);
    }
}

// ---------------- launch ----------------

extern "C" void kernel_launch(void* const* d_in, const int* in_sizes, int n_in,
                              void* d_out, int out_size, void* d_ws, size_t ws_size,
                              hipStream_t stream) {
    const float* x = (const float*)d_in[0];
    const int* ei = (const int*)d_in[1];
    const int* batch = (const int*)d_in[2];
    const float* W0 = (const float*)d_in[3];
    const float* b0 = (const float*)d_in[4];
    const float* W1 = (const float*)d_in[5];
    const float* b1 = (const float*)d_in[6];
    const float* W2 = (const float*)d_in[7];
    const float* b2 = (const float*)d_in[8];

    const int N = in_sizes[0] / F_IN;
    const int E = in_sizes[1] / 2;
    const int* src = ei;
    const int* dst = ei + E;
    const int NB = (N + 255) >> 8;

    char* w = (char*)d_ws;
    auto alloc = [&](size_t bytes) -> void* {
        void* p = (void*)w;
        w += (bytes + 255) & ~(size_t)255;
        return p;
    };
    float* isq = (float*)alloc((size_t)N * 4);
    float* dinv = (float*)alloc((size_t)N * 4);
    int* cnt = (int*)alloc((size_t)N * 4);
    int* bucket_cursor = (int*)alloc((size_t)MAXNB * 4);
    int* row_off = (int*)alloc((size_t)(N + 1) * 4);
    int* bsums = (int*)alloc(256 * 4);
    uint2* edges = (uint2*)alloc((size_t)E * 8);
    uint2* tmp = (uint2*)alloc((size_t)E * 8);
    float* psum = (float*)alloc((size_t)NGRAPH * TDIM * 4);
    float* pcnt = (float*)alloc((size_t)NGRAPH * 4);
    float* bufH = (float*)alloc((size_t)N * 128 * 4);
    unsigned* bufXb = (unsigned*)alloc((size_t)N * 64 * 4);
    unsigned short* whiT0 = (unsigned short*)alloc(128 * 128 * 2);
    unsigned short* wloT0 = (unsigned short*)alloc(128 * 128 * 2);
    unsigned short* whiT1 = (unsigned short*)alloc(128 * 128 * 2);
    unsigned short* wloT1 = (unsigned short*)alloc(128 * 128 * 2);
    unsigned short* whiT2 = (unsigned short*)alloc(64 * 128 * 2);
    unsigned short* wloT2 = (unsigned short*)alloc(64 * 128 * 2);

    hipMemsetAsync(cnt, 0, (size_t)N * 4, stream);
    hipMemsetAsync(bucket_cursor, 0, (size_t)MAXNB * 4, stream);
    hipMemsetAsync(psum, 0, (size_t)NGRAPH * TDIM * 4, stream);
    hipMemsetAsync(pcnt, 0, (size_t)NGRAPH * 4, stream);

    const int tb = 256;
    deg_count_kernel<<<(E + tb - 1) / tb, tb, 0, stream>>>(dst, cnt, E);

    int nchunk = (N + 2047) / 2048;
    scanA_kernel<<<nchunk, 256, 0, stream>>>(cnt, bsums, N);
    scanB_kernel<<<1, 64, 0, stream>>>(bsums, nchunk, row_off);
    scanC_kernel<<<nchunk, 256, 0, stream>>>(cnt, bsums, row_off, isq, dinv, N);

    int cblocks = (E + BIN_CH - 1) / BIN_CH;
    binC_kernel<<<cblocks, 256, 0, stream>>>(src, dst, row_off, bucket_cursor, tmp, E, N, NB);
    binD_kernel<<<NB, 256, 0, stream>>>(tmp, row_off, isq, edges, N);

    wconv_all_kernel<<<(40960 + 255) / 256, 256, 0, stream>>>(W0, W1, W2, whiT0, wloT0, whiT1,
                                                              wloT1, whiT2, wloT2);

    int gblocks = (N + 127) / 128;
    int ablocks = (N * 64 + 255) / 256;
    int a64blocks = (((N + 1) / 2) * 64 + 255) / 256;

    // layer 0
    gemm_mfma_kernel<128><<<gblocks, 256, 0, stream>>>(x, whiT0, wloT0, bufXb, N);
    agg128_kernel<<<ablocks, 256, 0, stream>>>(bufXb, row_off, edges, dinv, b0, bufH, N);
    // layer 1
    gemm_mfma_kernel<128><<<gblocks, 256, 0, stream>>>(bufH, whiT1, wloT1, bufXb, N);
    agg128_kernel<<<ablocks, 256, 0, stream>>>(bufXb, row_off, edges, dinv, b1, bufH, N);
    // layer 2 (Fout = 64)
    gemm_mfma_kernel<64><<<gblocks, 256, 0, stream>>>(bufH, whiT2, wloT2, bufXb, N);
    agg64_kernel<<<a64blocks, 256, 0, stream>>>(bufXb, row_off, edges, dinv, b2, bufH, N);

    // pool
    int pwaves = (N + POOL_CHUNK - 1) / POOL_CHUNK;
    int pblocks = (pwaves * 64 + 255) / 256;
    pool_kernel<<<pblocks, 256, 0, stream>>>(bufH, batch, psum, pcnt, N);
    fin_kernel<<<(NGRAPH * TDIM + 255) / 256, 256, 0, stream>>>(psum, pcnt, (float*)d_out);
}

// Round 12
// 458.628 us; speedup vs baseline: 1.6926x; 1.1267x over previous
//
#include <hip/hip_runtime.h>
#include <math.h>

#define F_IN 128
#define TDIM 64
#define NGRAPH 256

typedef __attribute__((ext_vector_type(8))) short short8;
typedef __attribute__((ext_vector_type(4))) float f32x4;

__device__ __forceinline__ float gelu_f(float x) {
    float x3 = x * x * x;
    return 0.5f * x * (1.0f + tanhf(0.7978845608028654f * (x + 0.044715f * x3)));
}

// fp32 <-> bf16 bit helpers (RNE)
__device__ __forceinline__ unsigned short bf16_of(float x) {
    unsigned u = __float_as_uint(x);
    return (unsigned short)((u + 0x7fffu + ((u >> 16) & 1u)) >> 16);
}
__device__ __forceinline__ float f_of(unsigned short h) {
    return __uint_as_float(((unsigned)h) << 16);
}
__device__ __forceinline__ unsigned bf16pair(float a, float b) {
    return (unsigned)bf16_of(a) | ((unsigned)bf16_of(b) << 16);
}
__device__ __forceinline__ float2 bf16unpack(unsigned u) {
    float2 r;
    r.x = __uint_as_float(u << 16);
    r.y = __uint_as_float(u & 0xffff0000u);
    return r;
}

// ---------------- edge build: fixed-stride bucket binning (packed records) ----------------
// Bucket = 256-node dst range. tmp record = src | (dst&255)<<24 (src<2^17 fits).
// CAP=6144 vs mean 4096 (32 sigma). Defensive clamps make overflow lossy, never OOB.

#define BIN_CH 4096
#define MAXNB 512
#define CAP 6144

__global__ __launch_bounds__(256) void binC_kernel(const int* __restrict__ src,
                                                   const int* __restrict__ dst,
                                                   int* __restrict__ bucket_cnt,
                                                   unsigned* __restrict__ tmp, int E, int NB) {
    __shared__ int hist[MAXNB];
    __shared__ int hbase[MAXNB];
    __shared__ int hcur[MAXNB];
    int tid = threadIdx.x;
    int base = blockIdx.x * BIN_CH;
    int end = base + BIN_CH;
    if (end > E) end = E;
    for (int i = tid; i < NB; i += 256) hist[i] = 0;
    __syncthreads();
    for (int e = base + tid; e < end; e += 256) atomicAdd(&hist[dst[e] >> 8], 1);
    __syncthreads();
    for (int i = tid; i < NB; i += 256) {
        int c = hist[i];
        hbase[i] = (c > 0) ? atomicAdd(&bucket_cnt[i], c) : 0;
        hcur[i] = 0;
    }
    __syncthreads();
    for (int e = base + tid; e < end; e += 256) {
        int d = dst[e];
        int b = d >> 8;
        int p = atomicAdd(&hcur[b], 1);
        int slot = hbase[b] + p;
        if (slot < CAP)
            tmp[(size_t)b * CAP + slot] = (unsigned)src[e] | ((unsigned)(d & 255) << 24);
    }
}

__global__ void scanBuckets_kernel(const int* __restrict__ bucket_cnt,
                                   int* __restrict__ bbase, int* __restrict__ row_off,
                                   int NB, int N) {
    if (threadIdx.x == 0 && blockIdx.x == 0) {
        int c = 0;
        for (int i = 0; i < NB; ++i) {
            bbase[i] = c;
            int v = bucket_cnt[i];
            c += (v < CAP ? v : CAP);
        }
        row_off[N] = c;
    }
}

__global__ __launch_bounds__(256) void binDcount_kernel(const unsigned* __restrict__ tmp,
                                                        const int* __restrict__ bucket_cnt,
                                                        const int* __restrict__ bbase,
                                                        int* __restrict__ row_off,
                                                        float* __restrict__ isq,
                                                        float* __restrict__ dinv, int N) {
    __shared__ int lcnt[256];
    __shared__ int sh[256];
    int b = blockIdx.x;
    int tid = threadIdx.x;
    int cntb = bucket_cnt[b];
    if (cntb > CAP) cntb = CAP;
    lcnt[tid] = 0;
    __syncthreads();
    const unsigned* tb = tmp + (size_t)b * CAP;
    for (int e = tid; e < cntb; e += 256) atomicAdd(&lcnt[tb[e] >> 24], 1);
    __syncthreads();
    int own = lcnt[tid];
    sh[tid] = own;
    __syncthreads();
    for (int off = 1; off < 256; off <<= 1) {
        int x = (tid >= off) ? sh[tid - off] : 0;
        __syncthreads();
        sh[tid] += x;
        __syncthreads();
    }
    int excl = sh[tid] - own;
    int node = (b << 8) + tid;
    if (node < N) {
        row_off[node] = bbase[b] + excl;
        float d = (float)own + 1.0f;
        isq[node] = rsqrtf(d);
        dinv[node] = 1.0f / d;
    }
}

__global__ __launch_bounds__(256) void binDscatter_kernel(const unsigned* __restrict__ tmp,
                                                          const int* __restrict__ bucket_cnt,
                                                          const int* __restrict__ row_off,
                                                          const float* __restrict__ isq,
                                                          uint2* __restrict__ edges, int N) {
    __shared__ int lcur[256];
    __shared__ float lisq[256];
    int b = blockIdx.x;
    int node0 = b << 8;
    int tid = threadIdx.x;
    lcur[tid] = 0;
    int nd = node0 + tid;
    lisq[tid] = (nd < N) ? isq[nd] : 0.f;
    __syncthreads();
    int cntb = bucket_cnt[b];
    if (cntb > CAP) cntb = CAP;
    const unsigned* tb = tmp + (size_t)b * CAP;
    for (int e = tid; e < cntb; e += 256) {
        unsigned rec = tb[e];
        int dl = (int)(rec >> 24);
        unsigned s = rec & 0xFFFFFFu;
        int p = atomicAdd(&lcur[dl], 1);
        float nrm = isq[s] * lisq[dl];
        edges[(size_t)row_off[node0 + dl] + p] = make_uint2(s, __float_as_uint(nrm));
    }
}

// ---------------- fused weight split for all 3 layers ----------------

__global__ __launch_bounds__(256) void wconv_all_kernel(const float* __restrict__ W0,
                                                        const float* __restrict__ W1,
                                                        const float* __restrict__ W2,
                                                        unsigned short* __restrict__ hi0,
                                                        unsigned short* __restrict__ lo0,
                                                        unsigned short* __restrict__ hi1,
                                                        unsigned short* __restrict__ lo1,
                                                        unsigned short* __restrict__ hi2,
                                                        unsigned short* __restrict__ lo2) {
    int idx = blockIdx.x * blockDim.x + threadIdx.x;
    const float* W;
    unsigned short *whi, *wlo;
    int local, FOUT;
    if (idx < 16384) {
        W = W0; whi = hi0; wlo = lo0; local = idx; FOUT = 128;
    } else if (idx < 32768) {
        W = W1; whi = hi1; wlo = lo1; local = idx - 16384; FOUT = 128;
    } else if (idx < 40960) {
        W = W2; whi = hi2; wlo = lo2; local = idx - 32768; FOUT = 64;
    } else {
        return;
    }
    int k = local / FOUT;
    int n = local % FOUT;
    float w = W[local];
    unsigned short h = bf16_of(w);
    whi[(size_t)n * 128 + k] = h;
    wlo[(size_t)n * 128 + k] = bf16_of(w - f_of(h));
}

// ---------------- MFMA GEMM (split-bf16, weights in LDS): Yb = pack_bf16(X @ W) ----------------

#define LROW 136  // LDS row stride in shorts (272 B = 256 + 16 pad)

template <int FOUT>
__global__ __launch_bounds__(256) void gemm_mfma_kernel(const float* __restrict__ X,
                                                        const unsigned short* __restrict__ whiT,
                                                        const unsigned short* __restrict__ wloT,
                                                        unsigned* __restrict__ Yb, int nrows) {
    constexpr int NT = FOUT / 16;
    __shared__ short lds[2 * FOUT * LROW];
    short* shi = lds;
    short* slo = lds + FOUT * LROW;

    for (int c = threadIdx.x; c < FOUT * 16; c += 256) {
        int n = c >> 4, r = c & 15;
        *(short8*)(shi + n * LROW + r * 8) = *(const short8*)(whiT + (size_t)n * 128 + r * 8);
        *(short8*)(slo + n * LROW + r * 8) = *(const short8*)(wloT + (size_t)n * 128 + r * 8);
    }
    __syncthreads();

    int lane = threadIdx.x & 63;
    int wave = threadIdx.x >> 6;
    int quad = lane >> 4;
    int l16 = lane & 15;
    int rowBase = blockIdx.x * 128 + wave * 32;

    f32x4 acc[2][NT];
#pragma unroll
    for (int m = 0; m < 2; ++m)
#pragma unroll
        for (int t = 0; t < NT; ++t) acc[m][t] = (f32x4){0.f, 0.f, 0.f, 0.f};

    int arow0 = rowBase + l16;
    int arow1 = rowBase + 16 + l16;
    bool ok0 = arow0 < nrows, ok1 = arow1 < nrows;
    const float* xr0 = X + (size_t)arow0 * 128;
    const float* xr1 = X + (size_t)arow1 * 128;

#pragma unroll
    for (int k0 = 0; k0 < 128; k0 += 32) {
        short8 ahi[2], alo[2];
#pragma unroll
        for (int m = 0; m < 2; ++m) {
            const float* xr = m ? xr1 : xr0;
            bool ok = m ? ok1 : ok0;
            float xv[8];
            if (ok) {
                float4 v0 = *(const float4*)(xr + k0 + quad * 8);
                float4 v1 = *(const float4*)(xr + k0 + quad * 8 + 4);
                xv[0] = v0.x; xv[1] = v0.y; xv[2] = v0.z; xv[3] = v0.w;
                xv[4] = v1.x; xv[5] = v1.y; xv[6] = v1.z; xv[7] = v1.w;
            } else {
#pragma unroll
                for (int j = 0; j < 8; ++j) xv[j] = 0.f;
            }
#pragma unroll
            for (int j = 0; j < 8; ++j) {
                unsigned short h = bf16_of(xv[j]);
                ahi[m][j] = (short)h;
                alo[m][j] = (short)bf16_of(xv[j] - f_of(h));
            }
        }
#pragma unroll
        for (int t = 0; t < NT; ++t) {
            int off = (t * 16 + l16) * LROW + k0 + quad * 8;
            short8 bhi = *(const short8*)(shi + off);
            short8 blo = *(const short8*)(slo + off);
#pragma unroll
            for (int m = 0; m < 2; ++m) {
                acc[m][t] = __builtin_amdgcn_mfma_f32_16x16x32_bf16(ahi[m], bhi, acc[m][t], 0, 0, 0);
                acc[m][t] = __builtin_amdgcn_mfma_f32_16x16x32_bf16(alo[m], bhi, acc[m][t], 0, 0, 0);
                acc[m][t] = __builtin_amdgcn_mfma_f32_16x16x32_bf16(ahi[m], blo, acc[m][t], 0, 0, 0);
            }
        }
    }

#pragma unroll
    for (int m = 0; m < 2; ++m) {
#pragma unroll
        for (int t = 0; t < NT; ++t) {
            int col = t * 16 + l16;
#pragma unroll
            for (int i = 0; i < 4; ++i) {
                int r = rowBase + m * 16 + quad * 4 + i;
                float v = acc[m][t][i];
                float nb = __shfl_xor(v, 1, 64);
                if (((lane & 1) == 0) && r < nrows)
                    Yb[(size_t)r * (FOUT / 2) + (col >> 1)] = bf16pair(v, nb);
            }
        }
    }
}

// ---------------- edge aggregation (F=128): cooperative record load + readlane ----------------

__global__ __launch_bounds__(256) void agg128_kernel(const unsigned* __restrict__ xlb,
                                                     const int* __restrict__ row_off,
                                                     const uint2* __restrict__ edges,
                                                     const float* __restrict__ dinv,
                                                     const float* __restrict__ bias,
                                                     float* __restrict__ out, int nnodes) {
    int wave = (blockIdx.x * blockDim.x + threadIdx.x) >> 6;
    int lane = threadIdx.x & 63;
    if (wave >= nnodes) return;
    int e0 = __builtin_amdgcn_readfirstlane(row_off[wave]);
    int e1 = __builtin_amdgcn_readfirstlane(row_off[wave + 1]);
    float ax = 0.f, ay = 0.f;
    int rounds = (e1 - e0 + 15) >> 4;
    for (int r = 0; r < rounds; ++r) {
        int base = e0 + (r << 4);
        int idx = base + (lane & 15);
        int cl = idx < e1 ? idx : e1 - 1;
        uint2 edv = edges[cl];
        unsigned sx[16];
        float nw[16];
#pragma unroll
        for (int j = 0; j < 16; ++j) {
            sx[j] = (unsigned)__builtin_amdgcn_readlane((int)edv.x, j);
            unsigned ny = (unsigned)__builtin_amdgcn_readlane((int)edv.y, j);
            nw[j] = (base + j < e1) ? __uint_as_float(ny) : 0.f;
        }
        unsigned v[16];
#pragma unroll
        for (int j = 0; j < 16; ++j) v[j] = xlb[(size_t)sx[j] * 64 + lane];
#pragma unroll
        for (int j = 0; j < 16; ++j) {
            float2 f = bf16unpack(v[j]);
            ax += nw[j] * f.x;
            ay += nw[j] * f.y;
        }
    }
    float di = dinv[wave];
    float2 pi = bf16unpack(xlb[(size_t)wave * 64 + lane]);
    float2 bb = *(const float2*)(bias + lane * 2);
    float2 o;
    o.x = gelu_f(ax + di * pi.x + bb.x);
    o.y = gelu_f(ay + di * pi.y + bb.y);
    *(float2*)(out + (size_t)wave * 128 + lane * 2) = o;
}

// ---------------- edge aggregation (F=64): node per half-wave, masked 16-deep ----------------

__global__ __launch_bounds__(256) void agg64_kernel(const unsigned* __restrict__ xlb,
                                                    const int* __restrict__ row_off,
                                                    const uint2* __restrict__ edges,
                                                    const float* __restrict__ dinv,
                                                    const float* __restrict__ bias,
                                                    float* __restrict__ out, int nnodes) {
    int wave = (blockIdx.x * blockDim.x + threadIdx.x) >> 6;
    int lane = threadIdx.x & 63;
    int sub = lane >> 5;
    int sl = lane & 31;
    int node = wave * 2 + sub;
    bool nv = node < nnodes;
    int e0 = nv ? row_off[node] : 0;
    int e1 = nv ? row_off[node + 1] : 0;
    int rounds = (e1 - e0 + 15) >> 4;
    int ro = __shfl_xor(rounds, 32, 64);
    int maxr = rounds > ro ? rounds : ro;
    float ax = 0.f, ay = 0.f;
    for (int r = 0; r < maxr; ++r) {
        int base = e0 + (r << 4);
        uint2 ed[16];
#pragma unroll
        for (int j = 0; j < 16; ++j) {
            int idx = base + j;
            int cl = idx < e1 ? idx : (e1 > e0 ? e1 - 1 : 0);
            ed[j] = edges[cl];
            if (idx >= e1) ed[j].y = 0u;
        }
        unsigned v[16];
#pragma unroll
        for (int j = 0; j < 16; ++j) v[j] = xlb[(size_t)ed[j].x * 32 + sl];
#pragma unroll
        for (int j = 0; j < 16; ++j) {
            float nw = __uint_as_float(ed[j].y);
            float2 f = bf16unpack(v[j]);
            ax += nw * f.x;
            ay += nw * f.y;
        }
    }
    if (nv) {
        float di = dinv[node];
        float2 pi = bf16unpack(xlb[(size_t)node * 32 + sl]);
        float2 bb = *(const float2*)(bias + sl * 2);
        float2 o;
        o.x = gelu_f(ax + di * pi.x + bb.x);
        o.y = gelu_f(ay + di * pi.y + bb.y);
        *(float2*)(out + (size_t)node * 64 + sl * 2) = o;
    }
}

// ---------------- mean pool (batch sorted) ----------------

#define POOL_CHUNK 64

__global__ __launch_bounds__(256) void pool_kernel(const float* __restrict__ h,
                                                   const int* __restrict__ batch,
                                                   float* __restrict__ psum,
                                                   float* __restrict__ pcnt, int nnodes) {
    int wave = (blockIdx.x * blockDim.x + threadIdx.x) >> 6;
    int lane = threadIdx.x & 63;
    int n0 = wave * POOL_CHUNK;
    if (n0 >= nnodes) return;
    int n1 = n0 + POOL_CHUNK;
    if (n1 > nnodes) n1 = nnodes;

    int g_cur = batch[n0];
    float acc = 0.f;
    int cnt = 0;
    for (int node = n0; node < n1; ++node) {
        int g = batch[node];
        if (g != g_cur) {
            atomicAdd(&psum[g_cur * TDIM + lane], acc);
            if (lane == 0) atomicAdd(&pcnt[g_cur], (float)cnt);
            acc = 0.f;
            cnt = 0;
            g_cur = g;
        }
        acc += h[(size_t)node * TDIM + lane];
        ++cnt;
    }
    atomicAdd(&psum[g_cur * TDIM + lane], acc);
    if (lane == 0) atomicAdd(&pcnt[g_cur], (float)cnt);
}

__global__ __launch_bounds__(256) void fin_kernel(const float* __restrict__ psum,
                                                  const float* __restrict__ pcnt,
                                                  float* __restrict__ out) {
    int i = blockIdx.x * blockDim.x + threadIdx.x;
    if (i < NGRAPH * TDIM) {
        float c = pcnt[i >> 6];
        out[i] = psum[i] / fmaxf(c, 1.0f);
    }
}

// ---------------- launch ----------------

extern "C" void kernel_launch(void* const* d_in, const int* in_sizes, int n_in,
                              void* d_out, int out_size, void* d_ws, size_t ws_size,
                              hipStream_t stream) {
    const float* x = (const float*)d_in[0];
    const int* ei = (const int*)d_in[1];
    const int* batch = (const int*)d_in[2];
    const float* W0 = (const float*)d_in[3];
    const float* b0 = (const float*)d_in[4];
    const float* W1 = (const float*)d_in[5];
    const float* b1 = (const float*)d_in[6];
    const float* W2 = (const float*)d_in[7];
    const float* b2 = (const float*)d_in[8];

    const int N = in_sizes[0] / F_IN;
    const int E = in_sizes[1] / 2;
    const int* src = ei;
    const int* dst = ei + E;
    const int NB = (N + 255) >> 8;

    char* w = (char*)d_ws;
    auto alloc = [&](size_t bytes) -> void* {
        void* p = (void*)w;
        w += (bytes + 255) & ~(size_t)255;
        return p;
    };
    float* isq = (float*)alloc((size_t)N * 4);
    float* dinv = (float*)alloc((size_t)N * 4);
    int* bucket_cnt = (int*)alloc((size_t)MAXNB * 4);
    int* bbase = (int*)alloc((size_t)MAXNB * 4);
    int* row_off = (int*)alloc((size_t)(N + 1) * 4);
    uint2* edges = (uint2*)alloc((size_t)E * 8);
    unsigned* tmp = (unsigned*)alloc((size_t)NB * CAP * 4);
    float* psum = (float*)alloc((size_t)NGRAPH * TDIM * 4);
    float* pcnt = (float*)alloc((size_t)NGRAPH * 4);
    float* bufH = (float*)alloc((size_t)N * 128 * 4);
    unsigned* bufXb = (unsigned*)alloc((size_t)N * 64 * 4);
    unsigned short* whiT0 = (unsigned short*)alloc(128 * 128 * 2);
    unsigned short* wloT0 = (unsigned short*)alloc(128 * 128 * 2);
    unsigned short* whiT1 = (unsigned short*)alloc(128 * 128 * 2);
    unsigned short* wloT1 = (unsigned short*)alloc(128 * 128 * 2);
    unsigned short* whiT2 = (unsigned short*)alloc(64 * 128 * 2);
    unsigned short* wloT2 = (unsigned short*)alloc(64 * 128 * 2);

    hipMemsetAsync(bucket_cnt, 0, (size_t)MAXNB * 4, stream);
    hipMemsetAsync(psum, 0, (size_t)NGRAPH * TDIM * 4, stream);
    hipMemsetAsync(pcnt, 0, (size_t)NGRAPH * 4, stream);

    int cblocks = (E + BIN_CH - 1) / BIN_CH;
    binC_kernel<<<cblocks, 256, 0, stream>>>(src, dst, bucket_cnt, tmp, E, NB);
    scanBuckets_kernel<<<1, 64, 0, stream>>>(bucket_cnt, bbase, row_off, NB, N);
    binDcount_kernel<<<NB, 256, 0, stream>>>(tmp, bucket_cnt, bbase, row_off, isq, dinv, N);
    binDscatter_kernel<<<NB, 256, 0, stream>>>(tmp, bucket_cnt, row_off, isq, edges, N);

    wconv_all_kernel<<<(40960 + 255) / 256, 256, 0, stream>>>(W0, W1, W2, whiT0, wloT0, whiT1,
                                                              wloT1, whiT2, wloT2);

    int gblocks = (N + 127) / 128;
    int ablocks = (N * 64 + 255) / 256;
    int a64blocks = (((N + 1) / 2) * 64 + 255) / 256;

    // layer 0
    gemm_mfma_kernel<128><<<gblocks, 256, 0, stream>>>(x, whiT0, wloT0, bufXb, N);
    agg128_kernel<<<ablocks, 256, 0, stream>>>(bufXb, row_off, edges, dinv, b0, bufH, N);
    // layer 1
    gemm_mfma_kernel<128><<<gblocks, 256, 0, stream>>>(bufH, whiT1, wloT1, bufXb, N);
    agg128_kernel<<<ablocks, 256, 0, stream>>>(bufXb, row_off, edges, dinv, b1, bufH, N);
    // layer 2 (Fout = 64)
    gemm_mfma_kernel<64><<<gblocks, 256, 0, stream>>>(bufH, whiT2, wloT2, bufXb, N);
    agg64_kernel<<<a64blocks, 256, 0, stream>>>(bufXb, row_off, edges, dinv, b2, bufH, N);

    // pool
    int pwaves = (N + POOL_CHUNK - 1) / POOL_CHUNK;
    int pblocks = (pwaves * 64 + 255) / 256;
    pool_kernel<<<pblocks, 256, 0, stream>>>(bufH, batch, psum, pcnt, N);
    fin_kernel<<<(NGRAPH * TDIM + 255) / 256, 256, 0, stream>>>(psum, pcnt, (float*)d_out);
}

// Round 14
// 435.829 us; speedup vs baseline: 1.7812x; 1.0523x over previous
//
#include <hip/hip_runtime.h>
#include <math.h>

#define F_IN 128
#define TDIM 64
#define NGRAPH 256

typedef __attribute__((ext_vector_type(8))) short short8;
typedef __attribute__((ext_vector_type(4))) float f32x4;

__device__ __forceinline__ float gelu_f(float x) {
    float x3 = x * x * x;
    return 0.5f * x * (1.0f + tanhf(0.7978845608028654f * (x + 0.044715f * x3)));
}

// fp32 <-> bf16 bit helpers (RNE)
__device__ __forceinline__ unsigned short bf16_of(float x) {
    unsigned u = __float_as_uint(x);
    return (unsigned short)((u + 0x7fffu + ((u >> 16) & 1u)) >> 16);
}
__device__ __forceinline__ float f_of(unsigned short h) {
    return __uint_as_float(((unsigned)h) << 16);
}
__device__ __forceinline__ unsigned bf16pair(float a, float b) {
    return (unsigned)bf16_of(a) | ((unsigned)bf16_of(b) << 16);
}
__device__ __forceinline__ float2 bf16unpack(unsigned u) {
    float2 r;
    r.x = __uint_as_float(u << 16);
    r.y = __uint_as_float(u & 0xffff0000u);
    return r;
}

// ---------------- edge build: fixed-stride bucket binning (packed records) ----------------

#define BIN_CH 4096
#define MAXNB 512
#define CAP 6144

__global__ __launch_bounds__(256) void binC_kernel(const int* __restrict__ src,
                                                   const int* __restrict__ dst,
                                                   int* __restrict__ bucket_cnt,
                                                   unsigned* __restrict__ tmp, int E, int NB) {
    __shared__ int hist[MAXNB];
    __shared__ int hbase[MAXNB];
    __shared__ int hcur[MAXNB];
    int tid = threadIdx.x;
    int base = blockIdx.x * BIN_CH;
    int end = base + BIN_CH;
    if (end > E) end = E;
    for (int i = tid; i < NB; i += 256) hist[i] = 0;
    __syncthreads();
    for (int e = base + tid; e < end; e += 256) atomicAdd(&hist[dst[e] >> 8], 1);
    __syncthreads();
    for (int i = tid; i < NB; i += 256) {
        int c = hist[i];
        hbase[i] = (c > 0) ? atomicAdd(&bucket_cnt[i], c) : 0;
        hcur[i] = 0;
    }
    __syncthreads();
    for (int e = base + tid; e < end; e += 256) {
        int d = dst[e];
        int b = d >> 8;
        int p = atomicAdd(&hcur[b], 1);
        int slot = hbase[b] + p;
        if (slot < CAP)
            tmp[(size_t)b * CAP + slot] = (unsigned)src[e] | ((unsigned)(d & 255) << 24);
    }
}

// merged: block 0 = serial bucket scan; blocks >=1 = weight hi/lo split (independent)
__global__ __launch_bounds__(256) void scan_wconv_kernel(const int* __restrict__ bucket_cnt,
                                                         int* __restrict__ bbase,
                                                         int* __restrict__ row_off, int NB,
                                                         int N, const float* __restrict__ W0,
                                                         const float* __restrict__ W1,
                                                         const float* __restrict__ W2,
                                                         unsigned short* __restrict__ hi0,
                                                         unsigned short* __restrict__ lo0,
                                                         unsigned short* __restrict__ hi1,
                                                         unsigned short* __restrict__ lo1,
                                                         unsigned short* __restrict__ hi2,
                                                         unsigned short* __restrict__ lo2) {
    if (blockIdx.x == 0) {
        if (threadIdx.x == 0) {
            int c = 0;
            for (int i = 0; i < NB; ++i) {
                bbase[i] = c;
                int v = bucket_cnt[i];
                c += (v < CAP ? v : CAP);
            }
            row_off[N] = c;
        }
        return;
    }
    int idx = (blockIdx.x - 1) * 256 + threadIdx.x;
    const float* W;
    unsigned short *whi, *wlo;
    int local, FOUT;
    if (idx < 16384) {
        W = W0; whi = hi0; wlo = lo0; local = idx; FOUT = 128;
    } else if (idx < 32768) {
        W = W1; whi = hi1; wlo = lo1; local = idx - 16384; FOUT = 128;
    } else if (idx < 40960) {
        W = W2; whi = hi2; wlo = lo2; local = idx - 32768; FOUT = 64;
    } else {
        return;
    }
    int k = local / FOUT;
    int n = local % FOUT;
    float w = W[local];
    unsigned short h = bf16_of(w);
    whi[(size_t)n * 128 + k] = h;
    wlo[(size_t)n * 128 + k] = bf16_of(w - f_of(h));
}

__global__ __launch_bounds__(256) void binDcount_kernel(const unsigned* __restrict__ tmp,
                                                        const int* __restrict__ bucket_cnt,
                                                        const int* __restrict__ bbase,
                                                        int* __restrict__ row_off,
                                                        float* __restrict__ isq,
                                                        float* __restrict__ dinv, int N) {
    __shared__ int lcnt[256];
    __shared__ int sh[256];
    int b = blockIdx.x;
    int tid = threadIdx.x;
    int cntb = bucket_cnt[b];
    if (cntb > CAP) cntb = CAP;
    lcnt[tid] = 0;
    __syncthreads();
    const unsigned* tb = tmp + (size_t)b * CAP;
    for (int e = tid; e < cntb; e += 256) atomicAdd(&lcnt[tb[e] >> 24], 1);
    __syncthreads();
    int own = lcnt[tid];
    sh[tid] = own;
    __syncthreads();
    for (int off = 1; off < 256; off <<= 1) {
        int x = (tid >= off) ? sh[tid - off] : 0;
        __syncthreads();
        sh[tid] += x;
        __syncthreads();
    }
    int excl = sh[tid] - own;
    int node = (b << 8) + tid;
    if (node < N) {
        row_off[node] = bbase[b] + excl;
        float d = (float)own + 1.0f;
        isq[node] = rsqrtf(d);
        dinv[node] = 1.0f / d;
    }
}

__global__ __launch_bounds__(256) void binDscatter_kernel(const unsigned* __restrict__ tmp,
                                                          const int* __restrict__ bucket_cnt,
                                                          const int* __restrict__ row_off,
                                                          const float* __restrict__ isq,
                                                          uint2* __restrict__ edges, int N) {
    __shared__ int lcur[256];
    __shared__ float lisq[256];
    int b = blockIdx.x;
    int node0 = b << 8;
    int tid = threadIdx.x;
    lcur[tid] = 0;
    int nd = node0 + tid;
    lisq[tid] = (nd < N) ? isq[nd] : 0.f;
    __syncthreads();
    int cntb = bucket_cnt[b];
    if (cntb > CAP) cntb = CAP;
    const unsigned* tb = tmp + (size_t)b * CAP;
    for (int e = tid; e < cntb; e += 256) {
        unsigned rec = tb[e];
        int dl = (int)(rec >> 24);
        unsigned s = rec & 0xFFFFFFu;
        int p = atomicAdd(&lcur[dl], 1);
        float nrm = isq[s] * lisq[dl];
        edges[(size_t)row_off[node0 + dl] + p] = make_uint2(s, __float_as_uint(nrm));
    }
}

// ---------------- MFMA GEMM layer0 (fp32 X, split-bf16, 3 MFMA): Yb = pack(X @ W) ----------------

#define LROW 136  // LDS row stride in shorts (272 B = 256 + 16 pad)

__global__ __launch_bounds__(256) void gemm_f32_kernel(const float* __restrict__ X,
                                                       const unsigned short* __restrict__ whiT,
                                                       const unsigned short* __restrict__ wloT,
                                                       unsigned* __restrict__ Yb, int nrows) {
    constexpr int FOUT = 128;
    constexpr int NT = FOUT / 16;
    __shared__ short lds[2 * FOUT * LROW];
    short* shi = lds;
    short* slo = lds + FOUT * LROW;

    for (int c = threadIdx.x; c < FOUT * 16; c += 256) {
        int n = c >> 4, r = c & 15;
        *(short8*)(shi + n * LROW + r * 8) = *(const short8*)(whiT + (size_t)n * 128 + r * 8);
        *(short8*)(slo + n * LROW + r * 8) = *(const short8*)(wloT + (size_t)n * 128 + r * 8);
    }
    __syncthreads();

    int lane = threadIdx.x & 63;
    int wave = threadIdx.x >> 6;
    int quad = lane >> 4;
    int l16 = lane & 15;
    int rowBase = blockIdx.x * 128 + wave * 32;

    f32x4 acc[2][NT];
#pragma unroll
    for (int m = 0; m < 2; ++m)
#pragma unroll
        for (int t = 0; t < NT; ++t) acc[m][t] = (f32x4){0.f, 0.f, 0.f, 0.f};

    int arow0 = rowBase + l16;
    int arow1 = rowBase + 16 + l16;
    bool ok0 = arow0 < nrows, ok1 = arow1 < nrows;
    const float* xr0 = X + (size_t)arow0 * 128;
    const float* xr1 = X + (size_t)arow1 * 128;

#pragma unroll
    for (int k0 = 0; k0 < 128; k0 += 32) {
        short8 ahi[2], alo[2];
#pragma unroll
        for (int m = 0; m < 2; ++m) {
            const float* xr = m ? xr1 : xr0;
            bool ok = m ? ok1 : ok0;
            float xv[8];
            if (ok) {
                float4 v0 = *(const float4*)(xr + k0 + quad * 8);
                float4 v1 = *(const float4*)(xr + k0 + quad * 8 + 4);
                xv[0] = v0.x; xv[1] = v0.y; xv[2] = v0.z; xv[3] = v0.w;
                xv[4] = v1.x; xv[5] = v1.y; xv[6] = v1.z; xv[7] = v1.w;
            } else {
#pragma unroll
                for (int j = 0; j < 8; ++j) xv[j] = 0.f;
            }
#pragma unroll
            for (int j = 0; j < 8; ++j) {
                unsigned short h = bf16_of(xv[j]);
                ahi[m][j] = (short)h;
                alo[m][j] = (short)bf16_of(xv[j] - f_of(h));
            }
        }
#pragma unroll
        for (int t = 0; t < NT; ++t) {
            int off = (t * 16 + l16) * LROW + k0 + quad * 8;
            short8 bhi = *(const short8*)(shi + off);
            short8 blo = *(const short8*)(slo + off);
#pragma unroll
            for (int m = 0; m < 2; ++m) {
                acc[m][t] = __builtin_amdgcn_mfma_f32_16x16x32_bf16(ahi[m], bhi, acc[m][t], 0, 0, 0);
                acc[m][t] = __builtin_amdgcn_mfma_f32_16x16x32_bf16(alo[m], bhi, acc[m][t], 0, 0, 0);
                acc[m][t] = __builtin_amdgcn_mfma_f32_16x16x32_bf16(ahi[m], blo, acc[m][t], 0, 0, 0);
            }
        }
    }

#pragma unroll
    for (int m = 0; m < 2; ++m) {
#pragma unroll
        for (int t = 0; t < NT; ++t) {
            int col = t * 16 + l16;
#pragma unroll
            for (int i = 0; i < 4; ++i) {
                int r = rowBase + m * 16 + quad * 4 + i;
                float v = acc[m][t][i];
                float nb = __shfl_xor(v, 1, 64);
                if (((lane & 1) == 0) && r < nrows)
                    Yb[(size_t)r * (FOUT / 2) + (col >> 1)] = bf16pair(v, nb);
            }
        }
    }
}

// ---------------- MFMA GEMM layers 1-2 (packed bf16 X, 2 MFMA): Yb = pack(Xb @ W) ----------------

template <int FOUT>
__global__ __launch_bounds__(256) void gemm_bf16_kernel(const unsigned* __restrict__ Xb,
                                                        const unsigned short* __restrict__ whiT,
                                                        const unsigned short* __restrict__ wloT,
                                                        unsigned* __restrict__ Yb, int nrows) {
    constexpr int NT = FOUT / 16;
    __shared__ short lds[2 * FOUT * LROW];
    short* shi = lds;
    short* slo = lds + FOUT * LROW;

    for (int c = threadIdx.x; c < FOUT * 16; c += 256) {
        int n = c >> 4, r = c & 15;
        *(short8*)(shi + n * LROW + r * 8) = *(const short8*)(whiT + (size_t)n * 128 + r * 8);
        *(short8*)(slo + n * LROW + r * 8) = *(const short8*)(wloT + (size_t)n * 128 + r * 8);
    }
    __syncthreads();

    int lane = threadIdx.x & 63;
    int wave = threadIdx.x >> 6;
    int quad = lane >> 4;
    int l16 = lane & 15;
    int rowBase = blockIdx.x * 128 + wave * 32;

    f32x4 acc[2][NT];
#pragma unroll
    for (int m = 0; m < 2; ++m)
#pragma unroll
        for (int t = 0; t < NT; ++t) acc[m][t] = (f32x4){0.f, 0.f, 0.f, 0.f};

    int arow0 = rowBase + l16;
    int arow1 = rowBase + 16 + l16;
    bool ok0 = arow0 < nrows, ok1 = arow1 < nrows;
    const short* xs0 = (const short*)Xb + (size_t)arow0 * 128;
    const short* xs1 = (const short*)Xb + (size_t)arow1 * 128;

#pragma unroll
    for (int k0 = 0; k0 < 128; k0 += 32) {
        short8 a[2];
#pragma unroll
        for (int m = 0; m < 2; ++m) {
            const short* xs = m ? xs1 : xs0;
            bool ok = m ? ok1 : ok0;
            if (ok)
                a[m] = *(const short8*)(xs + k0 + quad * 8);
            else
                a[m] = (short8){0, 0, 0, 0, 0, 0, 0, 0};
        }
#pragma unroll
        for (int t = 0; t < NT; ++t) {
            int off = (t * 16 + l16) * LROW + k0 + quad * 8;
            short8 bhi = *(const short8*)(shi + off);
            short8 blo = *(const short8*)(slo + off);
#pragma unroll
            for (int m = 0; m < 2; ++m) {
                acc[m][t] = __builtin_amdgcn_mfma_f32_16x16x32_bf16(a[m], bhi, acc[m][t], 0, 0, 0);
                acc[m][t] = __builtin_amdgcn_mfma_f32_16x16x32_bf16(a[m], blo, acc[m][t], 0, 0, 0);
            }
        }
    }

#pragma unroll
    for (int m = 0; m < 2; ++m) {
#pragma unroll
        for (int t = 0; t < NT; ++t) {
            int col = t * 16 + l16;
#pragma unroll
            for (int i = 0; i < 4; ++i) {
                int r = rowBase + m * 16 + quad * 4 + i;
                float v = acc[m][t][i];
                float nb = __shfl_xor(v, 1, 64);
                if (((lane & 1) == 0) && r < nrows)
                    Yb[(size_t)r * (FOUT / 2) + (col >> 1)] = bf16pair(v, nb);
            }
        }
    }
}

// ---------------- edge aggregation (F=128): bf16 gather, packed bf16 output ----------------

__global__ __launch_bounds__(256) void agg128_kernel(const unsigned* __restrict__ xlb,
                                                     const int* __restrict__ row_off,
                                                     const uint2* __restrict__ edges,
                                                     const float* __restrict__ dinv,
                                                     const float* __restrict__ bias,
                                                     unsigned* __restrict__ outb, int nnodes) {
    int wave = (blockIdx.x * blockDim.x + threadIdx.x) >> 6;
    int lane = threadIdx.x & 63;
    if (wave >= nnodes) return;
    int e0 = __builtin_amdgcn_readfirstlane(row_off[wave]);
    int e1 = __builtin_amdgcn_readfirstlane(row_off[wave + 1]);
    float ax = 0.f, ay = 0.f;
    int rounds = (e1 - e0 + 15) >> 4;
    for (int r = 0; r < rounds; ++r) {
        int base = e0 + (r << 4);
        int idx = base + (lane & 15);
        int cl = idx < e1 ? idx : e1 - 1;
        uint2 edv = edges[cl];
        unsigned sx[16];
        float nw[16];
#pragma unroll
        for (int j = 0; j < 16; ++j) {
            sx[j] = (unsigned)__builtin_amdgcn_readlane((int)edv.x, j);
            unsigned ny = (unsigned)__builtin_amdgcn_readlane((int)edv.y, j);
            nw[j] = (base + j < e1) ? __uint_as_float(ny) : 0.f;
        }
        unsigned v[16];
#pragma unroll
        for (int j = 0; j < 16; ++j) v[j] = xlb[(size_t)sx[j] * 64 + lane];
#pragma unroll
        for (int j = 0; j < 16; ++j) {
            float2 f = bf16unpack(v[j]);
            ax += nw[j] * f.x;
            ay += nw[j] * f.y;
        }
    }
    float di = dinv[wave];
    float2 pi = bf16unpack(xlb[(size_t)wave * 64 + lane]);
    float2 bb = *(const float2*)(bias + lane * 2);
    outb[(size_t)wave * 64 + lane] =
        bf16pair(gelu_f(ax + di * pi.x + bb.x), gelu_f(ay + di * pi.y + bb.y));
}

// ---------------- edge aggregation (F=64): node per half-wave, packed output ----------------

__global__ __launch_bounds__(256) void agg64_kernel(const unsigned* __restrict__ xlb,
                                                    const int* __restrict__ row_off,
                                                    const uint2* __restrict__ edges,
                                                    const float* __restrict__ dinv,
                                                    const float* __restrict__ bias,
                                                    unsigned* __restrict__ outb, int nnodes) {
    int wave = (blockIdx.x * blockDim.x + threadIdx.x) >> 6;
    int lane = threadIdx.x & 63;
    int sub = lane >> 5;
    int sl = lane & 31;
    int node = wave * 2 + sub;
    bool nv = node < nnodes;
    int e0 = nv ? row_off[node] : 0;
    int e1 = nv ? row_off[node + 1] : 0;
    int rounds = (e1 - e0 + 15) >> 4;
    int ro = __shfl_xor(rounds, 32, 64);
    int maxr = rounds > ro ? rounds : ro;
    float ax = 0.f, ay = 0.f;
    for (int r = 0; r < maxr; ++r) {
        int base = e0 + (r << 4);
        uint2 ed[16];
#pragma unroll
        for (int j = 0; j < 16; ++j) {
            int idx = base + j;
            int cl = idx < e1 ? idx : (e1 > e0 ? e1 - 1 : 0);
            ed[j] = edges[cl];
            if (idx >= e1) ed[j].y = 0u;
        }
        unsigned v[16];
#pragma unroll
        for (int j = 0; j < 16; ++j) v[j] = xlb[(size_t)ed[j].x * 32 + sl];
#pragma unroll
        for (int j = 0; j < 16; ++j) {
            float nw = __uint_as_float(ed[j].y);
            float2 f = bf16unpack(v[j]);
            ax += nw * f.x;
            ay += nw * f.y;
        }
    }
    if (nv) {
        float di = dinv[node];
        float2 pi = bf16unpack(xlb[(size_t)node * 32 + sl]);
        float2 bb = *(const float2*)(bias + sl * 2);
        outb[(size_t)node * 32 + sl] =
            bf16pair(gelu_f(ax + di * pi.x + bb.x), gelu_f(ay + di * pi.y + bb.y));
    }
}

// ---------------- mean pool (batch sorted, packed bf16 input) ----------------

#define POOL_CHUNK 64

__global__ __launch_bounds__(256) void pool_kernel(const unsigned* __restrict__ hb,
                                                   const int* __restrict__ batch,
                                                   float* __restrict__ psum,
                                                   float* __restrict__ pcnt, int nnodes) {
    int wave = (blockIdx.x * blockDim.x + threadIdx.x) >> 6;
    int lane = threadIdx.x & 63;
    int half = lane >> 5;
    int p = lane & 31;
    int n0 = wave * POOL_CHUNK + half * 32;
    if (n0 >= nnodes) return;
    int n1 = n0 + 32;
    if (n1 > nnodes) n1 = nnodes;

    int g_cur = batch[n0];
    float accx = 0.f, accy = 0.f;
    int cnt = 0;
    for (int node = n0; node < n1; ++node) {
        int g = batch[node];
        if (g != g_cur) {
            atomicAdd(&psum[g_cur * TDIM + 2 * p], accx);
            atomicAdd(&psum[g_cur * TDIM + 2 * p + 1], accy);
            if (p == 0) atomicAdd(&pcnt[g_cur], (float)cnt);
            accx = 0.f;
            accy = 0.f;
            cnt = 0;
            g_cur = g;
        }
        float2 f = bf16unpack(hb[(size_t)node * 32 + p]);
        accx += f.x;
        accy += f.y;
        ++cnt;
    }
    atomicAdd(&psum[g_cur * TDIM + 2 * p], accx);
    atomicAdd(&psum[g_cur * TDIM + 2 * p + 1], accy);
    if (p == 0) atomicAdd(&pcnt[g_cur], (float)cnt);
}

__global__ __launch_bounds__(256) void fin_kernel(const float* __restrict__ psum,
                                                  const float* __restrict__ pcnt,
                                                  float* __restrict__ out) {
    int i = blockIdx.x * blockDim.x + threadIdx.x;
    if (i < NGRAPH * TDIM) {
        float c = pcnt[i >> 6];
        out[i] = psum[i] / fmaxf(c, 1.0f);
    }
}

// ---------------- launch ----------------

extern "C" void kernel_launch(void* const* d_in, const int* in_sizes, int n_in,
                              void* d_out, int out_size, void* d_ws, size_t ws_size,
                              hipStream_t stream) {
    const float* x = (const float*)d_in[0];
    const int* ei = (const int*)d_in[1];
    const int* batch = (const int*)d_in[2];
    const float* W0 = (const float*)d_in[3];
    const float* b0 = (const float*)d_in[4];
    const float* W1 = (const float*)d_in[5];
    const float* b1 = (const float*)d_in[6];
    const float* W2 = (const float*)d_in[7];
    const float* b2 = (const float*)d_in[8];

    const int N = in_sizes[0] / F_IN;
    const int E = in_sizes[1] / 2;
    const int* src = ei;
    const int* dst = ei + E;
    const int NB = (N + 255) >> 8;

    char* w = (char*)d_ws;
    auto alloc = [&](size_t bytes) -> void* {
        void* p = (void*)w;
        w += (bytes + 255) & ~(size_t)255;
        return p;
    };
    float* isq = (float*)alloc((size_t)N * 4);
    float* dinv = (float*)alloc((size_t)N * 4);
    int* bucket_cnt = (int*)alloc((size_t)MAXNB * 4);
    int* bbase = (int*)alloc((size_t)MAXNB * 4);
    int* row_off = (int*)alloc((size_t)(N + 1) * 4);
    uint2* edges = (uint2*)alloc((size_t)E * 8);
    unsigned* tmp = (unsigned*)alloc((size_t)NB * CAP * 4);
    float* psum = (float*)alloc((size_t)NGRAPH * TDIM * 4);
    float* pcnt = (float*)alloc((size_t)NGRAPH * 4);
    unsigned* bufXb = (unsigned*)alloc((size_t)N * 64 * 4);  // gemm outputs (packed bf16)
    unsigned* bufHb = (unsigned*)alloc((size_t)N * 64 * 4);  // agg outputs (packed bf16)
    unsigned short* whiT0 = (unsigned short*)alloc(128 * 128 * 2);
    unsigned short* wloT0 = (unsigned short*)alloc(128 * 128 * 2);
    unsigned short* whiT1 = (unsigned short*)alloc(128 * 128 * 2);
    unsigned short* wloT1 = (unsigned short*)alloc(128 * 128 * 2);
    unsigned short* whiT2 = (unsigned short*)alloc(64 * 128 * 2);
    unsigned short* wloT2 = (unsigned short*)alloc(64 * 128 * 2);

    hipMemsetAsync(bucket_cnt, 0, (size_t)MAXNB * 4, stream);
    hipMemsetAsync(psum, 0, (size_t)NGRAPH * TDIM * 4, stream);
    hipMemsetAsync(pcnt, 0, (size_t)NGRAPH * 4, stream);

    int cblocks = (E + BIN_CH - 1) / BIN_CH;
    binC_kernel<<<cblocks, 256, 0, stream>>>(src, dst, bucket_cnt, tmp, E, NB);
    scan_wconv_kernel<<<1 + (40960 + 255) / 256, 256, 0, stream>>>(
        bucket_cnt, bbase, row_off, NB, N, W0, W1, W2, whiT0, wloT0, whiT1, wloT1, whiT2,
        wloT2);
    binDcount_kernel<<<NB, 256, 0, stream>>>(tmp, bucket_cnt, bbase, row_off, isq, dinv, N);
    binDscatter_kernel<<<NB, 256, 0, stream>>>(tmp, bucket_cnt, row_off, isq, edges, N);

    int gblocks = (N + 127) / 128;
    int ablocks = (N * 64 + 255) / 256;
    int a64blocks = (((N + 1) / 2) * 64 + 255) / 256;

    // layer 0 (fp32 x input)
    gemm_f32_kernel<<<gblocks, 256, 0, stream>>>(x, whiT0, wloT0, bufXb, N);
    agg128_kernel<<<ablocks, 256, 0, stream>>>(bufXb, row_off, edges, dinv, b0, bufHb, N);
    // layer 1 (bf16 h input)
    gemm_bf16_kernel<128><<<gblocks, 256, 0, stream>>>(bufHb, whiT1, wloT1, bufXb, N);
    agg128_kernel<<<ablocks, 256, 0, stream>>>(bufXb, row_off, edges, dinv, b1, bufHb, N);
    // layer 2 (Fout = 64)
    gemm_bf16_kernel<64><<<gblocks, 256, 0, stream>>>(bufHb, whiT2, wloT2, bufXb, N);
    agg64_kernel<<<a64blocks, 256, 0, stream>>>(bufXb, row_off, edges, dinv, b2, bufHb, N);

    // pool
    int pwaves = (N + POOL_CHUNK - 1) / POOL_CHUNK;
    int pblocks = (pwaves * 64 + 255) / 256;
    pool_kernel<<<pblocks, 256, 0, stream>>>(bufHb, batch, psum, pcnt, N);
    fin_kernel<<<(NGRAPH * TDIM + 255) / 256, 256, 0, stream>>>(psum, pcnt, (float*)d_out);
}

// Round 15
// 431.799 us; speedup vs baseline: 1.7978x; 1.0093x over previous
//
#include <hip/hip_runtime.h>
#include <math.h>

#define F_IN 128
#define TDIM 64
#define NGRAPH 256

typedef __attribute__((ext_vector_type(8))) short short8;
typedef __attribute__((ext_vector_type(4))) float f32x4;

__device__ __forceinline__ float gelu_f(float x) {
    float x3 = x * x * x;
    return 0.5f * x * (1.0f + tanhf(0.7978845608028654f * (x + 0.044715f * x3)));
}

__device__ __forceinline__ unsigned short bf16_of(float x) {
    unsigned u = __float_as_uint(x);
    return (unsigned short)((u + 0x7fffu + ((u >> 16) & 1u)) >> 16);
}
__device__ __forceinline__ float f_of(unsigned short h) {
    return __uint_as_float(((unsigned)h) << 16);
}
__device__ __forceinline__ unsigned bf16pair(float a, float b) {
    return (unsigned)bf16_of(a) | ((unsigned)bf16_of(b) << 16);
}
__device__ __forceinline__ float2 bf16unpack(unsigned u) {
    float2 r;
    r.x = __uint_as_float(u << 16);
    r.y = __uint_as_float(u & 0xffff0000u);
    return r;
}

// ---------------- edge build: fixed-stride bucket binning (packed records) ----------------

#define BIN_CH 4096
#define MAXNB 512
#define CAP 6144

__global__ __launch_bounds__(256) void zero_kernel(float* __restrict__ psum,
                                                   float* __restrict__ pcnt,
                                                   int* __restrict__ bucket_cnt) {
    int i = blockIdx.x * 256 + threadIdx.x;
    if (i < NGRAPH * TDIM) psum[i] = 0.f;
    if (i < NGRAPH) pcnt[i] = 0.f;
    if (i < MAXNB) bucket_cnt[i] = 0;
}

__global__ __launch_bounds__(256) void binC_kernel(const int* __restrict__ src,
                                                   const int* __restrict__ dst,
                                                   int* __restrict__ bucket_cnt,
                                                   unsigned* __restrict__ tmp, int E, int NB) {
    __shared__ int hist[MAXNB];
    __shared__ int hbase[MAXNB];
    __shared__ int hcur[MAXNB];
    int tid = threadIdx.x;
    int base = blockIdx.x * BIN_CH;
    int end = base + BIN_CH;
    if (end > E) end = E;
    for (int i = tid; i < NB; i += 256) hist[i] = 0;
    __syncthreads();
    for (int e = base + tid; e < end; e += 256) atomicAdd(&hist[dst[e] >> 8], 1);
    __syncthreads();
    for (int i = tid; i < NB; i += 256) {
        int c = hist[i];
        hbase[i] = (c > 0) ? atomicAdd(&bucket_cnt[i], c) : 0;
        hcur[i] = 0;
    }
    __syncthreads();
    for (int e = base + tid; e < end; e += 256) {
        int d = dst[e];
        int b = d >> 8;
        int p = atomicAdd(&hcur[b], 1);
        int slot = hbase[b] + p;
        if (slot < CAP)
            tmp[(size_t)b * CAP + slot] = (unsigned)src[e] | ((unsigned)(d & 255) << 24);
    }
}

// merged: block 0 = serial bucket scan; blocks >=1 = weight hi/lo split
__global__ __launch_bounds__(256) void scan_wconv_kernel(const int* __restrict__ bucket_cnt,
                                                         int* __restrict__ bbase,
                                                         int* __restrict__ row_off, int NB,
                                                         int N, const float* __restrict__ W0,
                                                         const float* __restrict__ W1,
                                                         const float* __restrict__ W2,
                                                         unsigned short* __restrict__ hi0,
                                                         unsigned short* __restrict__ lo0,
                                                         unsigned short* __restrict__ hi1,
                                                         unsigned short* __restrict__ lo1,
                                                         unsigned short* __restrict__ hi2,
                                                         unsigned short* __restrict__ lo2) {
    if (blockIdx.x == 0) {
        if (threadIdx.x == 0) {
            int c = 0;
            for (int i = 0; i < NB; ++i) {
                bbase[i] = c;
                int v = bucket_cnt[i];
                c += (v < CAP ? v : CAP);
            }
            row_off[N] = c;
        }
        return;
    }
    int idx = (blockIdx.x - 1) * 256 + threadIdx.x;
    const float* W;
    unsigned short *whi, *wlo;
    int local, FOUT;
    if (idx < 16384) {
        W = W0; whi = hi0; wlo = lo0; local = idx; FOUT = 128;
    } else if (idx < 32768) {
        W = W1; whi = hi1; wlo = lo1; local = idx - 16384; FOUT = 128;
    } else if (idx < 40960) {
        W = W2; whi = hi2; wlo = lo2; local = idx - 32768; FOUT = 64;
    } else {
        return;
    }
    int k = local / FOUT;
    int n = local % FOUT;
    float w = W[local];
    unsigned short h = bf16_of(w);
    whi[(size_t)n * 128 + k] = h;
    wlo[(size_t)n * 128 + k] = bf16_of(w - f_of(h));
}

__global__ __launch_bounds__(256) void binDcount_kernel(const unsigned* __restrict__ tmp,
                                                        const int* __restrict__ bucket_cnt,
                                                        const int* __restrict__ bbase,
                                                        int* __restrict__ row_off,
                                                        float* __restrict__ isq,
                                                        float* __restrict__ dinv, int N) {
    __shared__ int lcnt[256];
    __shared__ int sh[256];
    int b = blockIdx.x;
    int tid = threadIdx.x;
    int cntb = bucket_cnt[b];
    if (cntb > CAP) cntb = CAP;
    lcnt[tid] = 0;
    __syncthreads();
    const unsigned* tb = tmp + (size_t)b * CAP;
    for (int e = tid; e < cntb; e += 256) atomicAdd(&lcnt[tb[e] >> 24], 1);
    __syncthreads();
    int own = lcnt[tid];
    sh[tid] = own;
    __syncthreads();
    for (int off = 1; off < 256; off <<= 1) {
        int x = (tid >= off) ? sh[tid - off] : 0;
        __syncthreads();
        sh[tid] += x;
        __syncthreads();
    }
    int excl = sh[tid] - own;
    int node = (b << 8) + tid;
    if (node < N) {
        row_off[node] = bbase[b] + excl;
        float d = (float)own + 1.0f;
        isq[node] = rsqrtf(d);
        dinv[node] = 1.0f / d;
    }
}

__global__ __launch_bounds__(256) void binDscatter_kernel(const unsigned* __restrict__ tmp,
                                                          const int* __restrict__ bucket_cnt,
                                                          const int* __restrict__ row_off,
                                                          const float* __restrict__ isq,
                                                          uint2* __restrict__ edges, int N) {
    __shared__ int lcur[256];
    __shared__ float lisq[256];
    int b = blockIdx.x;
    int node0 = b << 8;
    int tid = threadIdx.x;
    lcur[tid] = 0;
    int nd = node0 + tid;
    lisq[tid] = (nd < N) ? isq[nd] : 0.f;
    __syncthreads();
    int cntb = bucket_cnt[b];
    if (cntb > CAP) cntb = CAP;
    const unsigned* tb = tmp + (size_t)b * CAP;
    for (int e = tid; e < cntb; e += 256) {
        unsigned rec = tb[e];
        int dl = (int)(rec >> 24);
        unsigned s = rec & 0xFFFFFFu;
        int p = atomicAdd(&lcur[dl], 1);
        float nrm = isq[s] * lisq[dl];
        edges[(size_t)row_off[node0 + dl] + p] = make_uint2(s, __float_as_uint(nrm));
    }
}

// ---------------- MFMA GEMM layer0 (fp32 X, split-bf16 W, 3 MFMA, 4 M-tiles/wave) ----------------
// 256-row blocks: B-frag LDS reads amortized over 4 M-tiles (LDS-BW balance).

#define LROW 136  // LDS row stride in shorts (272 B)

__global__ __launch_bounds__(256) void gemm_f32_kernel(const float* __restrict__ X,
                                                       const unsigned short* __restrict__ whiT,
                                                       const unsigned short* __restrict__ wloT,
                                                       unsigned* __restrict__ Yb, int nrows) {
    constexpr int FOUT = 128;
    constexpr int NT = FOUT / 16;
    __shared__ short lds[2 * FOUT * LROW];
    short* shi = lds;
    short* slo = lds + FOUT * LROW;

    for (int c = threadIdx.x; c < FOUT * 16; c += 256) {
        int n = c >> 4, r = c & 15;
        *(short8*)(shi + n * LROW + r * 8) = *(const short8*)(whiT + (size_t)n * 128 + r * 8);
        *(short8*)(slo + n * LROW + r * 8) = *(const short8*)(wloT + (size_t)n * 128 + r * 8);
    }
    __syncthreads();

    int lane = threadIdx.x & 63;
    int wave = threadIdx.x >> 6;
    int quad = lane >> 4;
    int l16 = lane & 15;
    int rowBase = blockIdx.x * 256 + wave * 64;

    f32x4 acc[4][NT];
#pragma unroll
    for (int m = 0; m < 4; ++m)
#pragma unroll
        for (int t = 0; t < NT; ++t) acc[m][t] = (f32x4){0.f, 0.f, 0.f, 0.f};

    const float* xr[4];
    bool ok[4];
#pragma unroll
    for (int m = 0; m < 4; ++m) {
        int arow = rowBase + m * 16 + l16;
        ok[m] = arow < nrows;
        xr[m] = X + (size_t)arow * 128;
    }

#pragma unroll
    for (int k0 = 0; k0 < 128; k0 += 32) {
        short8 ahi[4], alo[4];
#pragma unroll
        for (int m = 0; m < 4; ++m) {
            float xv[8];
            if (ok[m]) {
                float4 v0 = *(const float4*)(xr[m] + k0 + quad * 8);
                float4 v1 = *(const float4*)(xr[m] + k0 + quad * 8 + 4);
                xv[0] = v0.x; xv[1] = v0.y; xv[2] = v0.z; xv[3] = v0.w;
                xv[4] = v1.x; xv[5] = v1.y; xv[6] = v1.z; xv[7] = v1.w;
            } else {
#pragma unroll
                for (int j = 0; j < 8; ++j) xv[j] = 0.f;
            }
#pragma unroll
            for (int j = 0; j < 8; ++j) {
                unsigned short h = bf16_of(xv[j]);
                ahi[m][j] = (short)h;
                alo[m][j] = (short)bf16_of(xv[j] - f_of(h));
            }
        }
#pragma unroll
        for (int t = 0; t < NT; ++t) {
            int off = (t * 16 + l16) * LROW + k0 + quad * 8;
            short8 bhi = *(const short8*)(shi + off);
            short8 blo = *(const short8*)(slo + off);
#pragma unroll
            for (int m = 0; m < 4; ++m) {
                acc[m][t] = __builtin_amdgcn_mfma_f32_16x16x32_bf16(ahi[m], bhi, acc[m][t], 0, 0, 0);
                acc[m][t] = __builtin_amdgcn_mfma_f32_16x16x32_bf16(alo[m], bhi, acc[m][t], 0, 0, 0);
                acc[m][t] = __builtin_amdgcn_mfma_f32_16x16x32_bf16(ahi[m], blo, acc[m][t], 0, 0, 0);
            }
        }
    }

#pragma unroll
    for (int m = 0; m < 4; ++m) {
#pragma unroll
        for (int t = 0; t < NT; ++t) {
            int col = t * 16 + l16;
#pragma unroll
            for (int i = 0; i < 4; ++i) {
                int r = rowBase + m * 16 + quad * 4 + i;
                float v = acc[m][t][i];
                float nb = __shfl_xor(v, 1, 64);
                if (((lane & 1) == 0) && r < nrows)
                    Yb[(size_t)r * (FOUT / 2) + (col >> 1)] = bf16pair(v, nb);
            }
        }
    }
}

// ---------------- MFMA GEMM layers 1-2 (bf16 X, single-bf16 W, 1 MFMA, 4 M-tiles) ----------------
// A already bf16-quantized -> split-W lo term is below the noise floor; drop it.

template <int FOUT>
__global__ __launch_bounds__(256) void gemm_bf16_kernel(const unsigned* __restrict__ Xb,
                                                        const unsigned short* __restrict__ whiT,
                                                        unsigned* __restrict__ Yb, int nrows) {
    constexpr int NT = FOUT / 16;
    __shared__ short shi[FOUT * LROW];

    for (int c = threadIdx.x; c < FOUT * 16; c += 256) {
        int n = c >> 4, r = c & 15;
        *(short8*)(shi + n * LROW + r * 8) = *(const short8*)(whiT + (size_t)n * 128 + r * 8);
    }
    __syncthreads();

    int lane = threadIdx.x & 63;
    int wave = threadIdx.x >> 6;
    int quad = lane >> 4;
    int l16 = lane & 15;
    int rowBase = blockIdx.x * 256 + wave * 64;

    f32x4 acc[4][NT];
#pragma unroll
    for (int m = 0; m < 4; ++m)
#pragma unroll
        for (int t = 0; t < NT; ++t) acc[m][t] = (f32x4){0.f, 0.f, 0.f, 0.f};

    const short* xs[4];
    bool ok[4];
#pragma unroll
    for (int m = 0; m < 4; ++m) {
        int arow = rowBase + m * 16 + l16;
        ok[m] = arow < nrows;
        xs[m] = (const short*)Xb + (size_t)arow * 128;
    }

#pragma unroll
    for (int k0 = 0; k0 < 128; k0 += 32) {
        short8 a[4];
#pragma unroll
        for (int m = 0; m < 4; ++m) {
            if (ok[m])
                a[m] = *(const short8*)(xs[m] + k0 + quad * 8);
            else
                a[m] = (short8){0, 0, 0, 0, 0, 0, 0, 0};
        }
#pragma unroll
        for (int t = 0; t < NT; ++t) {
            short8 b = *(const short8*)(shi + (t * 16 + l16) * LROW + k0 + quad * 8);
#pragma unroll
            for (int m = 0; m < 4; ++m)
                acc[m][t] = __builtin_amdgcn_mfma_f32_16x16x32_bf16(a[m], b, acc[m][t], 0, 0, 0);
        }
    }

#pragma unroll
    for (int m = 0; m < 4; ++m) {
#pragma unroll
        for (int t = 0; t < NT; ++t) {
            int col = t * 16 + l16;
#pragma unroll
            for (int i = 0; i < 4; ++i) {
                int r = rowBase + m * 16 + quad * 4 + i;
                float v = acc[m][t][i];
                float nb = __shfl_xor(v, 1, 64);
                if (((lane & 1) == 0) && r < nrows)
                    Yb[(size_t)r * (FOUT / 2) + (col >> 1)] = bf16pair(v, nb);
            }
        }
    }
}

// ---------------- edge aggregation (F=128): full/tail rounds, coop record load ----------------

__global__ __launch_bounds__(256) void agg128_kernel(const unsigned* __restrict__ xlb,
                                                     const int* __restrict__ row_off,
                                                     const uint2* __restrict__ edges,
                                                     const float* __restrict__ dinv,
                                                     const float* __restrict__ bias,
                                                     unsigned* __restrict__ outb, int nnodes) {
    int wave = (blockIdx.x * blockDim.x + threadIdx.x) >> 6;
    int lane = threadIdx.x & 63;
    if (wave >= nnodes) return;
    int e0 = __builtin_amdgcn_readfirstlane(row_off[wave]);
    int e1 = __builtin_amdgcn_readfirstlane(row_off[wave + 1]);
    float ax = 0.f, ay = 0.f;
    int e = e0;
    int nfull = (e1 - e0) >> 4;
    for (int r = 0; r < nfull; ++r, e += 16) {
        uint2 edv = edges[e + (lane & 15)];
        unsigned sx[16];
        float nw[16];
#pragma unroll
        for (int j = 0; j < 16; ++j) {
            sx[j] = (unsigned)__builtin_amdgcn_readlane((int)edv.x, j);
            nw[j] = __uint_as_float((unsigned)__builtin_amdgcn_readlane((int)edv.y, j));
        }
        unsigned v[16];
#pragma unroll
        for (int j = 0; j < 16; ++j) v[j] = xlb[(size_t)sx[j] * 64 + lane];
#pragma unroll
        for (int j = 0; j < 16; ++j) {
            float2 f = bf16unpack(v[j]);
            ax += nw[j] * f.x;
            ay += nw[j] * f.y;
        }
    }
    if (e < e1) {  // masked tail round
        int idx = e + (lane & 15);
        int cl = idx < e1 ? idx : e1 - 1;
        uint2 edv = edges[cl];
        unsigned sx[16];
        float nw[16];
#pragma unroll
        for (int j = 0; j < 16; ++j) {
            sx[j] = (unsigned)__builtin_amdgcn_readlane((int)edv.x, j);
            unsigned ny = (unsigned)__builtin_amdgcn_readlane((int)edv.y, j);
            nw[j] = (e + j < e1) ? __uint_as_float(ny) : 0.f;
        }
        unsigned v[16];
#pragma unroll
        for (int j = 0; j < 16; ++j) v[j] = xlb[(size_t)sx[j] * 64 + lane];
#pragma unroll
        for (int j = 0; j < 16; ++j) {
            float2 f = bf16unpack(v[j]);
            ax += nw[j] * f.x;
            ay += nw[j] * f.y;
        }
    }
    float di = dinv[wave];
    float2 pi = bf16unpack(xlb[(size_t)wave * 64 + lane]);
    float2 bb = *(const float2*)(bias + lane * 2);
    outb[(size_t)wave * 64 + lane] =
        bf16pair(gelu_f(ax + di * pi.x + bb.x), gelu_f(ay + di * pi.y + bb.y));
}

// ---------------- edge aggregation (F=64): node per half-wave, masked 16-deep ----------------

__global__ __launch_bounds__(256) void agg64_kernel(const unsigned* __restrict__ xlb,
                                                    const int* __restrict__ row_off,
                                                    const uint2* __restrict__ edges,
                                                    const float* __restrict__ dinv,
                                                    const float* __restrict__ bias,
                                                    unsigned* __restrict__ outb, int nnodes) {
    int wave = (blockIdx.x * blockDim.x + threadIdx.x) >> 6;
    int lane = threadIdx.x & 63;
    int sub = lane >> 5;
    int sl = lane & 31;
    int node = wave * 2 + sub;
    bool nv = node < nnodes;
    int e0 = nv ? row_off[node] : 0;
    int e1 = nv ? row_off[node + 1] : 0;
    int rounds = (e1 - e0 + 15) >> 4;
    int ro = __shfl_xor(rounds, 32, 64);
    int maxr = rounds > ro ? rounds : ro;
    float ax = 0.f, ay = 0.f;
    for (int r = 0; r < maxr; ++r) {
        int base = e0 + (r << 4);
        uint2 ed[16];
#pragma unroll
        for (int j = 0; j < 16; ++j) {
            int idx = base + j;
            int cl = idx < e1 ? idx : (e1 > e0 ? e1 - 1 : 0);
            ed[j] = edges[cl];
            if (idx >= e1) ed[j].y = 0u;
        }
        unsigned v[16];
#pragma unroll
        for (int j = 0; j < 16; ++j) v[j] = xlb[(size_t)ed[j].x * 32 + sl];
#pragma unroll
        for (int j = 0; j < 16; ++j) {
            float nw = __uint_as_float(ed[j].y);
            float2 f = bf16unpack(v[j]);
            ax += nw * f.x;
            ay += nw * f.y;
        }
    }
    if (nv) {
        float di = dinv[node];
        float2 pi = bf16unpack(xlb[(size_t)node * 32 + sl]);
        float2 bb = *(const float2*)(bias + sl * 2);
        outb[(size_t)node * 32 + sl] =
            bf16pair(gelu_f(ax + di * pi.x + bb.x), gelu_f(ay + di * pi.y + bb.y));
    }
}

// ---------------- mean pool (batch sorted, packed bf16 input) ----------------

#define POOL_CHUNK 64

__global__ __launch_bounds__(256) void pool_kernel(const unsigned* __restrict__ hb,
                                                   const int* __restrict__ batch,
                                                   float* __restrict__ psum,
                                                   float* __restrict__ pcnt, int nnodes) {
    int wave = (blockIdx.x * blockDim.x + threadIdx.x) >> 6;
    int lane = threadIdx.x & 63;
    int half = lane >> 5;
    int p = lane & 31;
    int n0 = wave * POOL_CHUNK + half * 32;
    if (n0 >= nnodes) return;
    int n1 = n0 + 32;
    if (n1 > nnodes) n1 = nnodes;

    int g_cur = batch[n0];
    float accx = 0.f, accy = 0.f;
    int cnt = 0;
    for (int node = n0; node < n1; ++node) {
        int g = batch[node];
        if (g != g_cur) {
            atomicAdd(&psum[g_cur * TDIM + 2 * p], accx);
            atomicAdd(&psum[g_cur * TDIM + 2 * p + 1], accy);
            if (p == 0) atomicAdd(&pcnt[g_cur], (float)cnt);
            accx = 0.f;
            accy = 0.f;
            cnt = 0;
            g_cur = g;
        }
        float2 f = bf16unpack(hb[(size_t)node * 32 + p]);
        accx += f.x;
        accy += f.y;
        ++cnt;
    }
    atomicAdd(&psum[g_cur * TDIM + 2 * p], accx);
    atomicAdd(&psum[g_cur * TDIM + 2 * p + 1], accy);
    if (p == 0) atomicAdd(&pcnt[g_cur], (float)cnt);
}

__global__ __launch_bounds__(256) void fin_kernel(const float* __restrict__ psum,
                                                  const float* __restrict__ pcnt,
                                                  float* __restrict__ out) {
    int i = blockIdx.x * blockDim.x + threadIdx.x;
    if (i < NGRAPH * TDIM) {
        float c = pcnt[i >> 6];
        out[i] = psum[i] / fmaxf(c, 1.0f);
    }
}

// ---------------- launch ----------------

extern "C" void kernel_launch(void* const* d_in, const int* in_sizes, int n_in,
                              void* d_out, int out_size, void* d_ws, size_t ws_size,
                              hipStream_t stream) {
    const float* x = (const float*)d_in[0];
    const int* ei = (const int*)d_in[1];
    const int* batch = (const int*)d_in[2];
    const float* W0 = (const float*)d_in[3];
    const float* b0 = (const float*)d_in[4];
    const float* W1 = (const float*)d_in[5];
    const float* b1 = (const float*)d_in[6];
    const float* W2 = (const float*)d_in[7];
    const float* b2 = (const float*)d_in[8];

    const int N = in_sizes[0] / F_IN;
    const int E = in_sizes[1] / 2;
    const int* src = ei;
    const int* dst = ei + E;
    const int NB = (N + 255) >> 8;

    char* w = (char*)d_ws;
    auto alloc = [&](size_t bytes) -> void* {
        void* p = (void*)w;
        w += (bytes + 255) & ~(size_t)255;
        return p;
    };
    float* isq = (float*)alloc((size_t)N * 4);
    float* dinv = (float*)alloc((size_t)N * 4);
    int* bucket_cnt = (int*)alloc((size_t)MAXNB * 4);
    int* bbase = (int*)alloc((size_t)MAXNB * 4);
    int* row_off = (int*)alloc((size_t)(N + 1) * 4);
    uint2* edges = (uint2*)alloc((size_t)E * 8);
    unsigned* tmp = (unsigned*)alloc((size_t)NB * CAP * 4);
    float* psum = (float*)alloc((size_t)NGRAPH * TDIM * 4);
    float* pcnt = (float*)alloc((size_t)NGRAPH * 4);
    unsigned* bufXb = (unsigned*)alloc((size_t)N * 64 * 4);
    unsigned* bufHb = (unsigned*)alloc((size_t)N * 64 * 4);
    unsigned short* whiT0 = (unsigned short*)alloc(128 * 128 * 2);
    unsigned short* wloT0 = (unsigned short*)alloc(128 * 128 * 2);
    unsigned short* whiT1 = (unsigned short*)alloc(128 * 128 * 2);
    unsigned short* wloT1 = (unsigned short*)alloc(128 * 128 * 2);
    unsigned short* whiT2 = (unsigned short*)alloc(64 * 128 * 2);
    unsigned short* wloT2 = (unsigned short*)alloc(64 * 128 * 2);

    zero_kernel<<<(NGRAPH * TDIM + 255) / 256, 256, 0, stream>>>(psum, pcnt, bucket_cnt);

    int cblocks = (E + BIN_CH - 1) / BIN_CH;
    binC_kernel<<<cblocks, 256, 0, stream>>>(src, dst, bucket_cnt, tmp, E, NB);
    scan_wconv_kernel<<<1 + (40960 + 255) / 256, 256, 0, stream>>>(
        bucket_cnt, bbase, row_off, NB, N, W0, W1, W2, whiT0, wloT0, whiT1, wloT1, whiT2,
        wloT2);
    binDcount_kernel<<<NB, 256, 0, stream>>>(tmp, bucket_cnt, bbase, row_off, isq, dinv, N);
    binDscatter_kernel<<<NB, 256, 0, stream>>>(tmp, bucket_cnt, row_off, isq, edges, N);

    int gblocks = (N + 255) / 256;
    int ablocks = (N * 64 + 255) / 256;
    int a64blocks = (((N + 1) / 2) * 64 + 255) / 256;

    // layer 0 (fp32 x input, split-W)
    gemm_f32_kernel<<<gblocks, 256, 0, stream>>>(x, whiT0, wloT0, bufXb, N);
    agg128_kernel<<<ablocks, 256, 0, stream>>>(bufXb, row_off, edges, dinv, b0, bufHb, N);
    // layer 1 (bf16 h input, single-W)
    gemm_bf16_kernel<128><<<gblocks, 256, 0, stream>>>(bufHb, whiT1, bufXb, N);
    agg128_kernel<<<ablocks, 256, 0, stream>>>(bufXb, row_off, edges, dinv, b1, bufHb, N);
    // layer 2 (Fout = 64, single-W)
    gemm_bf16_kernel<64><<<gblocks, 256, 0, stream>>>(bufHb, whiT2, bufXb, N);
    agg64_kernel<<<a64blocks, 256, 0, stream>>>(bufXb, row_off, edges, dinv, b2, bufHb, N);

    // pool
    int pwaves = (N + POOL_CHUNK - 1) / POOL_CHUNK;
    int pblocks = (pwaves * 64 + 255) / 256;
    pool_kernel<<<pblocks, 256, 0, stream>>>(bufHb, batch, psum, pcnt, N);
    fin_kernel<<<(NGRAPH * TDIM + 255) / 256, 256, 0, stream>>>(psum, pcnt, (float*)d_out);
}